// Round 1
// baseline (4676.731 us; speedup 1.0000x reference)
//
#include <hip/hip_runtime.h>
#include <math.h>

// ---------------------------------------------------------------------------
// GIN edge-attribute decoder, fp32.
// Decoder trick: concat(x2[s],x2[d],l)@W1 == ya[s]+yb[d]+l*wl, ya=x2@W1[0:128],
// yb=x2@W1[128:256]. BN (training stats) handled by: GEMM epilogue accumulates
// col sum/sumsq -> bn_fin computes scale/shift -> next kernel applies on load.
// ---------------------------------------------------------------------------

#define WAVE 64

// ---------------- small kernels ----------------

__global__ void edge_pre(const float* __restrict__ coords,
                         const int* __restrict__ esrc, const int* __restrict__ edst,
                         float* __restrict__ agg0, float* __restrict__ lbuf, int E) {
    int e = blockIdx.x * 256 + threadIdx.x;
    if (e >= E) return;
    int s0 = esrc[e], d0 = edst[e];
    float ax = coords[s0*3+0], ay = coords[s0*3+1], az = coords[s0*3+2];
    float bx = coords[d0*3+0], by = coords[d0*3+1], bz = coords[d0*3+2];
    atomicAdd(&agg0[d0*3+0], ax);
    atomicAdd(&agg0[d0*3+1], ay);
    atomicAdd(&agg0[d0*3+2], az);
    float dx = bx-ax, dy = by-ay, dz = bz-az;
    lbuf[e] = sqrtf(dx*dx + dy*dy + dz*dz);
}

// t1 = ((1+eps)*coords + agg0) @ W1 + b1   (K=3), accumulate stats
__global__ __launch_bounds__(256) void lin0(const float* __restrict__ coords,
                                            const float* __restrict__ agg0,
                                            const float* __restrict__ W1,
                                            const float* __restrict__ b1,
                                            const float* __restrict__ eps0,
                                            float* __restrict__ t1,
                                            float* __restrict__ stats, int nrows) {
    int col = threadIdx.x & 127, half = threadIdx.x >> 7;
    float w0 = W1[col], w1 = W1[128+col], w2 = W1[256+col], bb = b1[col];
    float ep = 1.f + *eps0;
    float s = 0.f, q = 0.f;
    int r0 = blockIdx.x * 64;
    for (int i = 0; i < 32; ++i) {
        int row = r0 + half + 2*i;
        if (row < nrows) {
            float h0 = fmaf(ep, coords[row*3+0], agg0[row*3+0]);
            float h1 = fmaf(ep, coords[row*3+1], agg0[row*3+1]);
            float h2 = fmaf(ep, coords[row*3+2], agg0[row*3+2]);
            float v = fmaf(h0, w0, fmaf(h1, w1, fmaf(h2, w2, bb)));
            t1[row*128+col] = v;
            s += v; q += v*v;
        }
    }
    __shared__ float red[512];
    red[half*128+col] = s;
    red[256 + half*128+col] = q;
    __syncthreads();
    if (threadIdx.x < 128) {
        atomicAdd(&stats[col],       red[col] + red[128+col]);
        atomicAdd(&stats[128+col],   red[256+col] + red[384+col]);
    }
}

__global__ void bn_fin(const float* __restrict__ stats, const float* __restrict__ g,
                       const float* __restrict__ be, float* __restrict__ sc,
                       float* __restrict__ sh, float inv_count) {
    int c = threadIdx.x;
    float m = stats[c] * inv_count;
    float v = stats[128+c] * inv_count - m*m;
    float a = g[c] * rsqrtf(fmaxf(v, 0.f) + 1e-5f);
    sc[c] = a;
    sh[c] = be[c] - m*a;
}

__global__ void ew_bnrelu(const float* __restrict__ x, const float* __restrict__ sc,
                          const float* __restrict__ sh, float* __restrict__ y, int n4) {
    for (int i = blockIdx.x*blockDim.x + threadIdx.x; i < n4; i += gridDim.x*blockDim.x) {
        int c4 = i & 31;
        float4 v = ((const float4*)x)[i];
        float4 s = ((const float4*)sc)[c4];
        float4 t = ((const float4*)sh)[c4];
        v.x = fmaxf(fmaf(v.x, s.x, t.x), 0.f);
        v.y = fmaxf(fmaf(v.y, s.y, t.y), 0.f);
        v.z = fmaxf(fmaf(v.z, s.z, t.z), 0.f);
        v.w = fmaxf(fmaf(v.w, s.w, t.w), 0.f);
        ((float4*)y)[i] = v;
    }
}

__global__ void ew_combine(const float* __restrict__ x, const float* __restrict__ a,
                           const float* __restrict__ eps, float* __restrict__ y, int n4) {
    float ep = 1.f + *eps;
    for (int i = blockIdx.x*blockDim.x + threadIdx.x; i < n4; i += gridDim.x*blockDim.x) {
        float4 v = ((const float4*)x)[i];
        float4 g = ((const float4*)a)[i];
        v.x = fmaf(ep, v.x, g.x);
        v.y = fmaf(ep, v.y, g.y);
        v.z = fmaf(ep, v.z, g.z);
        v.w = fmaf(ep, v.w, g.w);
        ((float4*)y)[i] = v;
    }
}

__global__ void scatter_feat(const float* __restrict__ x, const int* __restrict__ esrc,
                             const int* __restrict__ edst, float* __restrict__ agg, int E) {
    int g = blockIdx.x * 8 + (threadIdx.x >> 5);
    int c4 = threadIdx.x & 31;
    if (g >= E) return;
    int s0 = esrc[g], d0 = edst[g];
    float4 v = ((const float4*)x)[s0*32 + c4];
    float* dst = agg + d0*128 + c4*4;
    atomicAdd(dst+0, v.x);
    atomicAdd(dst+1, v.y);
    atomicAdd(dst+2, v.z);
    atomicAdd(dst+3, v.w);
}

// ---------------- GEMM [N,128] @ [128,128], 64-col half per block ----------------
// tile: 64 rows x 64 cols, LDS: W-half 32KB + A-tile 32KB (XOR-swizzled)
template<bool IN_BN, bool STATS>
__global__ __launch_bounds__(256, 2) void gemm64(const float* __restrict__ A,
                                                 const float* __restrict__ W,
                                                 const float* __restrict__ bias,
                                                 const float* __restrict__ sc,
                                                 const float* __restrict__ sh,
                                                 float* __restrict__ C,
                                                 float* __restrict__ stats, int nrows) {
    __shared__ float4 sW[128*16];  // [k][c4]
    __shared__ float4 sA[64*32];   // [row][k4^swz]
    const int tid = threadIdx.x;
    const int colBase = blockIdx.y * 64;
    const int cb4 = colBase >> 2;
    {
        const float4* W4 = (const float4*)W;
        for (int i = tid; i < 128*16; i += 256) {
            int k = i >> 4, c4 = i & 15;
            sW[k*16 + c4] = W4[k*32 + cb4 + c4];
        }
    }
    const int tile0 = blockIdx.x * 64;
    {
        const float4* A4 = (const float4*)A;
        #pragma unroll
        for (int i = 0; i < 8; ++i) {
            int flat = tid + 256*i;
            int r = flat >> 5, c4 = flat & 31;
            int row = tile0 + r;
            float4 v = make_float4(0.f, 0.f, 0.f, 0.f);
            if (row < nrows) {
                v = A4[row*32 + c4];
                if (IN_BN) {
                    float4 s = ((const float4*)sc)[c4];
                    float4 t = ((const float4*)sh)[c4];
                    v.x = fmaxf(fmaf(v.x, s.x, t.x), 0.f);
                    v.y = fmaxf(fmaf(v.y, s.y, t.y), 0.f);
                    v.z = fmaxf(fmaf(v.z, s.z, t.z), 0.f);
                    v.w = fmaxf(fmaf(v.w, s.w, t.w), 0.f);
                }
            }
            sA[r*32 + (c4 ^ ((r >> 2) & 3))] = v;
        }
    }
    __syncthreads();
    const int cg = tid & 15;   // 16 groups x 4 cols
    const int rg = tid >> 4;   // 16 groups x 4 rows
    const int swz = rg & 3;
    float acc[4][4];
    #pragma unroll
    for (int r = 0; r < 4; ++r)
        #pragma unroll
        for (int c = 0; c < 4; ++c) acc[r][c] = 0.f;
    #pragma unroll 4
    for (int k4 = 0; k4 < 32; ++k4) {
        float4 w0 = sW[(k4*4+0)*16 + cg];
        float4 w1 = sW[(k4*4+1)*16 + cg];
        float4 w2 = sW[(k4*4+2)*16 + cg];
        float4 w3 = sW[(k4*4+3)*16 + cg];
        #pragma unroll
        for (int r = 0; r < 4; ++r) {
            float4 a = sA[(rg*4+r)*32 + (k4 ^ swz)];
            acc[r][0] = fmaf(a.x, w0.x, fmaf(a.y, w1.x, fmaf(a.z, w2.x, fmaf(a.w, w3.x, acc[r][0]))));
            acc[r][1] = fmaf(a.x, w0.y, fmaf(a.y, w1.y, fmaf(a.z, w2.y, fmaf(a.w, w3.y, acc[r][1]))));
            acc[r][2] = fmaf(a.x, w0.z, fmaf(a.y, w1.z, fmaf(a.z, w2.z, fmaf(a.w, w3.z, acc[r][2]))));
            acc[r][3] = fmaf(a.x, w0.w, fmaf(a.y, w1.w, fmaf(a.z, w2.w, fmaf(a.w, w3.w, acc[r][3]))));
        }
    }
    float4 bv = make_float4(0.f, 0.f, 0.f, 0.f);
    if (bias) bv = ((const float4*)bias)[cb4 + cg];
    float lsum[4] = {0,0,0,0}, lsq[4] = {0,0,0,0};
    #pragma unroll
    for (int r = 0; r < 4; ++r) {
        int row = tile0 + rg*4 + r;
        if (row < nrows) {
            float4 o;
            o.x = acc[r][0] + bv.x; o.y = acc[r][1] + bv.y;
            o.z = acc[r][2] + bv.z; o.w = acc[r][3] + bv.w;
            ((float4*)C)[row*32 + cb4 + cg] = o;
            if (STATS) {
                lsum[0] += o.x; lsq[0] += o.x*o.x;
                lsum[1] += o.y; lsq[1] += o.y*o.y;
                lsum[2] += o.z; lsq[2] += o.z*o.z;
                lsum[3] += o.w; lsq[3] += o.w*o.w;
            }
        }
    }
    if (STATS) {
        __syncthreads();
        float* sf = (float*)sA;
        #pragma unroll
        for (int cc = 0; cc < 4; ++cc) {
            sf[(cg*4+cc)*16 + rg] = lsum[cc];
            sf[1024 + (cg*4+cc)*16 + rg] = lsq[cc];
        }
        __syncthreads();
        if (tid < 64) {
            float s = 0.f, q = 0.f;
            #pragma unroll
            for (int j = 0; j < 16; ++j) { s += sf[tid*16+j]; q += sf[1024+tid*16+j]; }
            atomicAdd(&stats[colBase + tid], s);
            atomicAdd(&stats[128 + colBase + tid], q);
        }
    }
}

// -------- decoder BN stats over z = ya[s]+yb[d]+l*wl+b1, per column --------
__global__ __launch_bounds__(256) void edge_stats(const float* __restrict__ ya,
                                                  const float* __restrict__ yb,
                                                  const float* __restrict__ lbuf,
                                                  const int* __restrict__ esrc,
                                                  const int* __restrict__ edst,
                                                  const float* __restrict__ wl,
                                                  const float* __restrict__ b1,
                                                  float* __restrict__ stats, int E) {
    int col = threadIdx.x & 127, half = threadIdx.x >> 7;
    float wlc = wl[col], bc = b1[col];
    float s = 0.f, q = 0.f;
    for (int e = blockIdx.x*2 + half; e < E; e += gridDim.x*2) {
        int s0 = esrc[e], d0 = edst[e];
        float lv = lbuf[e];
        float z = ya[s0*128+col] + yb[d0*128+col] + fmaf(lv, wlc, bc);
        s += z; q += z*z;
    }
    __shared__ float red[512];
    red[half*128+col] = s;
    red[256 + half*128+col] = q;
    __syncthreads();
    if (threadIdx.x < 128) {
        atomicAdd(&stats[col],     red[col] + red[128+col]);
        atomicAdd(&stats[128+col], red[256+col] + red[384+col]);
    }
}

// -------- fused decoder: z -> bnrelu -> @W2+b2 -> relu -> .w3+b3 -> sigmoid --------
__global__ __launch_bounds__(256, 2) void decoder_fused(const float* __restrict__ ya,
                                                        const float* __restrict__ yb,
                                                        const float* __restrict__ lbuf,
                                                        const int* __restrict__ esrc,
                                                        const int* __restrict__ edst,
                                                        const float* __restrict__ wl,
                                                        const float* __restrict__ b1,
                                                        const float* __restrict__ sc,
                                                        const float* __restrict__ sh,
                                                        const float* __restrict__ W2,
                                                        const float* __restrict__ b2,
                                                        const float* __restrict__ w3,
                                                        const float* __restrict__ b3p,
                                                        float* __restrict__ out, int E) {
    __shared__ float4 sW[128*16];  // W2 [128][64] = [k][c4]
    __shared__ float4 sA[64*32];   // z tile, swizzled
    const int tid = threadIdx.x;
    {
        const float4* W4 = (const float4*)W2;
        for (int i = tid; i < 128*16; i += 256) sW[i] = W4[i];
    }
    const int tile0 = blockIdx.x * 64;
    {
        #pragma unroll
        for (int i = 0; i < 8; ++i) {
            int flat = tid + 256*i;
            int r = flat >> 5, c4 = flat & 31;
            int row = tile0 + r;
            float4 v = make_float4(0.f, 0.f, 0.f, 0.f);
            if (row < E) {
                int s0 = esrc[row], d0 = edst[row];
                float lv = lbuf[row];
                float4 va = ((const float4*)ya)[s0*32 + c4];
                float4 vb = ((const float4*)yb)[d0*32 + c4];
                float4 wv = ((const float4*)wl)[c4];
                float4 bb = ((const float4*)b1)[c4];
                float4 s4 = ((const float4*)sc)[c4];
                float4 t4 = ((const float4*)sh)[c4];
                v.x = fmaxf(fmaf(va.x + vb.x + fmaf(lv, wv.x, bb.x), s4.x, t4.x), 0.f);
                v.y = fmaxf(fmaf(va.y + vb.y + fmaf(lv, wv.y, bb.y), s4.y, t4.y), 0.f);
                v.z = fmaxf(fmaf(va.z + vb.z + fmaf(lv, wv.z, bb.z), s4.z, t4.z), 0.f);
                v.w = fmaxf(fmaf(va.w + vb.w + fmaf(lv, wv.w, bb.w), s4.w, t4.w), 0.f);
            }
            sA[r*32 + (c4 ^ ((r >> 2) & 3))] = v;
        }
    }
    __syncthreads();
    const int cg = tid & 15;
    const int rg = tid >> 4;
    const int swz = rg & 3;
    float acc[4][4];
    #pragma unroll
    for (int r = 0; r < 4; ++r)
        #pragma unroll
        for (int c = 0; c < 4; ++c) acc[r][c] = 0.f;
    #pragma unroll 4
    for (int k4 = 0; k4 < 32; ++k4) {
        float4 w0 = sW[(k4*4+0)*16 + cg];
        float4 w1 = sW[(k4*4+1)*16 + cg];
        float4 w2 = sW[(k4*4+2)*16 + cg];
        float4 w3v = sW[(k4*4+3)*16 + cg];
        #pragma unroll
        for (int r = 0; r < 4; ++r) {
            float4 a = sA[(rg*4+r)*32 + (k4 ^ swz)];
            acc[r][0] = fmaf(a.x, w0.x, fmaf(a.y, w1.x, fmaf(a.z, w2.x, fmaf(a.w, w3v.x, acc[r][0]))));
            acc[r][1] = fmaf(a.x, w0.y, fmaf(a.y, w1.y, fmaf(a.z, w2.y, fmaf(a.w, w3v.y, acc[r][1]))));
            acc[r][2] = fmaf(a.x, w0.z, fmaf(a.y, w1.z, fmaf(a.z, w2.z, fmaf(a.w, w3v.z, acc[r][2]))));
            acc[r][3] = fmaf(a.x, w0.w, fmaf(a.y, w1.w, fmaf(a.z, w2.w, fmaf(a.w, w3v.w, acc[r][3]))));
        }
    }
    float p[4];
    #pragma unroll
    for (int r = 0; r < 4; ++r) {
        float sum = 0.f;
        #pragma unroll
        for (int cc = 0; cc < 4; ++cc) {
            int col = cg*4 + cc;
            float h2 = fmaxf(acc[r][cc] + b2[col], 0.f);
            sum = fmaf(h2, w3[col], sum);
        }
        p[r] = sum;
    }
    __syncthreads();
    float* sf = (float*)sA;
    #pragma unroll
    for (int r = 0; r < 4; ++r) sf[(rg*4+r)*16 + cg] = p[r];
    __syncthreads();
    if (tid < 64) {
        int row = tile0 + tid;
        if (row < E) {
            float s = b3p[0];
            #pragma unroll
            for (int j = 0; j < 16; ++j) s += sf[tid*16+j];
            out[row] = 1.f / (1.f + expf(-s));
        }
    }
}

// ---------------------------------------------------------------------------

extern "C" void kernel_launch(void* const* d_in, const int* in_sizes, int n_in,
                              void* d_out, int out_size, void* d_ws, size_t ws_size,
                              hipStream_t stream) {
    const int N = in_sizes[0] / 3;
    const int E = in_sizes[1] / 2;

    const float* coords = (const float*)d_in[0];
    const int*   ei     = (const int*)d_in[1];
    const int*   esrc = ei;
    const int*   edst = ei + E;
    const float* g0_w1 = (const float*)d_in[2];
    const float* g0_b1 = (const float*)d_in[3];
    const float* g0_g1 = (const float*)d_in[4];
    const float* g0_be1= (const float*)d_in[5];
    const float* g0_w2 = (const float*)d_in[6];
    const float* g0_b2 = (const float*)d_in[7];
    const float* g0_g2 = (const float*)d_in[8];
    const float* g0_be2= (const float*)d_in[9];
    const float* g0_w3 = (const float*)d_in[10];
    const float* g0_b3 = (const float*)d_in[11];
    const float* eps0  = (const float*)d_in[12];
    const float* bn0_g = (const float*)d_in[13];
    const float* bn0_b = (const float*)d_in[14];
    const float* g1_w1 = (const float*)d_in[15];
    const float* g1_b1 = (const float*)d_in[16];
    const float* g1_g1 = (const float*)d_in[17];
    const float* g1_be1= (const float*)d_in[18];
    const float* g1_w2 = (const float*)d_in[19];
    const float* g1_b2 = (const float*)d_in[20];
    const float* g1_g2 = (const float*)d_in[21];
    const float* g1_be2= (const float*)d_in[22];
    const float* g1_w3 = (const float*)d_in[23];
    const float* g1_b3 = (const float*)d_in[24];
    const float* eps1  = (const float*)d_in[25];
    const float* bn1_g = (const float*)d_in[26];
    const float* bn1_b = (const float*)d_in[27];
    const float* d_w1  = (const float*)d_in[28];
    const float* d_b1  = (const float*)d_in[29];
    const float* d_g   = (const float*)d_in[30];
    const float* d_be  = (const float*)d_in[31];
    const float* d_w2  = (const float*)d_in[32];
    const float* d_b2  = (const float*)d_in[33];
    const float* d_w3  = (const float*)d_in[34];
    const float* d_b3  = (const float*)d_in[35];

    float* ws = (float*)d_ws;
    const size_t NF = (size_t)N * 128;
    float* buf0 = ws;
    float* buf1 = ws + NF;
    float* buf2 = ws + 2*NF;
    float* agg0 = ws + 3*NF;                 // N*3
    float* stats= agg0 + (size_t)N*3;        // 7*256
    float* scsh = stats + 7*256;             // 7*256
    float* lbuf = scsh + 7*256;              // E

    float* out = (float*)d_out;

    const float* wl = d_w1 + 256*128;   // row 256 of d_w1

    #define STATSK(k) (stats + (k)*256)
    #define SC(k) (scsh + (k)*256)
    #define SH(k) (scsh + (k)*256 + 128)

    const int rowTiles = (N + 63) / 64;
    dim3 gemmGrid(rowTiles, 2);
    const int edgeTiles = (E + 63) / 64;
    const float invN = 1.f / (float)N;
    const float invE = 1.f / (float)E;

    // zero agg0 + all BN stat accumulators (contiguous region)
    hipMemsetAsync(agg0, 0, ((size_t)N*3 + 7*256) * sizeof(float), stream);

    // layer 0
    edge_pre<<<(E + 255)/256, 256, 0, stream>>>(coords, esrc, edst, agg0, lbuf, E);
    lin0<<<rowTiles, 256, 0, stream>>>(coords, agg0, g0_w1, g0_b1, eps0, buf0, STATSK(0), N);
    bn_fin<<<1, 128, 0, stream>>>(STATSK(0), g0_g1, g0_be1, SC(0), SH(0), invN);
    gemm64<true,true><<<gemmGrid, 256, 0, stream>>>(buf0, g0_w2, g0_b2, SC(0), SH(0), buf1, STATSK(1), N);
    bn_fin<<<1, 128, 0, stream>>>(STATSK(1), g0_g2, g0_be2, SC(1), SH(1), invN);
    gemm64<true,true><<<gemmGrid, 256, 0, stream>>>(buf1, g0_w3, g0_b3, SC(1), SH(1), buf2, STATSK(2), N);
    bn_fin<<<1, 128, 0, stream>>>(STATSK(2), bn0_g, bn0_b, SC(2), SH(2), invN);
    ew_bnrelu<<<2048, 256, 0, stream>>>(buf2, SC(2), SH(2), buf0, N*32);      // x1 -> buf0

    // layer 1
    hipMemsetAsync(buf1, 0, NF * sizeof(float), stream);                       // agg1 -> buf1
    scatter_feat<<<(E + 7)/8, 256, 0, stream>>>(buf0, esrc, edst, buf1, E);
    ew_combine<<<2048, 256, 0, stream>>>(buf0, buf1, eps1, buf2, N*32);        // h1 -> buf2
    gemm64<false,true><<<gemmGrid, 256, 0, stream>>>(buf2, g1_w1, g1_b1, nullptr, nullptr, buf0, STATSK(3), N);
    bn_fin<<<1, 128, 0, stream>>>(STATSK(3), g1_g1, g1_be1, SC(3), SH(3), invN);
    gemm64<true,true><<<gemmGrid, 256, 0, stream>>>(buf0, g1_w2, g1_b2, SC(3), SH(3), buf1, STATSK(4), N);
    bn_fin<<<1, 128, 0, stream>>>(STATSK(4), g1_g2, g1_be2, SC(4), SH(4), invN);
    gemm64<true,true><<<gemmGrid, 256, 0, stream>>>(buf1, g1_w3, g1_b3, SC(4), SH(4), buf2, STATSK(5), N);
    bn_fin<<<1, 128, 0, stream>>>(STATSK(5), bn1_g, bn1_b, SC(5), SH(5), invN);
    ew_bnrelu<<<2048, 256, 0, stream>>>(buf2, SC(5), SH(5), buf0, N*32);      // x2 -> buf0

    // decoder: ya = x2@W1[0:128], yb = x2@W1[128:256]
    gemm64<false,false><<<gemmGrid, 256, 0, stream>>>(buf0, d_w1, nullptr, nullptr, nullptr, buf1, nullptr, N);
    gemm64<false,false><<<gemmGrid, 256, 0, stream>>>(buf0, d_w1 + 128*128, nullptr, nullptr, nullptr, buf2, nullptr, N);
    edge_stats<<<2048, 256, 0, stream>>>(buf1, buf2, lbuf, esrc, edst, wl, d_b1, STATSK(6), E);
    bn_fin<<<1, 128, 0, stream>>>(STATSK(6), d_g, d_be, SC(6), SH(6), invE);
    decoder_fused<<<edgeTiles, 256, 0, stream>>>(buf1, buf2, lbuf, esrc, edst, wl, d_b1,
                                                 SC(6), SH(6), d_w2, d_b2, d_w3, d_b3, out, E);
}

// Round 2
// 2174.589 us; speedup vs baseline: 2.1506x; 2.1506x over previous
//
#include <hip/hip_runtime.h>
#include <math.h>

// ---------------------------------------------------------------------------
// GIN edge-attribute decoder, fp32.
// Round 1 -> 2 change: scatter_feat (205M f32 atomics, 2.68ms) replaced by
// CSR-by-destination build (int atomics only) + gather kernels.
// Decoder trick: concat(x2[s],x2[d],l)@W1 == ya[s]+yb[d]+l*wl.
// BN (training stats): GEMM epilogues accumulate col sum/sumsq -> bn_fin
// computes scale/shift -> next kernel applies on load.
// ---------------------------------------------------------------------------

// ---------------- CSR build ----------------

__global__ void hist_dst(const int* __restrict__ edst, int* __restrict__ cursor, int E) {
    int e = blockIdx.x * 256 + threadIdx.x;
    if (e < E) atomicAdd(&cursor[edst[e]], 1);
}

// single-block exclusive scan of deg (==cursor) -> rowoff; cursor reset to row start
__global__ __launch_bounds__(1024) void scan_deg(const int* deg, int* rowoff, int* cursor, int N) {
    __shared__ int sums[1024];
    const int t = threadIdx.x;
    const int chunk = (N + 1023) >> 10;
    int lo = t * chunk, hi = lo + chunk;
    if (lo > N) lo = N;
    if (hi > N) hi = N;
    int s = 0;
    for (int i = lo; i < hi; ++i) s += deg[i];
    sums[t] = s;
    __syncthreads();
    for (int off = 1; off < 1024; off <<= 1) {
        int add = (t >= off) ? sums[t - off] : 0;
        __syncthreads();
        sums[t] += add;
        __syncthreads();
    }
    int run = sums[t] - s;  // exclusive base for this chunk
    for (int i = lo; i < hi; ++i) {
        int d = deg[i];
        rowoff[i] = run;
        cursor[i] = run;
        run += d;
    }
    if (t == 1023) rowoff[N] = sums[1023];
}

// fill perm (src index per dst-sorted slot) + per-edge contour length
__global__ void fill_csr(const int* __restrict__ esrc, const int* __restrict__ edst,
                         const float* __restrict__ coords,
                         int* cursor, int* __restrict__ perm,
                         float* __restrict__ lbuf, int E) {
    int e = blockIdx.x * 256 + threadIdx.x;
    if (e >= E) return;
    int s0 = esrc[e], d0 = edst[e];
    int pos = atomicAdd(&cursor[d0], 1);
    perm[pos] = s0;
    float dx = coords[d0*3+0] - coords[s0*3+0];
    float dy = coords[d0*3+1] - coords[s0*3+1];
    float dz = coords[d0*3+2] - coords[s0*3+2];
    lbuf[e] = sqrtf(dx*dx + dy*dy + dz*dz);
}

// ---------------- gathers ----------------

// agg0[i] = sum_{j in nbr(i)} coords[perm[j]]   (3 floats, coords L2-resident)
__global__ void gather_coords(const float* __restrict__ coords,
                              const int* __restrict__ rowoff, const int* __restrict__ perm,
                              float* __restrict__ agg0, int N) {
    int i = blockIdx.x * 256 + threadIdx.x;
    if (i >= N) return;
    float ax = 0.f, ay = 0.f, az = 0.f;
    int b = rowoff[i], t = rowoff[i+1];
    for (int j = b; j < t; ++j) {
        int p = perm[j];
        ax += coords[p*3+0];
        ay += coords[p*3+1];
        az += coords[p*3+2];
    }
    agg0[i*3+0] = ax; agg0[i*3+1] = ay; agg0[i*3+2] = az;
}

// y[i] = (1+eps)*x[i] + sum_{j in nbr(i)} x[perm[j]]   (one wave per node)
__global__ __launch_bounds__(256) void gather_combine(const float* __restrict__ x,
                                                      const int* __restrict__ rowoff,
                                                      const int* __restrict__ perm,
                                                      const float* __restrict__ eps,
                                                      float* __restrict__ y, int N) {
    int node = blockIdx.x * 4 + (threadIdx.x >> 6);
    int lane = threadIdx.x & 63;
    if (node >= N) return;
    float ep = 1.f + *eps;
    const float2* x2 = (const float2*)x;
    int b = rowoff[node], t = rowoff[node+1];
    float2 acc = make_float2(0.f, 0.f);
    for (int j = b; j < t; ++j) {
        int p = perm[j];
        float2 v = x2[(size_t)p*64 + lane];
        acc.x += v.x; acc.y += v.y;
    }
    float2 own = x2[(size_t)node*64 + lane];
    acc.x = fmaf(ep, own.x, acc.x);
    acc.y = fmaf(ep, own.y, acc.y);
    ((float2*)y)[(size_t)node*64 + lane] = acc;
}

// ---------------- small kernels ----------------

// t1 = ((1+eps)*coords + agg0) @ W1 + b1   (K=3), accumulate stats
__global__ __launch_bounds__(256) void lin0(const float* __restrict__ coords,
                                            const float* __restrict__ agg0,
                                            const float* __restrict__ W1,
                                            const float* __restrict__ b1,
                                            const float* __restrict__ eps0,
                                            float* __restrict__ t1,
                                            float* __restrict__ stats, int nrows) {
    int col = threadIdx.x & 127, half = threadIdx.x >> 7;
    float w0 = W1[col], w1 = W1[128+col], w2 = W1[256+col], bb = b1[col];
    float ep = 1.f + *eps0;
    float s = 0.f, q = 0.f;
    int r0 = blockIdx.x * 64;
    for (int i = 0; i < 32; ++i) {
        int row = r0 + half + 2*i;
        if (row < nrows) {
            float h0 = fmaf(ep, coords[row*3+0], agg0[row*3+0]);
            float h1 = fmaf(ep, coords[row*3+1], agg0[row*3+1]);
            float h2 = fmaf(ep, coords[row*3+2], agg0[row*3+2]);
            float v = fmaf(h0, w0, fmaf(h1, w1, fmaf(h2, w2, bb)));
            t1[row*128+col] = v;
            s += v; q += v*v;
        }
    }
    __shared__ float red[512];
    red[half*128+col] = s;
    red[256 + half*128+col] = q;
    __syncthreads();
    if (threadIdx.x < 128) {
        atomicAdd(&stats[col],       red[col] + red[128+col]);
        atomicAdd(&stats[128+col],   red[256+col] + red[384+col]);
    }
}

__global__ void bn_fin(const float* __restrict__ stats, const float* __restrict__ g,
                       const float* __restrict__ be, float* __restrict__ sc,
                       float* __restrict__ sh, float inv_count) {
    int c = threadIdx.x;
    float m = stats[c] * inv_count;
    float v = stats[128+c] * inv_count - m*m;
    float a = g[c] * rsqrtf(fmaxf(v, 0.f) + 1e-5f);
    sc[c] = a;
    sh[c] = be[c] - m*a;
}

__global__ void ew_bnrelu(const float* __restrict__ x, const float* __restrict__ sc,
                          const float* __restrict__ sh, float* __restrict__ y, int n4) {
    for (int i = blockIdx.x*blockDim.x + threadIdx.x; i < n4; i += gridDim.x*blockDim.x) {
        int c4 = i & 31;
        float4 v = ((const float4*)x)[i];
        float4 s = ((const float4*)sc)[c4];
        float4 t = ((const float4*)sh)[c4];
        v.x = fmaxf(fmaf(v.x, s.x, t.x), 0.f);
        v.y = fmaxf(fmaf(v.y, s.y, t.y), 0.f);
        v.z = fmaxf(fmaf(v.z, s.z, t.z), 0.f);
        v.w = fmaxf(fmaf(v.w, s.w, t.w), 0.f);
        ((float4*)y)[i] = v;
    }
}

// ---------------- GEMM [N,128] @ [128,128], 64-col half per block ----------------
template<bool IN_BN, bool STATS>
__global__ __launch_bounds__(256, 2) void gemm64(const float* __restrict__ A,
                                                 const float* __restrict__ W,
                                                 const float* __restrict__ bias,
                                                 const float* __restrict__ sc,
                                                 const float* __restrict__ sh,
                                                 float* __restrict__ C,
                                                 float* __restrict__ stats, int nrows) {
    __shared__ float4 sW[128*16];  // [k][c4]
    __shared__ float4 sA[64*32];   // [row][k4^swz]
    const int tid = threadIdx.x;
    const int colBase = blockIdx.y * 64;
    const int cb4 = colBase >> 2;
    {
        const float4* W4 = (const float4*)W;
        for (int i = tid; i < 128*16; i += 256) {
            int k = i >> 4, c4 = i & 15;
            sW[k*16 + c4] = W4[k*32 + cb4 + c4];
        }
    }
    const int tile0 = blockIdx.x * 64;
    {
        const float4* A4 = (const float4*)A;
        #pragma unroll
        for (int i = 0; i < 8; ++i) {
            int flat = tid + 256*i;
            int r = flat >> 5, c4 = flat & 31;
            int row = tile0 + r;
            float4 v = make_float4(0.f, 0.f, 0.f, 0.f);
            if (row < nrows) {
                v = A4[row*32 + c4];
                if (IN_BN) {
                    float4 s = ((const float4*)sc)[c4];
                    float4 t = ((const float4*)sh)[c4];
                    v.x = fmaxf(fmaf(v.x, s.x, t.x), 0.f);
                    v.y = fmaxf(fmaf(v.y, s.y, t.y), 0.f);
                    v.z = fmaxf(fmaf(v.z, s.z, t.z), 0.f);
                    v.w = fmaxf(fmaf(v.w, s.w, t.w), 0.f);
                }
            }
            sA[r*32 + (c4 ^ ((r >> 2) & 3))] = v;
        }
    }
    __syncthreads();
    const int cg = tid & 15;   // 16 groups x 4 cols
    const int rg = tid >> 4;   // 16 groups x 4 rows
    const int swz = rg & 3;
    float acc[4][4];
    #pragma unroll
    for (int r = 0; r < 4; ++r)
        #pragma unroll
        for (int c = 0; c < 4; ++c) acc[r][c] = 0.f;
    #pragma unroll 4
    for (int k4 = 0; k4 < 32; ++k4) {
        float4 w0 = sW[(k4*4+0)*16 + cg];
        float4 w1 = sW[(k4*4+1)*16 + cg];
        float4 w2 = sW[(k4*4+2)*16 + cg];
        float4 w3 = sW[(k4*4+3)*16 + cg];
        #pragma unroll
        for (int r = 0; r < 4; ++r) {
            float4 a = sA[(rg*4+r)*32 + (k4 ^ swz)];
            acc[r][0] = fmaf(a.x, w0.x, fmaf(a.y, w1.x, fmaf(a.z, w2.x, fmaf(a.w, w3.x, acc[r][0]))));
            acc[r][1] = fmaf(a.x, w0.y, fmaf(a.y, w1.y, fmaf(a.z, w2.y, fmaf(a.w, w3.y, acc[r][1]))));
            acc[r][2] = fmaf(a.x, w0.z, fmaf(a.y, w1.z, fmaf(a.z, w2.z, fmaf(a.w, w3.z, acc[r][2]))));
            acc[r][3] = fmaf(a.x, w0.w, fmaf(a.y, w1.w, fmaf(a.z, w2.w, fmaf(a.w, w3.w, acc[r][3]))));
        }
    }
    float4 bv = make_float4(0.f, 0.f, 0.f, 0.f);
    if (bias) bv = ((const float4*)bias)[cb4 + cg];
    float lsum[4] = {0,0,0,0}, lsq[4] = {0,0,0,0};
    #pragma unroll
    for (int r = 0; r < 4; ++r) {
        int row = tile0 + rg*4 + r;
        if (row < nrows) {
            float4 o;
            o.x = acc[r][0] + bv.x; o.y = acc[r][1] + bv.y;
            o.z = acc[r][2] + bv.z; o.w = acc[r][3] + bv.w;
            ((float4*)C)[row*32 + cb4 + cg] = o;
            if (STATS) {
                lsum[0] += o.x; lsq[0] += o.x*o.x;
                lsum[1] += o.y; lsq[1] += o.y*o.y;
                lsum[2] += o.z; lsq[2] += o.z*o.z;
                lsum[3] += o.w; lsq[3] += o.w*o.w;
            }
        }
    }
    if (STATS) {
        __syncthreads();
        float* sf = (float*)sA;
        #pragma unroll
        for (int cc = 0; cc < 4; ++cc) {
            sf[(cg*4+cc)*16 + rg] = lsum[cc];
            sf[1024 + (cg*4+cc)*16 + rg] = lsq[cc];
        }
        __syncthreads();
        if (tid < 64) {
            float s = 0.f, q = 0.f;
            #pragma unroll
            for (int j = 0; j < 16; ++j) { s += sf[tid*16+j]; q += sf[1024+tid*16+j]; }
            atomicAdd(&stats[colBase + tid], s);
            atomicAdd(&stats[128 + colBase + tid], q);
        }
    }
}

// -------- decoder BN stats over z = ya[s]+yb[d]+l*wl+b1, per column --------
__global__ __launch_bounds__(256) void edge_stats(const float* __restrict__ ya,
                                                  const float* __restrict__ yb,
                                                  const float* __restrict__ lbuf,
                                                  const int* __restrict__ esrc,
                                                  const int* __restrict__ edst,
                                                  const float* __restrict__ wl,
                                                  const float* __restrict__ b1,
                                                  float* __restrict__ stats, int E) {
    int col = threadIdx.x & 127, half = threadIdx.x >> 7;
    float wlc = wl[col], bc = b1[col];
    float s = 0.f, q = 0.f;
    for (int e = blockIdx.x*2 + half; e < E; e += gridDim.x*2) {
        int s0 = esrc[e], d0 = edst[e];
        float lv = lbuf[e];
        float z = ya[s0*128+col] + yb[d0*128+col] + fmaf(lv, wlc, bc);
        s += z; q += z*z;
    }
    __shared__ float red[512];
    red[half*128+col] = s;
    red[256 + half*128+col] = q;
    __syncthreads();
    if (threadIdx.x < 128) {
        atomicAdd(&stats[col],     red[col] + red[128+col]);
        atomicAdd(&stats[128+col], red[256+col] + red[384+col]);
    }
}

// -------- fused decoder: z -> bnrelu -> @W2+b2 -> relu -> .w3+b3 -> sigmoid --------
__global__ __launch_bounds__(256, 2) void decoder_fused(const float* __restrict__ ya,
                                                        const float* __restrict__ yb,
                                                        const float* __restrict__ lbuf,
                                                        const int* __restrict__ esrc,
                                                        const int* __restrict__ edst,
                                                        const float* __restrict__ wl,
                                                        const float* __restrict__ b1,
                                                        const float* __restrict__ sc,
                                                        const float* __restrict__ sh,
                                                        const float* __restrict__ W2,
                                                        const float* __restrict__ b2,
                                                        const float* __restrict__ w3,
                                                        const float* __restrict__ b3p,
                                                        float* __restrict__ out, int E) {
    __shared__ float4 sW[128*16];  // W2 [128][64] = [k][c4]
    __shared__ float4 sA[64*32];   // z tile, swizzled
    const int tid = threadIdx.x;
    {
        const float4* W4 = (const float4*)W2;
        for (int i = tid; i < 128*16; i += 256) sW[i] = W4[i];
    }
    const int tile0 = blockIdx.x * 64;
    {
        #pragma unroll
        for (int i = 0; i < 8; ++i) {
            int flat = tid + 256*i;
            int r = flat >> 5, c4 = flat & 31;
            int row = tile0 + r;
            float4 v = make_float4(0.f, 0.f, 0.f, 0.f);
            if (row < E) {
                int s0 = esrc[row], d0 = edst[row];
                float lv = lbuf[row];
                float4 va = ((const float4*)ya)[s0*32 + c4];
                float4 vb = ((const float4*)yb)[d0*32 + c4];
                float4 wv = ((const float4*)wl)[c4];
                float4 bb = ((const float4*)b1)[c4];
                float4 s4 = ((const float4*)sc)[c4];
                float4 t4 = ((const float4*)sh)[c4];
                v.x = fmaxf(fmaf(va.x + vb.x + fmaf(lv, wv.x, bb.x), s4.x, t4.x), 0.f);
                v.y = fmaxf(fmaf(va.y + vb.y + fmaf(lv, wv.y, bb.y), s4.y, t4.y), 0.f);
                v.z = fmaxf(fmaf(va.z + vb.z + fmaf(lv, wv.z, bb.z), s4.z, t4.z), 0.f);
                v.w = fmaxf(fmaf(va.w + vb.w + fmaf(lv, wv.w, bb.w), s4.w, t4.w), 0.f);
            }
            sA[r*32 + (c4 ^ ((r >> 2) & 3))] = v;
        }
    }
    __syncthreads();
    const int cg = tid & 15;
    const int rg = tid >> 4;
    const int swz = rg & 3;
    float acc[4][4];
    #pragma unroll
    for (int r = 0; r < 4; ++r)
        #pragma unroll
        for (int c = 0; c < 4; ++c) acc[r][c] = 0.f;
    #pragma unroll 4
    for (int k4 = 0; k4 < 32; ++k4) {
        float4 w0 = sW[(k4*4+0)*16 + cg];
        float4 w1 = sW[(k4*4+1)*16 + cg];
        float4 w2 = sW[(k4*4+2)*16 + cg];
        float4 w3v = sW[(k4*4+3)*16 + cg];
        #pragma unroll
        for (int r = 0; r < 4; ++r) {
            float4 a = sA[(rg*4+r)*32 + (k4 ^ swz)];
            acc[r][0] = fmaf(a.x, w0.x, fmaf(a.y, w1.x, fmaf(a.z, w2.x, fmaf(a.w, w3v.x, acc[r][0]))));
            acc[r][1] = fmaf(a.x, w0.y, fmaf(a.y, w1.y, fmaf(a.z, w2.y, fmaf(a.w, w3v.y, acc[r][1]))));
            acc[r][2] = fmaf(a.x, w0.z, fmaf(a.y, w1.z, fmaf(a.z, w2.z, fmaf(a.w, w3v.z, acc[r][2]))));
            acc[r][3] = fmaf(a.x, w0.w, fmaf(a.y, w1.w, fmaf(a.z, w2.w, fmaf(a.w, w3v.w, acc[r][3]))));
        }
    }
    float p[4];
    #pragma unroll
    for (int r = 0; r < 4; ++r) {
        float sum = 0.f;
        #pragma unroll
        for (int cc = 0; cc < 4; ++cc) {
            int col = cg*4 + cc;
            float h2 = fmaxf(acc[r][cc] + b2[col], 0.f);
            sum = fmaf(h2, w3[col], sum);
        }
        p[r] = sum;
    }
    __syncthreads();
    float* sf = (float*)sA;
    #pragma unroll
    for (int r = 0; r < 4; ++r) sf[(rg*4+r)*16 + cg] = p[r];
    __syncthreads();
    if (tid < 64) {
        int row = tile0 + tid;
        if (row < E) {
            float s = b3p[0];
            #pragma unroll
            for (int j = 0; j < 16; ++j) s += sf[tid*16+j];
            out[row] = 1.f / (1.f + expf(-s));
        }
    }
}

// ---------------------------------------------------------------------------

extern "C" void kernel_launch(void* const* d_in, const int* in_sizes, int n_in,
                              void* d_out, int out_size, void* d_ws, size_t ws_size,
                              hipStream_t stream) {
    const int N = in_sizes[0] / 3;
    const int E = in_sizes[1] / 2;

    const float* coords = (const float*)d_in[0];
    const int*   ei     = (const int*)d_in[1];
    const int*   esrc = ei;
    const int*   edst = ei + E;
    const float* g0_w1 = (const float*)d_in[2];
    const float* g0_b1 = (const float*)d_in[3];
    const float* g0_g1 = (const float*)d_in[4];
    const float* g0_be1= (const float*)d_in[5];
    const float* g0_w2 = (const float*)d_in[6];
    const float* g0_b2 = (const float*)d_in[7];
    const float* g0_g2 = (const float*)d_in[8];
    const float* g0_be2= (const float*)d_in[9];
    const float* g0_w3 = (const float*)d_in[10];
    const float* g0_b3 = (const float*)d_in[11];
    const float* eps0  = (const float*)d_in[12];
    const float* bn0_g = (const float*)d_in[13];
    const float* bn0_b = (const float*)d_in[14];
    const float* g1_w1 = (const float*)d_in[15];
    const float* g1_b1 = (const float*)d_in[16];
    const float* g1_g1 = (const float*)d_in[17];
    const float* g1_be1= (const float*)d_in[18];
    const float* g1_w2 = (const float*)d_in[19];
    const float* g1_b2 = (const float*)d_in[20];
    const float* g1_g2 = (const float*)d_in[21];
    const float* g1_be2= (const float*)d_in[22];
    const float* g1_w3 = (const float*)d_in[23];
    const float* g1_b3 = (const float*)d_in[24];
    const float* eps1  = (const float*)d_in[25];
    const float* bn1_g = (const float*)d_in[26];
    const float* bn1_b = (const float*)d_in[27];
    const float* d_w1  = (const float*)d_in[28];
    const float* d_b1  = (const float*)d_in[29];
    const float* d_g   = (const float*)d_in[30];
    const float* d_be  = (const float*)d_in[31];
    const float* d_w2  = (const float*)d_in[32];
    const float* d_b2  = (const float*)d_in[33];
    const float* d_w3  = (const float*)d_in[34];
    const float* d_b3  = (const float*)d_in[35];

    float* ws = (float*)d_ws;
    const size_t NF = (size_t)N * 128;
    float* buf0 = ws;
    float* buf1 = ws + NF;
    float* buf2 = ws + 2*NF;
    float* agg0 = ws + 3*NF;                 // N*3
    float* stats= agg0 + (size_t)N*3;        // 7*256
    float* scsh = stats + 7*256;             // 7*256
    float* lbuf = scsh + 7*256;              // E
    int*   cursor = (int*)(lbuf + E);        // N
    int*   rowoff = cursor + N;              // N+1
    int*   perm   = rowoff + N + 1;          // E

    float* out = (float*)d_out;

    const float* wl = d_w1 + 256*128;   // row 256 of d_w1

    #define STATSK(k) (stats + (k)*256)
    #define SC(k) (scsh + (k)*256)
    #define SH(k) (scsh + (k)*256 + 128)

    const int rowTiles = (N + 63) / 64;
    dim3 gemmGrid(rowTiles, 2);
    const int edgeTiles = (E + 63) / 64;
    const int eBlocks = (E + 255) / 256;
    const float invN = 1.f / (float)N;
    const float invE = 1.f / (float)E;

    // zero BN stat accumulators + CSR cursor
    hipMemsetAsync(stats, 0, 7*256 * sizeof(float), stream);
    hipMemsetAsync(cursor, 0, (size_t)N * sizeof(int), stream);

    // CSR build (by destination) + per-edge length
    hist_dst<<<eBlocks, 256, 0, stream>>>(edst, cursor, E);
    scan_deg<<<1, 1024, 0, stream>>>(cursor, rowoff, cursor, N);
    fill_csr<<<eBlocks, 256, 0, stream>>>(esrc, edst, coords, cursor, perm, lbuf, E);

    // layer 0
    gather_coords<<<(N + 255)/256, 256, 0, stream>>>(coords, rowoff, perm, agg0, N);
    lin0<<<rowTiles, 256, 0, stream>>>(coords, agg0, g0_w1, g0_b1, eps0, buf0, STATSK(0), N);
    bn_fin<<<1, 128, 0, stream>>>(STATSK(0), g0_g1, g0_be1, SC(0), SH(0), invN);
    gemm64<true,true><<<gemmGrid, 256, 0, stream>>>(buf0, g0_w2, g0_b2, SC(0), SH(0), buf1, STATSK(1), N);
    bn_fin<<<1, 128, 0, stream>>>(STATSK(1), g0_g2, g0_be2, SC(1), SH(1), invN);
    gemm64<true,true><<<gemmGrid, 256, 0, stream>>>(buf1, g0_w3, g0_b3, SC(1), SH(1), buf2, STATSK(2), N);
    bn_fin<<<1, 128, 0, stream>>>(STATSK(2), bn0_g, bn0_b, SC(2), SH(2), invN);
    ew_bnrelu<<<2048, 256, 0, stream>>>(buf2, SC(2), SH(2), buf0, N*32);      // x1 -> buf0

    // layer 1: h1 = (1+eps1)*x1 + gather(x1)  -> buf1  (replaces memset+scatter+combine)
    gather_combine<<<(N + 3)/4, 256, 0, stream>>>(buf0, rowoff, perm, eps1, buf1, N);
    gemm64<false,true><<<gemmGrid, 256, 0, stream>>>(buf1, g1_w1, g1_b1, nullptr, nullptr, buf2, STATSK(3), N);
    bn_fin<<<1, 128, 0, stream>>>(STATSK(3), g1_g1, g1_be1, SC(3), SH(3), invN);
    gemm64<true,true><<<gemmGrid, 256, 0, stream>>>(buf2, g1_w2, g1_b2, SC(3), SH(3), buf0, STATSK(4), N);
    bn_fin<<<1, 128, 0, stream>>>(STATSK(4), g1_g2, g1_be2, SC(4), SH(4), invN);
    gemm64<true,true><<<gemmGrid, 256, 0, stream>>>(buf0, g1_w3, g1_b3, SC(4), SH(4), buf1, STATSK(5), N);
    bn_fin<<<1, 128, 0, stream>>>(STATSK(5), bn1_g, bn1_b, SC(5), SH(5), invN);
    ew_bnrelu<<<2048, 256, 0, stream>>>(buf1, SC(5), SH(5), buf0, N*32);      // x2 -> buf0

    // decoder: ya = x2@W1[0:128], yb = x2@W1[128:256]
    gemm64<false,false><<<gemmGrid, 256, 0, stream>>>(buf0, d_w1, nullptr, nullptr, nullptr, buf1, nullptr, N);
    gemm64<false,false><<<gemmGrid, 256, 0, stream>>>(buf0, d_w1 + 128*128, nullptr, nullptr, nullptr, buf2, nullptr, N);
    edge_stats<<<2048, 256, 0, stream>>>(buf1, buf2, lbuf, esrc, edst, wl, d_b1, STATSK(6), E);
    bn_fin<<<1, 128, 0, stream>>>(STATSK(6), d_g, d_be, SC(6), SH(6), invE);
    decoder_fused<<<edgeTiles, 256, 0, stream>>>(buf1, buf2, lbuf, esrc, edst, wl, d_b1,
                                                 SC(6), SH(6), d_w2, d_b2, d_w3, d_b3, out, E);
}

// Round 4
// 2050.740 us; speedup vs baseline: 2.2805x; 1.0604x over previous
//
#include <hip/hip_runtime.h>
#include <math.h>

// ---------------------------------------------------------------------------
// GIN edge-attribute decoder, fp32.
// Round 2 -> 3 (resubmitted; round 3 bench was an infra timeout): process
// decoder edge passes in CSR (dst-sorted) slot order so yb[dst] is
// cache/register-local; edge_stats replaced by node-centric csr_stats (yb row
// in regs, only ya gathered); gather_combine pipelined.
// Decoder trick: concat(x2[s],x2[d],l)@W1 == ya[s]+yb[d]+l*wl.
// BN (training stats): GEMM epilogues accumulate col sum/sumsq -> bn_fin
// computes scale/shift -> next kernel applies on load.
// ---------------------------------------------------------------------------

// ---------------- CSR build ----------------

__global__ void hist_dst(const int* __restrict__ edst, int* __restrict__ cursor, int E) {
    int e = blockIdx.x * 256 + threadIdx.x;
    if (e < E) atomicAdd(&cursor[edst[e]], 1);
}

// single-block exclusive scan of deg (==cursor) -> rowoff; cursor reset to row start
__global__ __launch_bounds__(1024) void scan_deg(const int* deg, int* rowoff, int* cursor, int N) {
    __shared__ int sums[1024];
    const int t = threadIdx.x;
    const int chunk = (N + 1023) >> 10;
    int lo = t * chunk, hi = lo + chunk;
    if (lo > N) lo = N;
    if (hi > N) hi = N;
    int s = 0;
    for (int i = lo; i < hi; ++i) s += deg[i];
    sums[t] = s;
    __syncthreads();
    for (int off = 1; off < 1024; off <<= 1) {
        int add = (t >= off) ? sums[t - off] : 0;
        __syncthreads();
        sums[t] += add;
        __syncthreads();
    }
    int run = sums[t] - s;  // exclusive base for this chunk
    for (int i = lo; i < hi; ++i) {
        int d = deg[i];
        rowoff[i] = run;
        cursor[i] = run;
        run += d;
    }
    if (t == 1023) rowoff[N] = sums[1023];
}

// fill CSR slot arrays: src, dst, edge-id, contour length (slot order)
__global__ void fill_csr(const int* __restrict__ esrc, const int* __restrict__ edst,
                         const float* __restrict__ coords,
                         int* cursor, int* __restrict__ perm, int* __restrict__ dperm,
                         int* __restrict__ eperm, float* __restrict__ lperm, int E) {
    int e = blockIdx.x * 256 + threadIdx.x;
    if (e >= E) return;
    int s0 = esrc[e], d0 = edst[e];
    int pos = atomicAdd(&cursor[d0], 1);
    perm[pos] = s0;
    dperm[pos] = d0;
    eperm[pos] = e;
    float dx = coords[d0*3+0] - coords[s0*3+0];
    float dy = coords[d0*3+1] - coords[s0*3+1];
    float dz = coords[d0*3+2] - coords[s0*3+2];
    lperm[pos] = sqrtf(dx*dx + dy*dy + dz*dz);
}

// ---------------- gathers ----------------

// agg0[i] = sum_{j in nbr(i)} coords[perm[j]]
__global__ void gather_coords(const float* __restrict__ coords,
                              const int* __restrict__ rowoff, const int* __restrict__ perm,
                              float* __restrict__ agg0, int N) {
    int i = blockIdx.x * 256 + threadIdx.x;
    if (i >= N) return;
    float ax = 0.f, ay = 0.f, az = 0.f;
    int b = rowoff[i], t = rowoff[i+1];
    for (int j = b; j < t; ++j) {
        int p = perm[j];
        ax += coords[p*3+0];
        ay += coords[p*3+1];
        az += coords[p*3+2];
    }
    agg0[i*3+0] = ax; agg0[i*3+1] = ay; agg0[i*3+2] = az;
}

// y[i] = (1+eps)*x[i] + sum_{j in nbr(i)} x[perm[j]]  (one wave per node, 2-deep pipe)
__global__ __launch_bounds__(256) void gather_combine(const float* __restrict__ x,
                                                      const int* __restrict__ rowoff,
                                                      const int* __restrict__ perm,
                                                      const float* __restrict__ eps,
                                                      float* __restrict__ y, int N) {
    int node = blockIdx.x * 4 + (threadIdx.x >> 6);
    int lane = threadIdx.x & 63;
    if (node >= N) return;
    float ep = 1.f + *eps;
    const float2* x2 = (const float2*)x;
    int b = rowoff[node], t = rowoff[node+1];
    float2 acc = make_float2(0.f, 0.f);
    int j = b;
    for (; j + 2 <= t; j += 2) {
        int p0 = perm[j], p1 = perm[j+1];
        float2 v0 = x2[(size_t)p0*64 + lane];
        float2 v1 = x2[(size_t)p1*64 + lane];
        acc.x += v0.x + v1.x; acc.y += v0.y + v1.y;
    }
    if (j < t) {
        int p = perm[j];
        float2 v = x2[(size_t)p*64 + lane];
        acc.x += v.x; acc.y += v.y;
    }
    float2 own = x2[(size_t)node*64 + lane];
    acc.x = fmaf(ep, own.x, acc.x);
    acc.y = fmaf(ep, own.y, acc.y);
    ((float2*)y)[(size_t)node*64 + lane] = acc;
}

// ---------------- small kernels ----------------

// t1 = ((1+eps)*coords + agg0) @ W1 + b1   (K=3), accumulate stats
__global__ __launch_bounds__(256) void lin0(const float* __restrict__ coords,
                                            const float* __restrict__ agg0,
                                            const float* __restrict__ W1,
                                            const float* __restrict__ b1,
                                            const float* __restrict__ eps0,
                                            float* __restrict__ t1,
                                            float* __restrict__ stats, int nrows) {
    int col = threadIdx.x & 127, half = threadIdx.x >> 7;
    float w0 = W1[col], w1 = W1[128+col], w2 = W1[256+col], bb = b1[col];
    float ep = 1.f + *eps0;
    float s = 0.f, q = 0.f;
    int r0 = blockIdx.x * 64;
    for (int i = 0; i < 32; ++i) {
        int row = r0 + half + 2*i;
        if (row < nrows) {
            float h0 = fmaf(ep, coords[row*3+0], agg0[row*3+0]);
            float h1 = fmaf(ep, coords[row*3+1], agg0[row*3+1]);
            float h2 = fmaf(ep, coords[row*3+2], agg0[row*3+2]);
            float v = fmaf(h0, w0, fmaf(h1, w1, fmaf(h2, w2, bb)));
            t1[row*128+col] = v;
            s += v; q += v*v;
        }
    }
    __shared__ float red[512];
    red[half*128+col] = s;
    red[256 + half*128+col] = q;
    __syncthreads();
    if (threadIdx.x < 128) {
        atomicAdd(&stats[col],       red[col] + red[128+col]);
        atomicAdd(&stats[128+col],   red[256+col] + red[384+col]);
    }
}

__global__ void bn_fin(const float* __restrict__ stats, const float* __restrict__ g,
                       const float* __restrict__ be, float* __restrict__ sc,
                       float* __restrict__ sh, float inv_count) {
    int c = threadIdx.x;
    float m = stats[c] * inv_count;
    float v = stats[128+c] * inv_count - m*m;
    float a = g[c] * rsqrtf(fmaxf(v, 0.f) + 1e-5f);
    sc[c] = a;
    sh[c] = be[c] - m*a;
}

__global__ void ew_bnrelu(const float* __restrict__ x, const float* __restrict__ sc,
                          const float* __restrict__ sh, float* __restrict__ y, int n4) {
    for (int i = blockIdx.x*blockDim.x + threadIdx.x; i < n4; i += gridDim.x*blockDim.x) {
        int c4 = i & 31;
        float4 v = ((const float4*)x)[i];
        float4 s = ((const float4*)sc)[c4];
        float4 t = ((const float4*)sh)[c4];
        v.x = fmaxf(fmaf(v.x, s.x, t.x), 0.f);
        v.y = fmaxf(fmaf(v.y, s.y, t.y), 0.f);
        v.z = fmaxf(fmaf(v.z, s.z, t.z), 0.f);
        v.w = fmaxf(fmaf(v.w, s.w, t.w), 0.f);
        ((float4*)y)[i] = v;
    }
}

// ---------------- GEMM [N,128] @ [128,128], 64-col half per block ----------------
template<bool IN_BN, bool STATS>
__global__ __launch_bounds__(256, 2) void gemm64(const float* __restrict__ A,
                                                 const float* __restrict__ W,
                                                 const float* __restrict__ bias,
                                                 const float* __restrict__ sc,
                                                 const float* __restrict__ sh,
                                                 float* __restrict__ C,
                                                 float* __restrict__ stats, int nrows) {
    __shared__ float4 sW[128*16];  // [k][c4]
    __shared__ float4 sA[64*32];   // [row][k4^swz]
    const int tid = threadIdx.x;
    const int colBase = blockIdx.y * 64;
    const int cb4 = colBase >> 2;
    {
        const float4* W4 = (const float4*)W;
        for (int i = tid; i < 128*16; i += 256) {
            int k = i >> 4, c4 = i & 15;
            sW[k*16 + c4] = W4[k*32 + cb4 + c4];
        }
    }
    const int tile0 = blockIdx.x * 64;
    {
        const float4* A4 = (const float4*)A;
        #pragma unroll
        for (int i = 0; i < 8; ++i) {
            int flat = tid + 256*i;
            int r = flat >> 5, c4 = flat & 31;
            int row = tile0 + r;
            float4 v = make_float4(0.f, 0.f, 0.f, 0.f);
            if (row < nrows) {
                v = A4[row*32 + c4];
                if (IN_BN) {
                    float4 s = ((const float4*)sc)[c4];
                    float4 t = ((const float4*)sh)[c4];
                    v.x = fmaxf(fmaf(v.x, s.x, t.x), 0.f);
                    v.y = fmaxf(fmaf(v.y, s.y, t.y), 0.f);
                    v.z = fmaxf(fmaf(v.z, s.z, t.z), 0.f);
                    v.w = fmaxf(fmaf(v.w, s.w, t.w), 0.f);
                }
            }
            sA[r*32 + (c4 ^ ((r >> 2) & 3))] = v;
        }
    }
    __syncthreads();
    const int cg = tid & 15;   // 16 groups x 4 cols
    const int rg = tid >> 4;   // 16 groups x 4 rows
    const int swz = rg & 3;
    float acc[4][4];
    #pragma unroll
    for (int r = 0; r < 4; ++r)
        #pragma unroll
        for (int c = 0; c < 4; ++c) acc[r][c] = 0.f;
    #pragma unroll 4
    for (int k4 = 0; k4 < 32; ++k4) {
        float4 w0 = sW[(k4*4+0)*16 + cg];
        float4 w1 = sW[(k4*4+1)*16 + cg];
        float4 w2 = sW[(k4*4+2)*16 + cg];
        float4 w3 = sW[(k4*4+3)*16 + cg];
        #pragma unroll
        for (int r = 0; r < 4; ++r) {
            float4 a = sA[(rg*4+r)*32 + (k4 ^ swz)];
            acc[r][0] = fmaf(a.x, w0.x, fmaf(a.y, w1.x, fmaf(a.z, w2.x, fmaf(a.w, w3.x, acc[r][0]))));
            acc[r][1] = fmaf(a.x, w0.y, fmaf(a.y, w1.y, fmaf(a.z, w2.y, fmaf(a.w, w3.y, acc[r][1]))));
            acc[r][2] = fmaf(a.x, w0.z, fmaf(a.y, w1.z, fmaf(a.z, w2.z, fmaf(a.w, w3.z, acc[r][2]))));
            acc[r][3] = fmaf(a.x, w0.w, fmaf(a.y, w1.w, fmaf(a.z, w2.w, fmaf(a.w, w3.w, acc[r][3]))));
        }
    }
    float4 bv = make_float4(0.f, 0.f, 0.f, 0.f);
    if (bias) bv = ((const float4*)bias)[cb4 + cg];
    float lsum[4] = {0,0,0,0}, lsq[4] = {0,0,0,0};
    #pragma unroll
    for (int r = 0; r < 4; ++r) {
        int row = tile0 + rg*4 + r;
        if (row < nrows) {
            float4 o;
            o.x = acc[r][0] + bv.x; o.y = acc[r][1] + bv.y;
            o.z = acc[r][2] + bv.z; o.w = acc[r][3] + bv.w;
            ((float4*)C)[row*32 + cb4 + cg] = o;
            if (STATS) {
                lsum[0] += o.x; lsq[0] += o.x*o.x;
                lsum[1] += o.y; lsq[1] += o.y*o.y;
                lsum[2] += o.z; lsq[2] += o.z*o.z;
                lsum[3] += o.w; lsq[3] += o.w*o.w;
            }
        }
    }
    if (STATS) {
        __syncthreads();
        float* sf = (float*)sA;
        #pragma unroll
        for (int cc = 0; cc < 4; ++cc) {
            sf[(cg*4+cc)*16 + rg] = lsum[cc];
            sf[1024 + (cg*4+cc)*16 + rg] = lsq[cc];
        }
        __syncthreads();
        if (tid < 64) {
            float s = 0.f, q = 0.f;
            #pragma unroll
            for (int j = 0; j < 16; ++j) { s += sf[tid*16+j]; q += sf[1024+tid*16+j]; }
            atomicAdd(&stats[colBase + tid], s);
            atomicAdd(&stats[128 + colBase + tid], q);
        }
    }
}

// -------- decoder BN stats, node-centric: yb row in regs, gather ya only --------
__global__ __launch_bounds__(256) void csr_stats(const float* __restrict__ ya,
                                                 const float* __restrict__ yb,
                                                 const int* __restrict__ rowoff,
                                                 const int* __restrict__ perm,
                                                 const float* __restrict__ lperm,
                                                 const float* __restrict__ wl,
                                                 const float* __restrict__ b1,
                                                 float* __restrict__ stats, int N, int nspan) {
    int w = blockIdx.x * 4 + (threadIdx.x >> 6);
    int lane = threadIdx.x & 63;
    const float2* ya2 = (const float2*)ya;
    const float2* yb2 = (const float2*)yb;
    float2 wl2 = ((const float2*)wl)[lane];
    float2 b12 = ((const float2*)b1)[lane];
    float2 s = make_float2(0.f, 0.f), q = make_float2(0.f, 0.f);
    int i0 = w * nspan;
    int i1 = i0 + nspan; if (i1 > N) i1 = N;
    for (int i = i0; i < i1; ++i) {
        float2 ybr = yb2[(size_t)i*64 + lane];
        int b = rowoff[i], t = rowoff[i+1];
        for (int j = b; j < t; ++j) {
            int p = perm[j];
            float lv = lperm[j];
            float2 a = ya2[(size_t)p*64 + lane];
            float zx = a.x + ybr.x + fmaf(lv, wl2.x, b12.x);
            float zy = a.y + ybr.y + fmaf(lv, wl2.y, b12.y);
            s.x += zx; s.y += zy;
            q.x += zx*zx; q.y += zy*zy;
        }
    }
    __shared__ float red[1024];
    int wv = threadIdx.x >> 6;
    red[wv*128 + lane*2]       = s.x;
    red[wv*128 + lane*2 + 1]   = s.y;
    red[512 + wv*128 + lane*2]     = q.x;
    red[512 + wv*128 + lane*2 + 1] = q.y;
    __syncthreads();
    if (threadIdx.x < 128) {
        int c = threadIdx.x;
        float ss = red[c] + red[128+c] + red[256+c] + red[384+c];
        float qq = red[512+c] + red[640+c] + red[768+c] + red[896+c];
        atomicAdd(&stats[c], ss);
        atomicAdd(&stats[128+c], qq);
    }
}

// -------- fused decoder (CSR slot order): z -> bnrelu -> @W2+b2 -> relu -> .w3+b3 -> sigmoid --------
__global__ __launch_bounds__(256, 2) void decoder_fused(const float* __restrict__ ya,
                                                        const float* __restrict__ yb,
                                                        const float* __restrict__ lperm,
                                                        const int* __restrict__ perm,
                                                        const int* __restrict__ dperm,
                                                        const int* __restrict__ eperm,
                                                        const float* __restrict__ wl,
                                                        const float* __restrict__ b1,
                                                        const float* __restrict__ sc,
                                                        const float* __restrict__ sh,
                                                        const float* __restrict__ W2,
                                                        const float* __restrict__ b2,
                                                        const float* __restrict__ w3,
                                                        const float* __restrict__ b3p,
                                                        float* __restrict__ out, int E) {
    __shared__ float4 sW[128*16];  // W2 [128][64] = [k][c4]
    __shared__ float4 sA[64*32];   // z tile, swizzled
    const int tid = threadIdx.x;
    {
        const float4* W4 = (const float4*)W2;
        for (int i = tid; i < 128*16; i += 256) sW[i] = W4[i];
    }
    const int tile0 = blockIdx.x * 64;
    {
        #pragma unroll
        for (int i = 0; i < 8; ++i) {
            int flat = tid + 256*i;
            int r = flat >> 5, c4 = flat & 31;
            int row = tile0 + r;
            float4 v = make_float4(0.f, 0.f, 0.f, 0.f);
            if (row < E) {
                int s0 = perm[row], d0 = dperm[row];
                float lv = lperm[row];
                float4 va = ((const float4*)ya)[(size_t)s0*32 + c4];
                float4 vb = ((const float4*)yb)[(size_t)d0*32 + c4];
                float4 wv = ((const float4*)wl)[c4];
                float4 bb = ((const float4*)b1)[c4];
                float4 s4 = ((const float4*)sc)[c4];
                float4 t4 = ((const float4*)sh)[c4];
                v.x = fmaxf(fmaf(va.x + vb.x + fmaf(lv, wv.x, bb.x), s4.x, t4.x), 0.f);
                v.y = fmaxf(fmaf(va.y + vb.y + fmaf(lv, wv.y, bb.y), s4.y, t4.y), 0.f);
                v.z = fmaxf(fmaf(va.z + vb.z + fmaf(lv, wv.z, bb.z), s4.z, t4.z), 0.f);
                v.w = fmaxf(fmaf(va.w + vb.w + fmaf(lv, wv.w, bb.w), s4.w, t4.w), 0.f);
            }
            sA[r*32 + (c4 ^ ((r >> 2) & 3))] = v;
        }
    }
    __syncthreads();
    const int cg = tid & 15;
    const int rg = tid >> 4;
    const int swz = rg & 3;
    float acc[4][4];
    #pragma unroll
    for (int r = 0; r < 4; ++r)
        #pragma unroll
        for (int c = 0; c < 4; ++c) acc[r][c] = 0.f;
    #pragma unroll 4
    for (int k4 = 0; k4 < 32; ++k4) {
        float4 w0 = sW[(k4*4+0)*16 + cg];
        float4 w1 = sW[(k4*4+1)*16 + cg];
        float4 w2 = sW[(k4*4+2)*16 + cg];
        float4 w3v = sW[(k4*4+3)*16 + cg];
        #pragma unroll
        for (int r = 0; r < 4; ++r) {
            float4 a = sA[(rg*4+r)*32 + (k4 ^ swz)];
            acc[r][0] = fmaf(a.x, w0.x, fmaf(a.y, w1.x, fmaf(a.z, w2.x, fmaf(a.w, w3v.x, acc[r][0]))));
            acc[r][1] = fmaf(a.x, w0.y, fmaf(a.y, w1.y, fmaf(a.z, w2.y, fmaf(a.w, w3v.y, acc[r][1]))));
            acc[r][2] = fmaf(a.x, w0.z, fmaf(a.y, w1.z, fmaf(a.z, w2.z, fmaf(a.w, w3v.z, acc[r][2]))));
            acc[r][3] = fmaf(a.x, w0.w, fmaf(a.y, w1.w, fmaf(a.z, w2.w, fmaf(a.w, w3v.w, acc[r][3]))));
        }
    }
    float p[4];
    #pragma unroll
    for (int r = 0; r < 4; ++r) {
        float sum = 0.f;
        #pragma unroll
        for (int cc = 0; cc < 4; ++cc) {
            int col = cg*4 + cc;
            float h2 = fmaxf(acc[r][cc] + b2[col], 0.f);
            sum = fmaf(h2, w3[col], sum);
        }
        p[r] = sum;
    }
    __syncthreads();
    float* sf = (float*)sA;
    #pragma unroll
    for (int r = 0; r < 4; ++r) sf[(rg*4+r)*16 + cg] = p[r];
    __syncthreads();
    if (tid < 64) {
        int row = tile0 + tid;
        if (row < E) {
            float s = b3p[0];
            #pragma unroll
            for (int j = 0; j < 16; ++j) s += sf[tid*16+j];
            out[eperm[row]] = 1.f / (1.f + expf(-s));
        }
    }
}

// ---------------------------------------------------------------------------

extern "C" void kernel_launch(void* const* d_in, const int* in_sizes, int n_in,
                              void* d_out, int out_size, void* d_ws, size_t ws_size,
                              hipStream_t stream) {
    const int N = in_sizes[0] / 3;
    const int E = in_sizes[1] / 2;

    const float* coords = (const float*)d_in[0];
    const int*   ei     = (const int*)d_in[1];
    const int*   esrc = ei;
    const int*   edst = ei + E;
    const float* g0_w1 = (const float*)d_in[2];
    const float* g0_b1 = (const float*)d_in[3];
    const float* g0_g1 = (const float*)d_in[4];
    const float* g0_be1= (const float*)d_in[5];
    const float* g0_w2 = (const float*)d_in[6];
    const float* g0_b2 = (const float*)d_in[7];
    const float* g0_g2 = (const float*)d_in[8];
    const float* g0_be2= (const float*)d_in[9];
    const float* g0_w3 = (const float*)d_in[10];
    const float* g0_b3 = (const float*)d_in[11];
    const float* eps0  = (const float*)d_in[12];
    const float* bn0_g = (const float*)d_in[13];
    const float* bn0_b = (const float*)d_in[14];
    const float* g1_w1 = (const float*)d_in[15];
    const float* g1_b1 = (const float*)d_in[16];
    const float* g1_g1 = (const float*)d_in[17];
    const float* g1_be1= (const float*)d_in[18];
    const float* g1_w2 = (const float*)d_in[19];
    const float* g1_b2 = (const float*)d_in[20];
    const float* g1_g2 = (const float*)d_in[21];
    const float* g1_be2= (const float*)d_in[22];
    const float* g1_w3 = (const float*)d_in[23];
    const float* g1_b3 = (const float*)d_in[24];
    const float* eps1  = (const float*)d_in[25];
    const float* bn1_g = (const float*)d_in[26];
    const float* bn1_b = (const float*)d_in[27];
    const float* d_w1  = (const float*)d_in[28];
    const float* d_b1  = (const float*)d_in[29];
    const float* d_g   = (const float*)d_in[30];
    const float* d_be  = (const float*)d_in[31];
    const float* d_w2  = (const float*)d_in[32];
    const float* d_b2  = (const float*)d_in[33];
    const float* d_w3  = (const float*)d_in[34];
    const float* d_b3  = (const float*)d_in[35];

    float* ws = (float*)d_ws;
    const size_t NF = (size_t)N * 128;
    float* buf0 = ws;
    float* buf1 = ws + NF;
    float* buf2 = ws + 2*NF;
    float* agg0 = ws + 3*NF;                 // N*3
    float* stats= agg0 + (size_t)N*3;        // 7*256
    float* scsh = stats + 7*256;             // 7*256
    float* lperm = scsh + 7*256;             // E (slot order)
    int*   cursor = (int*)(lperm + E);       // N
    int*   rowoff = cursor + N;              // N+1
    int*   perm   = rowoff + N + 1;          // E (src per slot)
    int*   dperm  = perm + E;                // E (dst per slot)
    int*   eperm  = dperm + E;               // E (edge id per slot)

    float* out = (float*)d_out;

    const float* wl = d_w1 + 256*128;   // row 256 of d_w1

    #define STATSK(k) (stats + (k)*256)
    #define SC(k) (scsh + (k)*256)
    #define SH(k) (scsh + (k)*256 + 128)

    const int rowTiles = (N + 63) / 64;
    dim3 gemmGrid(rowTiles, 2);
    const int edgeTiles = (E + 63) / 64;
    const int eBlocks = (E + 255) / 256;
    const float invN = 1.f / (float)N;
    const float invE = 1.f / (float)E;
    const int nWaves = 2048 * 4;
    const int nspan = (N + nWaves - 1) / nWaves;

    // zero BN stat accumulators + CSR cursor
    hipMemsetAsync(stats, 0, 7*256 * sizeof(float), stream);
    hipMemsetAsync(cursor, 0, (size_t)N * sizeof(int), stream);

    // CSR build (by destination) + per-edge length in slot order
    hist_dst<<<eBlocks, 256, 0, stream>>>(edst, cursor, E);
    scan_deg<<<1, 1024, 0, stream>>>(cursor, rowoff, cursor, N);
    fill_csr<<<eBlocks, 256, 0, stream>>>(esrc, edst, coords, cursor, perm, dperm, eperm, lperm, E);

    // layer 0
    gather_coords<<<(N + 255)/256, 256, 0, stream>>>(coords, rowoff, perm, agg0, N);
    lin0<<<rowTiles, 256, 0, stream>>>(coords, agg0, g0_w1, g0_b1, eps0, buf0, STATSK(0), N);
    bn_fin<<<1, 128, 0, stream>>>(STATSK(0), g0_g1, g0_be1, SC(0), SH(0), invN);
    gemm64<true,true><<<gemmGrid, 256, 0, stream>>>(buf0, g0_w2, g0_b2, SC(0), SH(0), buf1, STATSK(1), N);
    bn_fin<<<1, 128, 0, stream>>>(STATSK(1), g0_g2, g0_be2, SC(1), SH(1), invN);
    gemm64<true,true><<<gemmGrid, 256, 0, stream>>>(buf1, g0_w3, g0_b3, SC(1), SH(1), buf2, STATSK(2), N);
    bn_fin<<<1, 128, 0, stream>>>(STATSK(2), bn0_g, bn0_b, SC(2), SH(2), invN);
    ew_bnrelu<<<2048, 256, 0, stream>>>(buf2, SC(2), SH(2), buf0, N*32);      // x1 -> buf0

    // layer 1: h1 = (1+eps1)*x1 + gather(x1)  -> buf1
    gather_combine<<<(N + 3)/4, 256, 0, stream>>>(buf0, rowoff, perm, eps1, buf1, N);
    gemm64<false,true><<<gemmGrid, 256, 0, stream>>>(buf1, g1_w1, g1_b1, nullptr, nullptr, buf2, STATSK(3), N);
    bn_fin<<<1, 128, 0, stream>>>(STATSK(3), g1_g1, g1_be1, SC(3), SH(3), invN);
    gemm64<true,true><<<gemmGrid, 256, 0, stream>>>(buf2, g1_w2, g1_b2, SC(3), SH(3), buf0, STATSK(4), N);
    bn_fin<<<1, 128, 0, stream>>>(STATSK(4), g1_g2, g1_be2, SC(4), SH(4), invN);
    gemm64<true,true><<<gemmGrid, 256, 0, stream>>>(buf0, g1_w3, g1_b3, SC(4), SH(4), buf1, STATSK(5), N);
    bn_fin<<<1, 128, 0, stream>>>(STATSK(5), bn1_g, bn1_b, SC(5), SH(5), invN);
    ew_bnrelu<<<2048, 256, 0, stream>>>(buf1, SC(5), SH(5), buf0, N*32);      // x2 -> buf0

    // decoder: ya = x2@W1[0:128], yb = x2@W1[128:256]
    gemm64<false,false><<<gemmGrid, 256, 0, stream>>>(buf0, d_w1, nullptr, nullptr, nullptr, buf1, nullptr, N);
    gemm64<false,false><<<gemmGrid, 256, 0, stream>>>(buf0, d_w1 + 128*128, nullptr, nullptr, nullptr, buf2, nullptr, N);
    csr_stats<<<2048, 256, 0, stream>>>(buf1, buf2, rowoff, perm, lperm, wl, d_b1, STATSK(6), N, nspan);
    bn_fin<<<1, 128, 0, stream>>>(STATSK(6), d_g, d_be, SC(6), SH(6), invE);
    decoder_fused<<<edgeTiles, 256, 0, stream>>>(buf1, buf2, lperm, perm, dperm, eperm, wl, d_b1,
                                                 SC(6), SH(6), d_w2, d_b2, d_w3, d_b3, out, E);
}

// Round 6
// 1710.149 us; speedup vs baseline: 2.7347x; 1.1992x over previous
//
#include <hip/hip_runtime.h>
#include <hip/hip_bf16.h>
#include <math.h>

// ---------------------------------------------------------------------------
// GIN edge-attribute decoder.
// Round 4 -> 5 (resubmitted; round 5 bench was an infra timeout):
// decoder_fused GEMM (E x128 @ 128x64, 26 GFLOP) moved from fp32 VALU
// (LDS-BW-bound, 46% VALUBusy, 22% occ) to bf16 MFMA
// (mfma_f32_16x16x32_bf16, fp32 accum). LDS halves to 32KB (5 blocks/CU),
// XOR-swizzled bf16 tiles (row-stride 256B would be 16-way conflict).
// Everything else (fp32 GEMM chain, CSR gathers, BN stats) unchanged.
// Decoder trick: concat(x2[s],x2[d],l)@W1 == ya[s]+yb[d]+l*wl.
// ---------------------------------------------------------------------------

typedef __attribute__((ext_vector_type(8))) __bf16 bf16x8;
typedef __attribute__((ext_vector_type(4))) float f32x4;

__device__ __forceinline__ unsigned int pack_bf16(float a, float b) {
    unsigned short ua = __builtin_bit_cast(unsigned short, __float2bfloat16(a));
    unsigned short ub = __builtin_bit_cast(unsigned short, __float2bfloat16(b));
    return (unsigned int)ua | ((unsigned int)ub << 16);
}

// ---------------- CSR build ----------------

__global__ void hist_dst(const int* __restrict__ edst, int* __restrict__ cursor, int E) {
    int e = blockIdx.x * 256 + threadIdx.x;
    if (e < E) atomicAdd(&cursor[edst[e]], 1);
}

__global__ __launch_bounds__(1024) void scan_deg(const int* deg, int* rowoff, int* cursor, int N) {
    __shared__ int sums[1024];
    const int t = threadIdx.x;
    const int chunk = (N + 1023) >> 10;
    int lo = t * chunk, hi = lo + chunk;
    if (lo > N) lo = N;
    if (hi > N) hi = N;
    int s = 0;
    for (int i = lo; i < hi; ++i) s += deg[i];
    sums[t] = s;
    __syncthreads();
    for (int off = 1; off < 1024; off <<= 1) {
        int add = (t >= off) ? sums[t - off] : 0;
        __syncthreads();
        sums[t] += add;
        __syncthreads();
    }
    int run = sums[t] - s;
    for (int i = lo; i < hi; ++i) {
        int d = deg[i];
        rowoff[i] = run;
        cursor[i] = run;
        run += d;
    }
    if (t == 1023) rowoff[N] = sums[1023];
}

__global__ void fill_csr(const int* __restrict__ esrc, const int* __restrict__ edst,
                         const float* __restrict__ coords,
                         int* cursor, int* __restrict__ perm, int* __restrict__ dperm,
                         int* __restrict__ eperm, float* __restrict__ lperm, int E) {
    int e = blockIdx.x * 256 + threadIdx.x;
    if (e >= E) return;
    int s0 = esrc[e], d0 = edst[e];
    int pos = atomicAdd(&cursor[d0], 1);
    perm[pos] = s0;
    dperm[pos] = d0;
    eperm[pos] = e;
    float dx = coords[d0*3+0] - coords[s0*3+0];
    float dy = coords[d0*3+1] - coords[s0*3+1];
    float dz = coords[d0*3+2] - coords[s0*3+2];
    lperm[pos] = sqrtf(dx*dx + dy*dy + dz*dz);
}

// ---------------- gathers ----------------

__global__ void gather_coords(const float* __restrict__ coords,
                              const int* __restrict__ rowoff, const int* __restrict__ perm,
                              float* __restrict__ agg0, int N) {
    int i = blockIdx.x * 256 + threadIdx.x;
    if (i >= N) return;
    float ax = 0.f, ay = 0.f, az = 0.f;
    int b = rowoff[i], t = rowoff[i+1];
    for (int j = b; j < t; ++j) {
        int p = perm[j];
        ax += coords[p*3+0];
        ay += coords[p*3+1];
        az += coords[p*3+2];
    }
    agg0[i*3+0] = ax; agg0[i*3+1] = ay; agg0[i*3+2] = az;
}

__global__ __launch_bounds__(256) void gather_combine(const float* __restrict__ x,
                                                      const int* __restrict__ rowoff,
                                                      const int* __restrict__ perm,
                                                      const float* __restrict__ eps,
                                                      float* __restrict__ y, int N) {
    int node = blockIdx.x * 4 + (threadIdx.x >> 6);
    int lane = threadIdx.x & 63;
    if (node >= N) return;
    float ep = 1.f + *eps;
    const float2* x2 = (const float2*)x;
    int b = rowoff[node], t = rowoff[node+1];
    float2 acc = make_float2(0.f, 0.f);
    int j = b;
    for (; j + 2 <= t; j += 2) {
        int p0 = perm[j], p1 = perm[j+1];
        float2 v0 = x2[(size_t)p0*64 + lane];
        float2 v1 = x2[(size_t)p1*64 + lane];
        acc.x += v0.x + v1.x; acc.y += v0.y + v1.y;
    }
    if (j < t) {
        int p = perm[j];
        float2 v = x2[(size_t)p*64 + lane];
        acc.x += v.x; acc.y += v.y;
    }
    float2 own = x2[(size_t)node*64 + lane];
    acc.x = fmaf(ep, own.x, acc.x);
    acc.y = fmaf(ep, own.y, acc.y);
    ((float2*)y)[(size_t)node*64 + lane] = acc;
}

// ---------------- small kernels ----------------

__global__ __launch_bounds__(256) void lin0(const float* __restrict__ coords,
                                            const float* __restrict__ agg0,
                                            const float* __restrict__ W1,
                                            const float* __restrict__ b1,
                                            const float* __restrict__ eps0,
                                            float* __restrict__ t1,
                                            float* __restrict__ stats, int nrows) {
    int col = threadIdx.x & 127, half = threadIdx.x >> 7;
    float w0 = W1[col], w1 = W1[128+col], w2 = W1[256+col], bb = b1[col];
    float ep = 1.f + *eps0;
    float s = 0.f, q = 0.f;
    int r0 = blockIdx.x * 64;
    for (int i = 0; i < 32; ++i) {
        int row = r0 + half + 2*i;
        if (row < nrows) {
            float h0 = fmaf(ep, coords[row*3+0], agg0[row*3+0]);
            float h1 = fmaf(ep, coords[row*3+1], agg0[row*3+1]);
            float h2 = fmaf(ep, coords[row*3+2], agg0[row*3+2]);
            float v = fmaf(h0, w0, fmaf(h1, w1, fmaf(h2, w2, bb)));
            t1[row*128+col] = v;
            s += v; q += v*v;
        }
    }
    __shared__ float red[512];
    red[half*128+col] = s;
    red[256 + half*128+col] = q;
    __syncthreads();
    if (threadIdx.x < 128) {
        atomicAdd(&stats[col],       red[col] + red[128+col]);
        atomicAdd(&stats[128+col],   red[256+col] + red[384+col]);
    }
}

__global__ void bn_fin(const float* __restrict__ stats, const float* __restrict__ g,
                       const float* __restrict__ be, float* __restrict__ sc,
                       float* __restrict__ sh, float inv_count) {
    int c = threadIdx.x;
    float m = stats[c] * inv_count;
    float v = stats[128+c] * inv_count - m*m;
    float a = g[c] * rsqrtf(fmaxf(v, 0.f) + 1e-5f);
    sc[c] = a;
    sh[c] = be[c] - m*a;
}

__global__ void ew_bnrelu(const float* __restrict__ x, const float* __restrict__ sc,
                          const float* __restrict__ sh, float* __restrict__ y, int n4) {
    for (int i = blockIdx.x*blockDim.x + threadIdx.x; i < n4; i += gridDim.x*blockDim.x) {
        int c4 = i & 31;
        float4 v = ((const float4*)x)[i];
        float4 s = ((const float4*)sc)[c4];
        float4 t = ((const float4*)sh)[c4];
        v.x = fmaxf(fmaf(v.x, s.x, t.x), 0.f);
        v.y = fmaxf(fmaf(v.y, s.y, t.y), 0.f);
        v.z = fmaxf(fmaf(v.z, s.z, t.z), 0.f);
        v.w = fmaxf(fmaf(v.w, s.w, t.w), 0.f);
        ((float4*)y)[i] = v;
    }
}

// W2 [128][64] f32 -> w2t [64 cols][128 k] bf16
__global__ void prep_w2(const float* __restrict__ W2, unsigned short* __restrict__ w2t) {
    int i = blockIdx.x * 256 + threadIdx.x;
    if (i >= 128*64) return;
    int k = i >> 6, c = i & 63;
    w2t[c*128 + k] = __builtin_bit_cast(unsigned short, __float2bfloat16(W2[i]));
}

// ---------------- fp32 GEMM [N,128] @ [128,128], 64-col half per block -------
template<bool IN_BN, bool STATS>
__global__ __launch_bounds__(256, 2) void gemm64(const float* __restrict__ A,
                                                 const float* __restrict__ W,
                                                 const float* __restrict__ bias,
                                                 const float* __restrict__ sc,
                                                 const float* __restrict__ sh,
                                                 float* __restrict__ C,
                                                 float* __restrict__ stats, int nrows) {
    __shared__ float4 sW[128*16];  // [k][c4]
    __shared__ float4 sA[64*32];   // [row][k4^swz]
    const int tid = threadIdx.x;
    const int colBase = blockIdx.y * 64;
    const int cb4 = colBase >> 2;
    {
        const float4* W4 = (const float4*)W;
        for (int i = tid; i < 128*16; i += 256) {
            int k = i >> 4, c4 = i & 15;
            sW[k*16 + c4] = W4[k*32 + cb4 + c4];
        }
    }
    const int tile0 = blockIdx.x * 64;
    {
        const float4* A4 = (const float4*)A;
        #pragma unroll
        for (int i = 0; i < 8; ++i) {
            int flat = tid + 256*i;
            int r = flat >> 5, c4 = flat & 31;
            int row = tile0 + r;
            float4 v = make_float4(0.f, 0.f, 0.f, 0.f);
            if (row < nrows) {
                v = A4[row*32 + c4];
                if (IN_BN) {
                    float4 s = ((const float4*)sc)[c4];
                    float4 t = ((const float4*)sh)[c4];
                    v.x = fmaxf(fmaf(v.x, s.x, t.x), 0.f);
                    v.y = fmaxf(fmaf(v.y, s.y, t.y), 0.f);
                    v.z = fmaxf(fmaf(v.z, s.z, t.z), 0.f);
                    v.w = fmaxf(fmaf(v.w, s.w, t.w), 0.f);
                }
            }
            sA[r*32 + (c4 ^ ((r >> 2) & 3))] = v;
        }
    }
    __syncthreads();
    const int cg = tid & 15;
    const int rg = tid >> 4;
    const int swz = rg & 3;
    float acc[4][4];
    #pragma unroll
    for (int r = 0; r < 4; ++r)
        #pragma unroll
        for (int c = 0; c < 4; ++c) acc[r][c] = 0.f;
    #pragma unroll 4
    for (int k4 = 0; k4 < 32; ++k4) {
        float4 w0 = sW[(k4*4+0)*16 + cg];
        float4 w1 = sW[(k4*4+1)*16 + cg];
        float4 w2 = sW[(k4*4+2)*16 + cg];
        float4 w3 = sW[(k4*4+3)*16 + cg];
        #pragma unroll
        for (int r = 0; r < 4; ++r) {
            float4 a = sA[(rg*4+r)*32 + (k4 ^ swz)];
            acc[r][0] = fmaf(a.x, w0.x, fmaf(a.y, w1.x, fmaf(a.z, w2.x, fmaf(a.w, w3.x, acc[r][0]))));
            acc[r][1] = fmaf(a.x, w0.y, fmaf(a.y, w1.y, fmaf(a.z, w2.y, fmaf(a.w, w3.y, acc[r][1]))));
            acc[r][2] = fmaf(a.x, w0.z, fmaf(a.y, w1.z, fmaf(a.z, w2.z, fmaf(a.w, w3.z, acc[r][2]))));
            acc[r][3] = fmaf(a.x, w0.w, fmaf(a.y, w1.w, fmaf(a.z, w2.w, fmaf(a.w, w3.w, acc[r][3]))));
        }
    }
    float4 bv = make_float4(0.f, 0.f, 0.f, 0.f);
    if (bias) bv = ((const float4*)bias)[cb4 + cg];
    float lsum[4] = {0,0,0,0}, lsq[4] = {0,0,0,0};
    #pragma unroll
    for (int r = 0; r < 4; ++r) {
        int row = tile0 + rg*4 + r;
        if (row < nrows) {
            float4 o;
            o.x = acc[r][0] + bv.x; o.y = acc[r][1] + bv.y;
            o.z = acc[r][2] + bv.z; o.w = acc[r][3] + bv.w;
            ((float4*)C)[row*32 + cb4 + cg] = o;
            if (STATS) {
                lsum[0] += o.x; lsq[0] += o.x*o.x;
                lsum[1] += o.y; lsq[1] += o.y*o.y;
                lsum[2] += o.z; lsq[2] += o.z*o.z;
                lsum[3] += o.w; lsq[3] += o.w*o.w;
            }
        }
    }
    if (STATS) {
        __syncthreads();
        float* sf = (float*)sA;
        #pragma unroll
        for (int cc = 0; cc < 4; ++cc) {
            sf[(cg*4+cc)*16 + rg] = lsum[cc];
            sf[1024 + (cg*4+cc)*16 + rg] = lsq[cc];
        }
        __syncthreads();
        if (tid < 64) {
            float s = 0.f, q = 0.f;
            #pragma unroll
            for (int j = 0; j < 16; ++j) { s += sf[tid*16+j]; q += sf[1024+tid*16+j]; }
            atomicAdd(&stats[colBase + tid], s);
            atomicAdd(&stats[128 + colBase + tid], q);
        }
    }
}

// -------- decoder BN stats, node-centric: yb row in regs, gather ya only -----
__global__ __launch_bounds__(256) void csr_stats(const float* __restrict__ ya,
                                                 const float* __restrict__ yb,
                                                 const int* __restrict__ rowoff,
                                                 const int* __restrict__ perm,
                                                 const float* __restrict__ lperm,
                                                 const float* __restrict__ wl,
                                                 const float* __restrict__ b1,
                                                 float* __restrict__ stats, int N, int nspan) {
    int w = blockIdx.x * 4 + (threadIdx.x >> 6);
    int lane = threadIdx.x & 63;
    const float2* ya2 = (const float2*)ya;
    const float2* yb2 = (const float2*)yb;
    float2 wl2 = ((const float2*)wl)[lane];
    float2 b12 = ((const float2*)b1)[lane];
    float2 s = make_float2(0.f, 0.f), q = make_float2(0.f, 0.f);
    int i0 = w * nspan;
    int i1 = i0 + nspan; if (i1 > N) i1 = N;
    for (int i = i0; i < i1; ++i) {
        float2 ybr = yb2[(size_t)i*64 + lane];
        int b = rowoff[i], t = rowoff[i+1];
        for (int j = b; j < t; ++j) {
            int p = perm[j];
            float lv = lperm[j];
            float2 a = ya2[(size_t)p*64 + lane];
            float zx = a.x + ybr.x + fmaf(lv, wl2.x, b12.x);
            float zy = a.y + ybr.y + fmaf(lv, wl2.y, b12.y);
            s.x += zx; s.y += zy;
            q.x += zx*zx; q.y += zy*zy;
        }
    }
    __shared__ float red[1024];
    int wv = threadIdx.x >> 6;
    red[wv*128 + lane*2]       = s.x;
    red[wv*128 + lane*2 + 1]   = s.y;
    red[512 + wv*128 + lane*2]     = q.x;
    red[512 + wv*128 + lane*2 + 1] = q.y;
    __syncthreads();
    if (threadIdx.x < 128) {
        int c = threadIdx.x;
        float ss = red[c] + red[128+c] + red[256+c] + red[384+c];
        float qq = red[512+c] + red[640+c] + red[768+c] + red[896+c];
        atomicAdd(&stats[c], ss);
        atomicAdd(&stats[128+c], qq);
    }
}

// -------- fused decoder (CSR slot order), bf16 MFMA GEMM --------------------
// tile: 64 edges x 64 cols, K=128. LDS: sA z-tile [64][128] bf16 (16KB) +
// sB W2^T [64 cols][128 k] bf16 (16KB), both XOR-swizzled byte^=(row&7)<<4.
// 4 waves: wave w owns rows 16w..16w+15; 4 col-tiles x 4 K-steps = 16 MFMA.
__global__ __launch_bounds__(256) void decoder_fused(const float* __restrict__ ya,
                                                     const float* __restrict__ yb,
                                                     const float* __restrict__ lperm,
                                                     const int* __restrict__ perm,
                                                     const int* __restrict__ dperm,
                                                     const int* __restrict__ eperm,
                                                     const float* __restrict__ wl,
                                                     const float* __restrict__ b1,
                                                     const float* __restrict__ sc,
                                                     const float* __restrict__ sh,
                                                     const unsigned short* __restrict__ w2t,
                                                     const float* __restrict__ b2,
                                                     const float* __restrict__ w3,
                                                     const float* __restrict__ b3p,
                                                     float* __restrict__ out, int E) {
    __shared__ int4 sAB[2048];           // 32KB: [0,16K)=sA, [16K,32K)=sB
    char* sA = (char*)sAB;
    char* sB = (char*)sAB + 16384;
    const int tid = threadIdx.x;
    const int tile0 = blockIdx.x * 64;

    // stage sB: w2t [64][128] bf16 = 1024 x 16B slots -> swizzled LDS
    {
        const int4* src = (const int4*)w2t;
        #pragma unroll
        for (int ii = 0; ii < 4; ++ii) {
            int s = tid + 256*ii;            // 16B slot id
            int col = s >> 4, k16 = s & 15;  // 16B = 8 bf16 k's
            int byte = ((col << 8) + (k16 << 4)) ^ ((col & 7) << 4);
            *(int4*)(sB + byte) = src[s];
        }
    }
    // stage sA: z = bnrelu(ya[s]+yb[d]+l*wl+b1) -> bf16, swizzled
    {
        const int c4 = tid & 31;   // fixed per thread: k-chunk (4 floats)
        const int rb = tid >> 5;
        float4 wv = ((const float4*)wl)[c4];
        float4 bb = ((const float4*)b1)[c4];
        float4 s4 = ((const float4*)sc)[c4];
        float4 t4 = ((const float4*)sh)[c4];
        #pragma unroll
        for (int i = 0; i < 8; ++i) {
            int r = rb + 8*i;
            int row = tile0 + r;
            float4 v = make_float4(0.f, 0.f, 0.f, 0.f);
            if (row < E) {
                int s0 = perm[row], d0 = dperm[row];
                float lv = lperm[row];
                float4 va = ((const float4*)ya)[(size_t)s0*32 + c4];
                float4 vb = ((const float4*)yb)[(size_t)d0*32 + c4];
                v.x = fmaxf(fmaf(va.x + vb.x + fmaf(lv, wv.x, bb.x), s4.x, t4.x), 0.f);
                v.y = fmaxf(fmaf(va.y + vb.y + fmaf(lv, wv.y, bb.y), s4.y, t4.y), 0.f);
                v.z = fmaxf(fmaf(va.z + vb.z + fmaf(lv, wv.z, bb.z), s4.z, t4.z), 0.f);
                v.w = fmaxf(fmaf(va.w + vb.w + fmaf(lv, wv.w, bb.w), s4.w, t4.w), 0.f);
            }
            uint2 pk;
            pk.x = pack_bf16(v.x, v.y);
            pk.y = pack_bf16(v.z, v.w);
            int byte = ((r << 8) + (c4 << 3)) ^ ((r & 7) << 4);
            *(uint2*)(sA + byte) = pk;
        }
    }
    __syncthreads();

    const int l = tid & 63;
    const int w = tid >> 6;
    const int arow = (w << 4) + (l & 15);
    const int kbase = (l >> 4) << 3;       // 8*(l/16)
    f32x4 accv[4];
    #pragma unroll
    for (int c = 0; c < 4; ++c) accv[c] = (f32x4){0.f, 0.f, 0.f, 0.f};

    #pragma unroll
    for (int t = 0; t < 4; ++t) {
        int k0 = t*32 + kbase;             // k index
        int abyte = ((arow << 8) + (k0 << 1)) ^ ((arow & 7) << 4);
        bf16x8 af = __builtin_bit_cast(bf16x8, *(const int4*)(sA + abyte));
        #pragma unroll
        for (int c = 0; c < 4; ++c) {
            int bcol = (c << 4) + (l & 15);
            int bbyte = ((bcol << 8) + (k0 << 1)) ^ ((bcol & 7) << 4);
            bf16x8 bf = __builtin_bit_cast(bf16x8, *(const int4*)(sB + bbyte));
            accv[c] = __builtin_amdgcn_mfma_f32_16x16x32_bf16(af, bf, accv[c], 0, 0, 0);
        }
    }

    // epilogue: h2 = relu(acc + b2[col]); p_row = sum_col h2*w3[col]
    float p0 = 0.f, p1 = 0.f, p2 = 0.f, p3 = 0.f;
    #pragma unroll
    for (int c = 0; c < 4; ++c) {
        int col = (c << 4) + (l & 15);
        float b2c = b2[col], w3c = w3[col];
        f32x4 a = accv[c];
        p0 = fmaf(fmaxf(a[0] + b2c, 0.f), w3c, p0);
        p1 = fmaf(fmaxf(a[1] + b2c, 0.f), w3c, p1);
        p2 = fmaf(fmaxf(a[2] + b2c, 0.f), w3c, p2);
        p3 = fmaf(fmaxf(a[3] + b2c, 0.f), w3c, p3);
    }
    #pragma unroll
    for (int m = 1; m < 16; m <<= 1) {
        p0 += __shfl_xor(p0, m, 64);
        p1 += __shfl_xor(p1, m, 64);
        p2 += __shfl_xor(p2, m, 64);
        p3 += __shfl_xor(p3, m, 64);
    }
    if ((l & 15) == 0) {
        float b3v = b3p[0];
        int rbase = tile0 + (w << 4) + ((l >> 4) << 2);  // D row = (lane>>4)*4 + reg
        float pj[4] = {p0, p1, p2, p3};
        #pragma unroll
        for (int j = 0; j < 4; ++j) {
            int row = rbase + j;
            if (row < E) out[eperm[row]] = 1.f / (1.f + expf(-(pj[j] + b3v)));
        }
    }
}

// ---------------------------------------------------------------------------

extern "C" void kernel_launch(void* const* d_in, const int* in_sizes, int n_in,
                              void* d_out, int out_size, void* d_ws, size_t ws_size,
                              hipStream_t stream) {
    const int N = in_sizes[0] / 3;
    const int E = in_sizes[1] / 2;

    const float* coords = (const float*)d_in[0];
    const int*   ei     = (const int*)d_in[1];
    const int*   esrc = ei;
    const int*   edst = ei + E;
    const float* g0_w1 = (const float*)d_in[2];
    const float* g0_b1 = (const float*)d_in[3];
    const float* g0_g1 = (const float*)d_in[4];
    const float* g0_be1= (const float*)d_in[5];
    const float* g0_w2 = (const float*)d_in[6];
    const float* g0_b2 = (const float*)d_in[7];
    const float* g0_g2 = (const float*)d_in[8];
    const float* g0_be2= (const float*)d_in[9];
    const float* g0_w3 = (const float*)d_in[10];
    const float* g0_b3 = (const float*)d_in[11];
    const float* eps0  = (const float*)d_in[12];
    const float* bn0_g = (const float*)d_in[13];
    const float* bn0_b = (const float*)d_in[14];
    const float* g1_w1 = (const float*)d_in[15];
    const float* g1_b1 = (const float*)d_in[16];
    const float* g1_g1 = (const float*)d_in[17];
    const float* g1_be1= (const float*)d_in[18];
    const float* g1_w2 = (const float*)d_in[19];
    const float* g1_b2 = (const float*)d_in[20];
    const float* g1_g2 = (const float*)d_in[21];
    const float* g1_be2= (const float*)d_in[22];
    const float* g1_w3 = (const float*)d_in[23];
    const float* g1_b3 = (const float*)d_in[24];
    const float* eps1  = (const float*)d_in[25];
    const float* bn1_g = (const float*)d_in[26];
    const float* bn1_b = (const float*)d_in[27];
    const float* d_w1  = (const float*)d_in[28];
    const float* d_b1  = (const float*)d_in[29];
    const float* d_g   = (const float*)d_in[30];
    const float* d_be  = (const float*)d_in[31];
    const float* d_w2  = (const float*)d_in[32];
    const float* d_b2  = (const float*)d_in[33];
    const float* d_w3  = (const float*)d_in[34];
    const float* d_b3  = (const float*)d_in[35];

    float* ws = (float*)d_ws;
    const size_t NF = (size_t)N * 128;
    float* buf0 = ws;
    float* buf1 = ws + NF;
    float* buf2 = ws + 2*NF;
    float* agg0 = ws + 3*NF;                 // N*3
    float* stats= agg0 + (size_t)N*3;        // 7*256
    float* scsh = stats + 7*256;             // 7*256
    float* lperm = scsh + 7*256;             // E (slot order)
    int*   cursor = (int*)(lperm + E);       // N
    int*   rowoff = cursor + N;              // N+1
    int*   perm   = rowoff + N + 1;          // E (src per slot)
    int*   dperm  = perm + E;                // E (dst per slot)
    int*   eperm  = dperm + E;               // E (edge id per slot)
    unsigned short* w2t = (unsigned short*)(eperm + E);  // 128*64 bf16

    float* out = (float*)d_out;

    const float* wl = d_w1 + 256*128;   // row 256 of d_w1

    #define STATSK(k) (stats + (k)*256)
    #define SC(k) (scsh + (k)*256)
    #define SH(k) (scsh + (k)*256 + 128)

    const int rowTiles = (N + 63) / 64;
    dim3 gemmGrid(rowTiles, 2);
    const int edgeTiles = (E + 63) / 64;
    const int eBlocks = (E + 255) / 256;
    const float invN = 1.f / (float)N;
    const float invE = 1.f / (float)E;
    const int nWaves = 2048 * 4;
    const int nspan = (N + nWaves - 1) / nWaves;

    // zero BN stat accumulators + CSR cursor
    hipMemsetAsync(stats, 0, 7*256 * sizeof(float), stream);
    hipMemsetAsync(cursor, 0, (size_t)N * sizeof(int), stream);

    // CSR build (by destination) + per-edge length in slot order
    hist_dst<<<eBlocks, 256, 0, stream>>>(edst, cursor, E);
    scan_deg<<<1, 1024, 0, stream>>>(cursor, rowoff, cursor, N);
    fill_csr<<<eBlocks, 256, 0, stream>>>(esrc, edst, coords, cursor, perm, dperm, eperm, lperm, E);
    prep_w2<<<32, 256, 0, stream>>>(d_w2, w2t);

    // layer 0
    gather_coords<<<(N + 255)/256, 256, 0, stream>>>(coords, rowoff, perm, agg0, N);
    lin0<<<rowTiles, 256, 0, stream>>>(coords, agg0, g0_w1, g0_b1, eps0, buf0, STATSK(0), N);
    bn_fin<<<1, 128, 0, stream>>>(STATSK(0), g0_g1, g0_be1, SC(0), SH(0), invN);
    gemm64<true,true><<<gemmGrid, 256, 0, stream>>>(buf0, g0_w2, g0_b2, SC(0), SH(0), buf1, STATSK(1), N);
    bn_fin<<<1, 128, 0, stream>>>(STATSK(1), g0_g2, g0_be2, SC(1), SH(1), invN);
    gemm64<true,true><<<gemmGrid, 256, 0, stream>>>(buf1, g0_w3, g0_b3, SC(1), SH(1), buf2, STATSK(2), N);
    bn_fin<<<1, 128, 0, stream>>>(STATSK(2), bn0_g, bn0_b, SC(2), SH(2), invN);
    ew_bnrelu<<<2048, 256, 0, stream>>>(buf2, SC(2), SH(2), buf0, N*32);      // x1 -> buf0

    // layer 1: h1 = (1+eps1)*x1 + gather(x1)  -> buf1
    gather_combine<<<(N + 3)/4, 256, 0, stream>>>(buf0, rowoff, perm, eps1, buf1, N);
    gemm64<false,true><<<gemmGrid, 256, 0, stream>>>(buf1, g1_w1, g1_b1, nullptr, nullptr, buf2, STATSK(3), N);
    bn_fin<<<1, 128, 0, stream>>>(STATSK(3), g1_g1, g1_be1, SC(3), SH(3), invN);
    gemm64<true,true><<<gemmGrid, 256, 0, stream>>>(buf2, g1_w2, g1_b2, SC(3), SH(3), buf0, STATSK(4), N);
    bn_fin<<<1, 128, 0, stream>>>(STATSK(4), g1_g2, g1_be2, SC(4), SH(4), invN);
    gemm64<true,true><<<gemmGrid, 256, 0, stream>>>(buf0, g1_w3, g1_b3, SC(4), SH(4), buf1, STATSK(5), N);
    bn_fin<<<1, 128, 0, stream>>>(STATSK(5), bn1_g, bn1_b, SC(5), SH(5), invN);
    ew_bnrelu<<<2048, 256, 0, stream>>>(buf1, SC(5), SH(5), buf0, N*32);      // x2 -> buf0

    // decoder: ya = x2@W1[0:128], yb = x2@W1[128:256]
    gemm64<false,false><<<gemmGrid, 256, 0, stream>>>(buf0, d_w1, nullptr, nullptr, nullptr, buf1, nullptr, N);
    gemm64<false,false><<<gemmGrid, 256, 0, stream>>>(buf0, d_w1 + 128*128, nullptr, nullptr, nullptr, buf2, nullptr, N);
    csr_stats<<<2048, 256, 0, stream>>>(buf1, buf2, rowoff, perm, lperm, wl, d_b1, STATSK(6), N, nspan);
    bn_fin<<<1, 128, 0, stream>>>(STATSK(6), d_g, d_be, SC(6), SH(6), invE);
    decoder_fused<<<edgeTiles, 256, 0, stream>>>(buf1, buf2, lperm, perm, dperm, eperm, wl, d_b1,
                                                 SC(6), SH(6), w2t, d_b2, d_w3, d_b3, out, E);
}

// Round 7
// 1537.354 us; speedup vs baseline: 3.0421x; 1.1124x over previous
//
#include <hip/hip_runtime.h>
#include <hip/hip_bf16.h>
#include <math.h>

// ---------------------------------------------------------------------------
// GIN edge-attribute decoder.
// Round 6 -> 7: all seven node GEMMs ([N,128]@[128,128] and the two ya/yb
// [N,128]@[128,128(half of d_w1)]) moved from fp32 VALU to the HW-validated
// bf16 MFMA tile (64 rows x 128 cols, fp32 accum, XOR-swizzled LDS), weights
// pre-transposed to bf16 [col][k]. Both ew_bnrelu passes eliminated: x1's
// BN+ReLU folds into gather_combine (per gathered row), x2's into the ya/yb
// GEMM staging (IN_BN). Round-6 evidence: absmax identical fp32 vs bf16-MFMA
// (floor is BN var cancellation), so bf16 GEMM error is below the floor.
// Decoder trick: concat(x2[s],x2[d],l)@W1 == ya[s]+yb[d]+l*wl.
// ---------------------------------------------------------------------------

typedef __attribute__((ext_vector_type(8))) __bf16 bf16x8;
typedef __attribute__((ext_vector_type(4))) float f32x4;

__device__ __forceinline__ unsigned int pack_bf16(float a, float b) {
    unsigned short ua = __builtin_bit_cast(unsigned short, __float2bfloat16(a));
    unsigned short ub = __builtin_bit_cast(unsigned short, __float2bfloat16(b));
    return (unsigned int)ua | ((unsigned int)ub << 16);
}

// ---------------- CSR build ----------------

__global__ void hist_dst(const int* __restrict__ edst, int* __restrict__ cursor, int E) {
    int e = blockIdx.x * 256 + threadIdx.x;
    if (e < E) atomicAdd(&cursor[edst[e]], 1);
}

__global__ __launch_bounds__(1024) void scan_deg(const int* deg, int* rowoff, int* cursor, int N) {
    __shared__ int sums[1024];
    const int t = threadIdx.x;
    const int chunk = (N + 1023) >> 10;
    int lo = t * chunk, hi = lo + chunk;
    if (lo > N) lo = N;
    if (hi > N) hi = N;
    int s = 0;
    for (int i = lo; i < hi; ++i) s += deg[i];
    sums[t] = s;
    __syncthreads();
    for (int off = 1; off < 1024; off <<= 1) {
        int add = (t >= off) ? sums[t - off] : 0;
        __syncthreads();
        sums[t] += add;
        __syncthreads();
    }
    int run = sums[t] - s;
    for (int i = lo; i < hi; ++i) {
        int d = deg[i];
        rowoff[i] = run;
        cursor[i] = run;
        run += d;
    }
    if (t == 1023) rowoff[N] = sums[1023];
}

__global__ void fill_csr(const int* __restrict__ esrc, const int* __restrict__ edst,
                         const float* __restrict__ coords,
                         int* cursor, int* __restrict__ perm, int* __restrict__ dperm,
                         int* __restrict__ eperm, float* __restrict__ lperm, int E) {
    int e = blockIdx.x * 256 + threadIdx.x;
    if (e >= E) return;
    int s0 = esrc[e], d0 = edst[e];
    int pos = atomicAdd(&cursor[d0], 1);
    perm[pos] = s0;
    dperm[pos] = d0;
    eperm[pos] = e;
    float dx = coords[d0*3+0] - coords[s0*3+0];
    float dy = coords[d0*3+1] - coords[s0*3+1];
    float dz = coords[d0*3+2] - coords[s0*3+2];
    lperm[pos] = sqrtf(dx*dx + dy*dy + dz*dz);
}

// ---------------- gathers ----------------

__global__ void gather_coords(const float* __restrict__ coords,
                              const int* __restrict__ rowoff, const int* __restrict__ perm,
                              float* __restrict__ agg0, int N) {
    int i = blockIdx.x * 256 + threadIdx.x;
    if (i >= N) return;
    float ax = 0.f, ay = 0.f, az = 0.f;
    int b = rowoff[i], t = rowoff[i+1];
    for (int j = b; j < t; ++j) {
        int p = perm[j];
        ax += coords[p*3+0];
        ay += coords[p*3+1];
        az += coords[p*3+2];
    }
    agg0[i*3+0] = ax; agg0[i*3+1] = ay; agg0[i*3+2] = az;
}

// y[i] = (1+eps)*bnrelu(x[i]) + sum_j bnrelu(x[perm[j]])  (BN folded in)
__global__ __launch_bounds__(256) void gather_combine_bn(const float* __restrict__ x,
                                                         const int* __restrict__ rowoff,
                                                         const int* __restrict__ perm,
                                                         const float* __restrict__ sc,
                                                         const float* __restrict__ sh,
                                                         const float* __restrict__ eps,
                                                         float* __restrict__ y, int N) {
    int node = blockIdx.x * 4 + (threadIdx.x >> 6);
    int lane = threadIdx.x & 63;
    if (node >= N) return;
    float ep = 1.f + *eps;
    const float2* x2 = (const float2*)x;
    float2 scv = ((const float2*)sc)[lane];
    float2 shv = ((const float2*)sh)[lane];
    int b = rowoff[node], t = rowoff[node+1];
    float2 acc = make_float2(0.f, 0.f);
    int j = b;
    for (; j + 2 <= t; j += 2) {
        int p0 = perm[j], p1 = perm[j+1];
        float2 v0 = x2[(size_t)p0*64 + lane];
        float2 v1 = x2[(size_t)p1*64 + lane];
        acc.x += fmaxf(fmaf(v0.x, scv.x, shv.x), 0.f) + fmaxf(fmaf(v1.x, scv.x, shv.x), 0.f);
        acc.y += fmaxf(fmaf(v0.y, scv.y, shv.y), 0.f) + fmaxf(fmaf(v1.y, scv.y, shv.y), 0.f);
    }
    if (j < t) {
        int p = perm[j];
        float2 v = x2[(size_t)p*64 + lane];
        acc.x += fmaxf(fmaf(v.x, scv.x, shv.x), 0.f);
        acc.y += fmaxf(fmaf(v.y, scv.y, shv.y), 0.f);
    }
    float2 own = x2[(size_t)node*64 + lane];
    acc.x = fmaf(ep, fmaxf(fmaf(own.x, scv.x, shv.x), 0.f), acc.x);
    acc.y = fmaf(ep, fmaxf(fmaf(own.y, scv.y, shv.y), 0.f), acc.y);
    ((float2*)y)[(size_t)node*64 + lane] = acc;
}

// ---------------- small kernels ----------------

__global__ __launch_bounds__(256) void lin0(const float* __restrict__ coords,
                                            const float* __restrict__ agg0,
                                            const float* __restrict__ W1,
                                            const float* __restrict__ b1,
                                            const float* __restrict__ eps0,
                                            float* __restrict__ t1,
                                            float* __restrict__ stats, int nrows) {
    int col = threadIdx.x & 127, half = threadIdx.x >> 7;
    float w0 = W1[col], w1 = W1[128+col], w2 = W1[256+col], bb = b1[col];
    float ep = 1.f + *eps0;
    float s = 0.f, q = 0.f;
    int r0 = blockIdx.x * 64;
    for (int i = 0; i < 32; ++i) {
        int row = r0 + half + 2*i;
        if (row < nrows) {
            float h0 = fmaf(ep, coords[row*3+0], agg0[row*3+0]);
            float h1 = fmaf(ep, coords[row*3+1], agg0[row*3+1]);
            float h2 = fmaf(ep, coords[row*3+2], agg0[row*3+2]);
            float v = fmaf(h0, w0, fmaf(h1, w1, fmaf(h2, w2, bb)));
            t1[row*128+col] = v;
            s += v; q += v*v;
        }
    }
    __shared__ float red[512];
    red[half*128+col] = s;
    red[256 + half*128+col] = q;
    __syncthreads();
    if (threadIdx.x < 128) {
        atomicAdd(&stats[col],       red[col] + red[128+col]);
        atomicAdd(&stats[128+col],   red[256+col] + red[384+col]);
    }
}

__global__ void bn_fin(const float* __restrict__ stats, const float* __restrict__ g,
                       const float* __restrict__ be, float* __restrict__ sc,
                       float* __restrict__ sh, float inv_count) {
    int c = threadIdx.x;
    float m = stats[c] * inv_count;
    float v = stats[128+c] * inv_count - m*m;
    float a = g[c] * rsqrtf(fmaxf(v, 0.f) + 1e-5f);
    sc[c] = a;
    sh[c] = be[c] - m*a;
}

// W2 [128][64] f32 -> w2t [64 cols][128 k] bf16 (decoder)
__global__ void prep_w2(const float* __restrict__ W2, unsigned short* __restrict__ w2t) {
    int i = blockIdx.x * 256 + threadIdx.x;
    if (i >= 128*64) return;
    int k = i >> 6, c = i & 63;
    w2t[c*128 + k] = __builtin_bit_cast(unsigned short, __float2bfloat16(W2[i]));
}

// 7 node-GEMM weights [128][128] f32 -> [col][k] bf16, one matrix per blockIdx.y
__global__ void prep_wT(const float* __restrict__ w0, const float* __restrict__ w1,
                        const float* __restrict__ w2, const float* __restrict__ w3,
                        const float* __restrict__ w4, const float* __restrict__ w5,
                        const float* __restrict__ w6, unsigned short* __restrict__ dst) {
    int m = blockIdx.y;
    const float* src = (m==0)?w0:(m==1)?w1:(m==2)?w2:(m==3)?w3:(m==4)?w4:(m==5)?w5:w6;
    int i = blockIdx.x * 256 + threadIdx.x;   // 16384 elements
    int k = i >> 7, c = i & 127;
    dst[m*16384 + c*128 + k] =
        __builtin_bit_cast(unsigned short, __float2bfloat16(src[i]));
}

// ---------------- bf16 MFMA node GEMM: [N,128] @ [128,128] ------------------
// tile 64 rows x 128 cols, K=128. LDS: sA [64][128]bf16 16KB + sB [128][128]
// bf16 32KB + 4KB stats reduce = 52KB -> 3 blocks/CU. 4 waves; wave w owns
// rows 16w..16w+15; 8 col-tiles x 4 K-steps = 32 MFMA/wave.
template<bool IN_BN, bool STATS>
__global__ __launch_bounds__(256) void gemm_mfma(const float* __restrict__ A,
                                                 const unsigned short* __restrict__ wT,
                                                 const float* __restrict__ bias,
                                                 const float* __restrict__ sc,
                                                 const float* __restrict__ sh,
                                                 float* __restrict__ C,
                                                 float* __restrict__ stats, int nrows) {
    __shared__ int4 sAi[1024];           // 16KB
    __shared__ int4 sBi[2048];           // 32KB
    __shared__ float sred[2][4][128];    // 4KB
    char* sA = (char*)sAi;
    char* sB = (char*)sBi;
    const int tid = threadIdx.x;
    const int tile0 = blockIdx.x * 64;

    // stage sB: wT [128 col][128 k] bf16 = 2048 x 16B slots -> swizzled
    {
        const int4* src = (const int4*)wT;
        #pragma unroll
        for (int ii = 0; ii < 8; ++ii) {
            int s = tid + 256*ii;
            int col = s >> 4, k16 = s & 15;
            int byte = ((col << 8) + (k16 << 4)) ^ ((col & 7) << 4);
            *(int4*)(sB + byte) = src[s];
        }
    }
    // stage sA: fp32 rows (+optional BN/ReLU) -> bf16, swizzled
    {
        const int c4 = tid & 31;
        const int rb = tid >> 5;
        float4 s4, t4;
        if (IN_BN) {
            s4 = ((const float4*)sc)[c4];
            t4 = ((const float4*)sh)[c4];
        }
        const float4* A4 = (const float4*)A;
        #pragma unroll
        for (int i = 0; i < 8; ++i) {
            int r = rb + 8*i;
            int row = tile0 + r;
            float4 v = make_float4(0.f, 0.f, 0.f, 0.f);
            if (row < nrows) {
                v = A4[(size_t)row*32 + c4];
                if (IN_BN) {
                    v.x = fmaxf(fmaf(v.x, s4.x, t4.x), 0.f);
                    v.y = fmaxf(fmaf(v.y, s4.y, t4.y), 0.f);
                    v.z = fmaxf(fmaf(v.z, s4.z, t4.z), 0.f);
                    v.w = fmaxf(fmaf(v.w, s4.w, t4.w), 0.f);
                }
            }
            uint2 pk;
            pk.x = pack_bf16(v.x, v.y);
            pk.y = pack_bf16(v.z, v.w);
            int byte = ((r << 8) + (c4 << 3)) ^ ((r & 7) << 4);
            *(uint2*)(sA + byte) = pk;
        }
    }
    __syncthreads();

    const int l = tid & 63;
    const int w = tid >> 6;
    const int arow = (w << 4) + (l & 15);
    const int kbase = (l >> 4) << 3;
    f32x4 accv[8];
    #pragma unroll
    for (int c = 0; c < 8; ++c) accv[c] = (f32x4){0.f, 0.f, 0.f, 0.f};

    #pragma unroll
    for (int t = 0; t < 4; ++t) {
        int k0 = t*32 + kbase;
        int abyte = ((arow << 8) + (k0 << 1)) ^ ((arow & 7) << 4);
        bf16x8 af = __builtin_bit_cast(bf16x8, *(const int4*)(sA + abyte));
        #pragma unroll
        for (int c = 0; c < 8; ++c) {
            int bcol = (c << 4) + (l & 15);
            int bbyte = ((bcol << 8) + (k0 << 1)) ^ ((bcol & 7) << 4);
            bf16x8 bf = __builtin_bit_cast(bf16x8, *(const int4*)(sB + bbyte));
            accv[c] = __builtin_amdgcn_mfma_f32_16x16x32_bf16(af, bf, accv[c], 0, 0, 0);
        }
    }

    // epilogue: bias add, store, optional column stats
    const int rj = (l >> 4) << 2;
    float lsum[8], lsq[8];
    #pragma unroll
    for (int c = 0; c < 8; ++c) {
        int col = (c << 4) + (l & 15);
        float bv = bias ? bias[col] : 0.f;
        f32x4 a = accv[c];
        float s = 0.f, q = 0.f;
        #pragma unroll
        for (int j = 0; j < 4; ++j) {
            int row = tile0 + (w << 4) + rj + j;
            float o = a[j] + bv;
            if (row < nrows) {
                C[(size_t)row*128 + col] = o;
                if (STATS) { s += o; q += o*o; }
            }
        }
        lsum[c] = s; lsq[c] = q;
    }
    if (STATS) {
        #pragma unroll
        for (int c = 0; c < 8; ++c) {
            lsum[c] += __shfl_xor(lsum[c], 16, 64);
            lsum[c] += __shfl_xor(lsum[c], 32, 64);
            lsq[c]  += __shfl_xor(lsq[c], 16, 64);
            lsq[c]  += __shfl_xor(lsq[c], 32, 64);
        }
        if ((l >> 4) == 0) {
            #pragma unroll
            for (int c = 0; c < 8; ++c) {
                int col = (c << 4) + l;
                sred[0][w][col] = lsum[c];
                sred[1][w][col] = lsq[c];
            }
        }
        __syncthreads();
        if (tid < 128) {
            float s = sred[0][0][tid] + sred[0][1][tid] + sred[0][2][tid] + sred[0][3][tid];
            float q = sred[1][0][tid] + sred[1][1][tid] + sred[1][2][tid] + sred[1][3][tid];
            atomicAdd(&stats[tid], s);
            atomicAdd(&stats[128 + tid], q);
        }
    }
}

// -------- decoder BN stats, node-centric: yb row in regs, gather ya only -----
__global__ __launch_bounds__(256) void csr_stats(const float* __restrict__ ya,
                                                 const float* __restrict__ yb,
                                                 const int* __restrict__ rowoff,
                                                 const int* __restrict__ perm,
                                                 const float* __restrict__ lperm,
                                                 const float* __restrict__ wl,
                                                 const float* __restrict__ b1,
                                                 float* __restrict__ stats, int N, int nspan) {
    int w = blockIdx.x * 4 + (threadIdx.x >> 6);
    int lane = threadIdx.x & 63;
    const float2* ya2 = (const float2*)ya;
    const float2* yb2 = (const float2*)yb;
    float2 wl2 = ((const float2*)wl)[lane];
    float2 b12 = ((const float2*)b1)[lane];
    float2 s = make_float2(0.f, 0.f), q = make_float2(0.f, 0.f);
    int i0 = w * nspan;
    int i1 = i0 + nspan; if (i1 > N) i1 = N;
    for (int i = i0; i < i1; ++i) {
        float2 ybr = yb2[(size_t)i*64 + lane];
        int b = rowoff[i], t = rowoff[i+1];
        for (int j = b; j < t; ++j) {
            int p = perm[j];
            float lv = lperm[j];
            float2 a = ya2[(size_t)p*64 + lane];
            float zx = a.x + ybr.x + fmaf(lv, wl2.x, b12.x);
            float zy = a.y + ybr.y + fmaf(lv, wl2.y, b12.y);
            s.x += zx; s.y += zy;
            q.x += zx*zx; q.y += zy*zy;
        }
    }
    __shared__ float red[1024];
    int wv = threadIdx.x >> 6;
    red[wv*128 + lane*2]       = s.x;
    red[wv*128 + lane*2 + 1]   = s.y;
    red[512 + wv*128 + lane*2]     = q.x;
    red[512 + wv*128 + lane*2 + 1] = q.y;
    __syncthreads();
    if (threadIdx.x < 128) {
        int c = threadIdx.x;
        float ss = red[c] + red[128+c] + red[256+c] + red[384+c];
        float qq = red[512+c] + red[640+c] + red[768+c] + red[896+c];
        atomicAdd(&stats[c], ss);
        atomicAdd(&stats[128+c], qq);
    }
}

// -------- fused decoder (CSR slot order), bf16 MFMA GEMM --------------------
__global__ __launch_bounds__(256) void decoder_fused(const float* __restrict__ ya,
                                                     const float* __restrict__ yb,
                                                     const float* __restrict__ lperm,
                                                     const int* __restrict__ perm,
                                                     const int* __restrict__ dperm,
                                                     const int* __restrict__ eperm,
                                                     const float* __restrict__ wl,
                                                     const float* __restrict__ b1,
                                                     const float* __restrict__ sc,
                                                     const float* __restrict__ sh,
                                                     const unsigned short* __restrict__ w2t,
                                                     const float* __restrict__ b2,
                                                     const float* __restrict__ w3,
                                                     const float* __restrict__ b3p,
                                                     float* __restrict__ out, int E) {
    __shared__ int4 sAB[2048];           // 32KB: [0,16K)=sA, [16K,32K)=sB
    char* sA = (char*)sAB;
    char* sB = (char*)sAB + 16384;
    const int tid = threadIdx.x;
    const int tile0 = blockIdx.x * 64;

    {
        const int4* src = (const int4*)w2t;
        #pragma unroll
        for (int ii = 0; ii < 4; ++ii) {
            int s = tid + 256*ii;
            int col = s >> 4, k16 = s & 15;
            int byte = ((col << 8) + (k16 << 4)) ^ ((col & 7) << 4);
            *(int4*)(sB + byte) = src[s];
        }
    }
    {
        const int c4 = tid & 31;
        const int rb = tid >> 5;
        float4 wv = ((const float4*)wl)[c4];
        float4 bb = ((const float4*)b1)[c4];
        float4 s4 = ((const float4*)sc)[c4];
        float4 t4 = ((const float4*)sh)[c4];
        #pragma unroll
        for (int i = 0; i < 8; ++i) {
            int r = rb + 8*i;
            int row = tile0 + r;
            float4 v = make_float4(0.f, 0.f, 0.f, 0.f);
            if (row < E) {
                int s0 = perm[row], d0 = dperm[row];
                float lv = lperm[row];
                float4 va = ((const float4*)ya)[(size_t)s0*32 + c4];
                float4 vb = ((const float4*)yb)[(size_t)d0*32 + c4];
                v.x = fmaxf(fmaf(va.x + vb.x + fmaf(lv, wv.x, bb.x), s4.x, t4.x), 0.f);
                v.y = fmaxf(fmaf(va.y + vb.y + fmaf(lv, wv.y, bb.y), s4.y, t4.y), 0.f);
                v.z = fmaxf(fmaf(va.z + vb.z + fmaf(lv, wv.z, bb.z), s4.z, t4.z), 0.f);
                v.w = fmaxf(fmaf(va.w + vb.w + fmaf(lv, wv.w, bb.w), s4.w, t4.w), 0.f);
            }
            uint2 pk;
            pk.x = pack_bf16(v.x, v.y);
            pk.y = pack_bf16(v.z, v.w);
            int byte = ((r << 8) + (c4 << 3)) ^ ((r & 7) << 4);
            *(uint2*)(sA + byte) = pk;
        }
    }
    __syncthreads();

    const int l = tid & 63;
    const int w = tid >> 6;
    const int arow = (w << 4) + (l & 15);
    const int kbase = (l >> 4) << 3;
    f32x4 accv[4];
    #pragma unroll
    for (int c = 0; c < 4; ++c) accv[c] = (f32x4){0.f, 0.f, 0.f, 0.f};

    #pragma unroll
    for (int t = 0; t < 4; ++t) {
        int k0 = t*32 + kbase;
        int abyte = ((arow << 8) + (k0 << 1)) ^ ((arow & 7) << 4);
        bf16x8 af = __builtin_bit_cast(bf16x8, *(const int4*)(sA + abyte));
        #pragma unroll
        for (int c = 0; c < 4; ++c) {
            int bcol = (c << 4) + (l & 15);
            int bbyte = ((bcol << 8) + (k0 << 1)) ^ ((bcol & 7) << 4);
            bf16x8 bf = __builtin_bit_cast(bf16x8, *(const int4*)(sB + bbyte));
            accv[c] = __builtin_amdgcn_mfma_f32_16x16x32_bf16(af, bf, accv[c], 0, 0, 0);
        }
    }

    float p0 = 0.f, p1 = 0.f, p2 = 0.f, p3 = 0.f;
    #pragma unroll
    for (int c = 0; c < 4; ++c) {
        int col = (c << 4) + (l & 15);
        float b2c = b2[col], w3c = w3[col];
        f32x4 a = accv[c];
        p0 = fmaf(fmaxf(a[0] + b2c, 0.f), w3c, p0);
        p1 = fmaf(fmaxf(a[1] + b2c, 0.f), w3c, p1);
        p2 = fmaf(fmaxf(a[2] + b2c, 0.f), w3c, p2);
        p3 = fmaf(fmaxf(a[3] + b2c, 0.f), w3c, p3);
    }
    #pragma unroll
    for (int m = 1; m < 16; m <<= 1) {
        p0 += __shfl_xor(p0, m, 64);
        p1 += __shfl_xor(p1, m, 64);
        p2 += __shfl_xor(p2, m, 64);
        p3 += __shfl_xor(p3, m, 64);
    }
    if ((l & 15) == 0) {
        float b3v = b3p[0];
        int rbase = tile0 + (w << 4) + ((l >> 4) << 2);
        float pj[4] = {p0, p1, p2, p3};
        #pragma unroll
        for (int j = 0; j < 4; ++j) {
            int row = rbase + j;
            if (row < E) out[eperm[row]] = 1.f / (1.f + expf(-(pj[j] + b3v)));
        }
    }
}

// ---------------------------------------------------------------------------

extern "C" void kernel_launch(void* const* d_in, const int* in_sizes, int n_in,
                              void* d_out, int out_size, void* d_ws, size_t ws_size,
                              hipStream_t stream) {
    const int N = in_sizes[0] / 3;
    const int E = in_sizes[1] / 2;

    const float* coords = (const float*)d_in[0];
    const int*   ei     = (const int*)d_in[1];
    const int*   esrc = ei;
    const int*   edst = ei + E;
    const float* g0_w1 = (const float*)d_in[2];
    const float* g0_b1 = (const float*)d_in[3];
    const float* g0_g1 = (const float*)d_in[4];
    const float* g0_be1= (const float*)d_in[5];
    const float* g0_w2 = (const float*)d_in[6];
    const float* g0_b2 = (const float*)d_in[7];
    const float* g0_g2 = (const float*)d_in[8];
    const float* g0_be2= (const float*)d_in[9];
    const float* g0_w3 = (const float*)d_in[10];
    const float* g0_b3 = (const float*)d_in[11];
    const float* eps0  = (const float*)d_in[12];
    const float* bn0_g = (const float*)d_in[13];
    const float* bn0_b = (const float*)d_in[14];
    const float* g1_w1 = (const float*)d_in[15];
    const float* g1_b1 = (const float*)d_in[16];
    const float* g1_g1 = (const float*)d_in[17];
    const float* g1_be1= (const float*)d_in[18];
    const float* g1_w2 = (const float*)d_in[19];
    const float* g1_b2 = (const float*)d_in[20];
    const float* g1_g2 = (const float*)d_in[21];
    const float* g1_be2= (const float*)d_in[22];
    const float* g1_w3 = (const float*)d_in[23];
    const float* g1_b3 = (const float*)d_in[24];
    const float* eps1  = (const float*)d_in[25];
    const float* bn1_g = (const float*)d_in[26];
    const float* bn1_b = (const float*)d_in[27];
    const float* d_w1  = (const float*)d_in[28];
    const float* d_b1  = (const float*)d_in[29];
    const float* d_g   = (const float*)d_in[30];
    const float* d_be  = (const float*)d_in[31];
    const float* d_w2  = (const float*)d_in[32];
    const float* d_b2  = (const float*)d_in[33];
    const float* d_w3  = (const float*)d_in[34];
    const float* d_b3  = (const float*)d_in[35];

    float* ws = (float*)d_ws;
    const size_t NF = (size_t)N * 128;
    float* buf0 = ws;
    float* buf1 = ws + NF;
    float* buf2 = ws + 2*NF;
    float* agg0 = ws + 3*NF;                 // N*3
    float* stats= agg0 + (size_t)N*3;        // 7*256
    float* scsh = stats + 7*256;             // 7*256
    float* lperm = scsh + 7*256;             // E (slot order)
    int*   cursor = (int*)(lperm + E);       // N
    int*   rowoff = cursor + N;              // N+1
    int*   perm   = rowoff + N + 1;          // E (src per slot)
    int*   dperm  = perm + E;                // E (dst per slot)
    int*   eperm  = dperm + E;               // E (edge id per slot)
    unsigned short* w2t = (unsigned short*)(eperm + E);  // 64*128 bf16
    unsigned short* wT  = w2t + 64*128;                  // 7 * 128*128 bf16

    float* out = (float*)d_out;

    const float* wl = d_w1 + 256*128;   // row 256 of d_w1

    #define STATSK(k) (stats + (k)*256)
    #define SC(k) (scsh + (k)*256)
    #define SH(k) (scsh + (k)*256 + 128)
    #define WT(m) (wT + (m)*16384)

    const int rowTiles = (N + 63) / 64;
    const int edgeTiles = (E + 63) / 64;
    const int eBlocks = (E + 255) / 256;
    const float invN = 1.f / (float)N;
    const float invE = 1.f / (float)E;
    const int nWaves = 2048 * 4;
    const int nspan = (N + nWaves - 1) / nWaves;

    // zero BN stat accumulators + CSR cursor
    hipMemsetAsync(stats, 0, 7*256 * sizeof(float), stream);
    hipMemsetAsync(cursor, 0, (size_t)N * sizeof(int), stream);

    // CSR build + weight prep (bf16 transposed)
    hist_dst<<<eBlocks, 256, 0, stream>>>(edst, cursor, E);
    scan_deg<<<1, 1024, 0, stream>>>(cursor, rowoff, cursor, N);
    fill_csr<<<eBlocks, 256, 0, stream>>>(esrc, edst, coords, cursor, perm, dperm, eperm, lperm, E);
    prep_w2<<<32, 256, 0, stream>>>(d_w2, w2t);
    prep_wT<<<dim3(64, 7), 256, 0, stream>>>(g0_w2, g0_w3, g1_w1, g1_w2, g1_w3,
                                             d_w1, d_w1 + 128*128, wT);

    // layer 0
    gather_coords<<<(N + 255)/256, 256, 0, stream>>>(coords, rowoff, perm, agg0, N);
    lin0<<<rowTiles, 256, 0, stream>>>(coords, agg0, g0_w1, g0_b1, eps0, buf0, STATSK(0), N);
    bn_fin<<<1, 128, 0, stream>>>(STATSK(0), g0_g1, g0_be1, SC(0), SH(0), invN);
    gemm_mfma<true,true><<<rowTiles, 256, 0, stream>>>(buf0, WT(0), g0_b2, SC(0), SH(0), buf1, STATSK(1), N);
    bn_fin<<<1, 128, 0, stream>>>(STATSK(1), g0_g2, g0_be2, SC(1), SH(1), invN);
    gemm_mfma<true,true><<<rowTiles, 256, 0, stream>>>(buf1, WT(1), g0_b3, SC(1), SH(1), buf2, STATSK(2), N);
    bn_fin<<<1, 128, 0, stream>>>(STATSK(2), bn0_g, bn0_b, SC(2), SH(2), invN);

    // layer 1: h1 = (1+eps1)*bnrelu(t3) + gather(bnrelu(t3))  (BN folded)
    gather_combine_bn<<<(N + 3)/4, 256, 0, stream>>>(buf2, rowoff, perm, SC(2), SH(2), eps1, buf0, N);
    gemm_mfma<false,true><<<rowTiles, 256, 0, stream>>>(buf0, WT(2), g1_b1, nullptr, nullptr, buf1, STATSK(3), N);
    bn_fin<<<1, 128, 0, stream>>>(STATSK(3), g1_g1, g1_be1, SC(3), SH(3), invN);
    gemm_mfma<true,true><<<rowTiles, 256, 0, stream>>>(buf1, WT(3), g1_b2, SC(3), SH(3), buf2, STATSK(4), N);
    bn_fin<<<1, 128, 0, stream>>>(STATSK(4), g1_g2, g1_be2, SC(4), SH(4), invN);
    gemm_mfma<true,true><<<rowTiles, 256, 0, stream>>>(buf2, WT(4), g1_b3, SC(4), SH(4), buf0, STATSK(5), N);
    bn_fin<<<1, 128, 0, stream>>>(STATSK(5), bn1_g, bn1_b, SC(5), SH(5), invN);

    // decoder: ya/yb from raw buf0 with BN(5) folded into staging
    gemm_mfma<true,false><<<rowTiles, 256, 0, stream>>>(buf0, WT(5), nullptr, SC(5), SH(5), buf1, nullptr, N);
    gemm_mfma<true,false><<<rowTiles, 256, 0, stream>>>(buf0, WT(6), nullptr, SC(5), SH(5), buf2, nullptr, N);
    csr_stats<<<2048, 256, 0, stream>>>(buf1, buf2, rowoff, perm, lperm, wl, d_b1, STATSK(6), N, nspan);
    bn_fin<<<1, 128, 0, stream>>>(STATSK(6), d_g, d_be, SC(6), SH(6), invE);
    decoder_fused<<<edgeTiles, 256, 0, stream>>>(buf1, buf2, lperm, perm, dperm, eperm, wl, d_b1,
                                                 SC(6), SH(6), w2t, d_b2, d_w3, d_b3, out, E);
}

// Round 9
// 1511.803 us; speedup vs baseline: 3.0935x; 1.0169x over previous
//
#include <hip/hip_runtime.h>
#include <hip/hip_bf16.h>
#include <math.h>

// ---------------------------------------------------------------------------
// GIN edge-attribute decoder.
// Round 7 -> 8 (resubmitted; round 8 bench was an infra timeout):
// (1) ya/yb stored bf16 (GEMM epilogue writes ushort) -> halves the random
// row-gather traffic in csr_stats and decoder_fused, the two HBM/LLC-gather-
// bound kernels. Stats and decoder consume the SAME rounded values (BN
// self-consistent). ya_bf/yb_bf alias buf1/buf2 (no new ws).
// (2) bn_fin kernels deleted; every consumer computes BN scale/shift from the
// raw stats accumulators at block start (removes 7 launches + bubbles).
// Round-6/7 evidence: absmax pinned at 0.00390625 across fp32 and bf16-MFMA
// rounds -> error floor is BN var cancellation, not GEMM precision.
// Decoder trick: concat(x2[s],x2[d],l)@W1 == ya[s]+yb[d]+l*wl.
// ---------------------------------------------------------------------------

typedef __attribute__((ext_vector_type(8))) __bf16 bf16x8;
typedef __attribute__((ext_vector_type(4))) float f32x4;

__device__ __forceinline__ unsigned int pack_bf16(float a, float b) {
    unsigned short ua = __builtin_bit_cast(unsigned short, __float2bfloat16(a));
    unsigned short ub = __builtin_bit_cast(unsigned short, __float2bfloat16(b));
    return (unsigned int)ua | ((unsigned int)ub << 16);
}
__device__ __forceinline__ float bflo(unsigned int u) {
    return __builtin_bit_cast(float, u << 16);
}
__device__ __forceinline__ float bfhi(unsigned int u) {
    return __builtin_bit_cast(float, u & 0xffff0000u);
}

// ---------------- CSR build ----------------

__global__ void hist_dst(const int* __restrict__ edst, int* __restrict__ cursor, int E) {
    int e = blockIdx.x * 256 + threadIdx.x;
    if (e < E) atomicAdd(&cursor[edst[e]], 1);
}

__global__ __launch_bounds__(1024) void scan_deg(const int* deg, int* rowoff, int* cursor, int N) {
    __shared__ int sums[1024];
    const int t = threadIdx.x;
    const int chunk = (N + 1023) >> 10;
    int lo = t * chunk, hi = lo + chunk;
    if (lo > N) lo = N;
    if (hi > N) hi = N;
    int s = 0;
    for (int i = lo; i < hi; ++i) s += deg[i];
    sums[t] = s;
    __syncthreads();
    for (int off = 1; off < 1024; off <<= 1) {
        int add = (t >= off) ? sums[t - off] : 0;
        __syncthreads();
        sums[t] += add;
        __syncthreads();
    }
    int run = sums[t] - s;
    for (int i = lo; i < hi; ++i) {
        int d = deg[i];
        rowoff[i] = run;
        cursor[i] = run;
        run += d;
    }
    if (t == 1023) rowoff[N] = sums[1023];
}

__global__ void fill_csr(const int* __restrict__ esrc, const int* __restrict__ edst,
                         const float* __restrict__ coords,
                         int* cursor, int* __restrict__ perm, int* __restrict__ dperm,
                         int* __restrict__ eperm, float* __restrict__ lperm, int E) {
    int e = blockIdx.x * 256 + threadIdx.x;
    if (e >= E) return;
    int s0 = esrc[e], d0 = edst[e];
    int pos = atomicAdd(&cursor[d0], 1);
    perm[pos] = s0;
    dperm[pos] = d0;
    eperm[pos] = e;
    float dx = coords[d0*3+0] - coords[s0*3+0];
    float dy = coords[d0*3+1] - coords[s0*3+1];
    float dz = coords[d0*3+2] - coords[s0*3+2];
    lperm[pos] = sqrtf(dx*dx + dy*dy + dz*dz);
}

// ---------------- gathers ----------------

__global__ void gather_coords(const float* __restrict__ coords,
                              const int* __restrict__ rowoff, const int* __restrict__ perm,
                              float* __restrict__ agg0, int N) {
    int i = blockIdx.x * 256 + threadIdx.x;
    if (i >= N) return;
    float ax = 0.f, ay = 0.f, az = 0.f;
    int b = rowoff[i], t = rowoff[i+1];
    for (int j = b; j < t; ++j) {
        int p = perm[j];
        ax += coords[p*3+0];
        ay += coords[p*3+1];
        az += coords[p*3+2];
    }
    agg0[i*3+0] = ax; agg0[i*3+1] = ay; agg0[i*3+2] = az;
}

// y[i] = (1+eps)*bnrelu(x[i]) + sum_j bnrelu(x[perm[j]]); BN from raw stats
__global__ __launch_bounds__(256) void gather_combine_bn(const float* __restrict__ x,
                                                         const int* __restrict__ rowoff,
                                                         const int* __restrict__ perm,
                                                         const float* __restrict__ st,
                                                         const float* __restrict__ g,
                                                         const float* __restrict__ be,
                                                         float invN,
                                                         const float* __restrict__ eps,
                                                         float* __restrict__ y, int N) {
    int node = blockIdx.x * 4 + (threadIdx.x >> 6);
    int lane = threadIdx.x & 63;
    if (node >= N) return;
    float ep = 1.f + *eps;
    int c0 = lane*2, c1 = c0 + 1;
    float m0 = st[c0]*invN, m1 = st[c1]*invN;
    float v0 = fmaxf(st[128+c0]*invN - m0*m0, 0.f);
    float v1 = fmaxf(st[128+c1]*invN - m1*m1, 0.f);
    float a0 = g[c0]*rsqrtf(v0 + 1e-5f), a1 = g[c1]*rsqrtf(v1 + 1e-5f);
    float2 scv = make_float2(a0, a1);
    float2 shv = make_float2(be[c0] - m0*a0, be[c1] - m1*a1);
    const float2* x2 = (const float2*)x;
    int b = rowoff[node], t = rowoff[node+1];
    float2 acc = make_float2(0.f, 0.f);
    int j = b;
    for (; j + 2 <= t; j += 2) {
        int p0 = perm[j], p1 = perm[j+1];
        float2 v0v = x2[(size_t)p0*64 + lane];
        float2 v1v = x2[(size_t)p1*64 + lane];
        acc.x += fmaxf(fmaf(v0v.x, scv.x, shv.x), 0.f) + fmaxf(fmaf(v1v.x, scv.x, shv.x), 0.f);
        acc.y += fmaxf(fmaf(v0v.y, scv.y, shv.y), 0.f) + fmaxf(fmaf(v1v.y, scv.y, shv.y), 0.f);
    }
    if (j < t) {
        int p = perm[j];
        float2 v = x2[(size_t)p*64 + lane];
        acc.x += fmaxf(fmaf(v.x, scv.x, shv.x), 0.f);
        acc.y += fmaxf(fmaf(v.y, scv.y, shv.y), 0.f);
    }
    float2 own = x2[(size_t)node*64 + lane];
    acc.x = fmaf(ep, fmaxf(fmaf(own.x, scv.x, shv.x), 0.f), acc.x);
    acc.y = fmaf(ep, fmaxf(fmaf(own.y, scv.y, shv.y), 0.f), acc.y);
    ((float2*)y)[(size_t)node*64 + lane] = acc;
}

// ---------------- small kernels ----------------

__global__ __launch_bounds__(256) void lin0(const float* __restrict__ coords,
                                            const float* __restrict__ agg0,
                                            const float* __restrict__ W1,
                                            const float* __restrict__ b1,
                                            const float* __restrict__ eps0,
                                            float* __restrict__ t1,
                                            float* __restrict__ stats, int nrows) {
    int col = threadIdx.x & 127, half = threadIdx.x >> 7;
    float w0 = W1[col], w1 = W1[128+col], w2 = W1[256+col], bb = b1[col];
    float ep = 1.f + *eps0;
    float s = 0.f, q = 0.f;
    int r0 = blockIdx.x * 64;
    for (int i = 0; i < 32; ++i) {
        int row = r0 + half + 2*i;
        if (row < nrows) {
            float h0 = fmaf(ep, coords[row*3+0], agg0[row*3+0]);
            float h1 = fmaf(ep, coords[row*3+1], agg0[row*3+1]);
            float h2 = fmaf(ep, coords[row*3+2], agg0[row*3+2]);
            float v = fmaf(h0, w0, fmaf(h1, w1, fmaf(h2, w2, bb)));
            t1[row*128+col] = v;
            s += v; q += v*v;
        }
    }
    __shared__ float red[512];
    red[half*128+col] = s;
    red[256 + half*128+col] = q;
    __syncthreads();
    if (threadIdx.x < 128) {
        atomicAdd(&stats[col],       red[col] + red[128+col]);
        atomicAdd(&stats[128+col],   red[256+col] + red[384+col]);
    }
}

// W2 [128][64] f32 -> w2t [64 cols][128 k] bf16 (decoder)
__global__ void prep_w2(const float* __restrict__ W2, unsigned short* __restrict__ w2t) {
    int i = blockIdx.x * 256 + threadIdx.x;
    if (i >= 128*64) return;
    int k = i >> 6, c = i & 63;
    w2t[c*128 + k] = __builtin_bit_cast(unsigned short, __float2bfloat16(W2[i]));
}

// 7 node-GEMM weights [128][128] f32 -> [col][k] bf16
__global__ void prep_wT(const float* __restrict__ w0, const float* __restrict__ w1,
                        const float* __restrict__ w2, const float* __restrict__ w3,
                        const float* __restrict__ w4, const float* __restrict__ w5,
                        const float* __restrict__ w6, unsigned short* __restrict__ dst) {
    int m = blockIdx.y;
    const float* src = (m==0)?w0:(m==1)?w1:(m==2)?w2:(m==3)?w3:(m==4)?w4:(m==5)?w5:w6;
    int i = blockIdx.x * 256 + threadIdx.x;
    int k = i >> 7, c = i & 127;
    dst[m*16384 + c*128 + k] =
        __builtin_bit_cast(unsigned short, __float2bfloat16(src[i]));
}

// ---------------- bf16 MFMA node GEMM: [N,128] @ [128,128] ------------------
// BN scale/shift computed in-block from raw stats (sred reused as sc/sh).
template<bool IN_BN, bool STATS, bool OUT_BF16>
__global__ __launch_bounds__(256) void gemm_mfma(const float* __restrict__ A,
                                                 const unsigned short* __restrict__ wT,
                                                 const float* __restrict__ bias,
                                                 const float* __restrict__ inst,
                                                 const float* __restrict__ bng,
                                                 const float* __restrict__ bnb,
                                                 float invCnt,
                                                 float* __restrict__ C,
                                                 unsigned short* __restrict__ Cb,
                                                 float* __restrict__ stats, int nrows) {
    __shared__ int4 sAi[1024];           // 16KB
    __shared__ int4 sBi[2048];           // 32KB
    __shared__ float sred[2][4][128];    // 4KB (also holds sc/sh during staging)
    char* sA = (char*)sAi;
    char* sB = (char*)sBi;
    float* sSC = &sred[0][0][0];
    float* sSH = &sred[0][1][0];
    const int tid = threadIdx.x;
    const int tile0 = blockIdx.x * 64;

    if (IN_BN) {
        if (tid < 128) {
            float m = inst[tid] * invCnt;
            float v = fmaxf(inst[128+tid] * invCnt - m*m, 0.f);
            float a = bng[tid] * rsqrtf(v + 1e-5f);
            sSC[tid] = a;
            sSH[tid] = bnb[tid] - m*a;
        }
        __syncthreads();
    }

    // stage sB: wT [128 col][128 k] bf16 -> swizzled
    {
        const int4* src = (const int4*)wT;
        #pragma unroll
        for (int ii = 0; ii < 8; ++ii) {
            int s = tid + 256*ii;
            int col = s >> 4, k16 = s & 15;
            int byte = ((col << 8) + (k16 << 4)) ^ ((col & 7) << 4);
            *(int4*)(sB + byte) = src[s];
        }
    }
    // stage sA: fp32 rows (+optional BN/ReLU) -> bf16, swizzled
    {
        const int c4 = tid & 31;
        const int rb = tid >> 5;
        float4 s4, t4;
        if (IN_BN) {
            s4 = ((const float4*)sSC)[c4];
            t4 = ((const float4*)sSH)[c4];
        }
        const float4* A4 = (const float4*)A;
        #pragma unroll
        for (int i = 0; i < 8; ++i) {
            int r = rb + 8*i;
            int row = tile0 + r;
            float4 v = make_float4(0.f, 0.f, 0.f, 0.f);
            if (row < nrows) {
                v = A4[(size_t)row*32 + c4];
                if (IN_BN) {
                    v.x = fmaxf(fmaf(v.x, s4.x, t4.x), 0.f);
                    v.y = fmaxf(fmaf(v.y, s4.y, t4.y), 0.f);
                    v.z = fmaxf(fmaf(v.z, s4.z, t4.z), 0.f);
                    v.w = fmaxf(fmaf(v.w, s4.w, t4.w), 0.f);
                }
            }
            uint2 pk;
            pk.x = pack_bf16(v.x, v.y);
            pk.y = pack_bf16(v.z, v.w);
            int byte = ((r << 8) + (c4 << 3)) ^ ((r & 7) << 4);
            *(uint2*)(sA + byte) = pk;
        }
    }
    __syncthreads();

    const int l = tid & 63;
    const int w = tid >> 6;
    const int arow = (w << 4) + (l & 15);
    const int kbase = (l >> 4) << 3;
    f32x4 accv[8];
    #pragma unroll
    for (int c = 0; c < 8; ++c) accv[c] = (f32x4){0.f, 0.f, 0.f, 0.f};

    #pragma unroll
    for (int t = 0; t < 4; ++t) {
        int k0 = t*32 + kbase;
        int abyte = ((arow << 8) + (k0 << 1)) ^ ((arow & 7) << 4);
        bf16x8 af = __builtin_bit_cast(bf16x8, *(const int4*)(sA + abyte));
        #pragma unroll
        for (int c = 0; c < 8; ++c) {
            int bcol = (c << 4) + (l & 15);
            int bbyte = ((bcol << 8) + (k0 << 1)) ^ ((bcol & 7) << 4);
            bf16x8 bf = __builtin_bit_cast(bf16x8, *(const int4*)(sB + bbyte));
            accv[c] = __builtin_amdgcn_mfma_f32_16x16x32_bf16(af, bf, accv[c], 0, 0, 0);
        }
    }

    const int rj = (l >> 4) << 2;
    float lsum[8], lsq[8];
    #pragma unroll
    for (int c = 0; c < 8; ++c) {
        int col = (c << 4) + (l & 15);
        float bv = bias ? bias[col] : 0.f;
        f32x4 a = accv[c];
        float s = 0.f, q = 0.f;
        #pragma unroll
        for (int j = 0; j < 4; ++j) {
            int row = tile0 + (w << 4) + rj + j;
            float o = a[j] + bv;
            if (row < nrows) {
                if (OUT_BF16)
                    Cb[(size_t)row*128 + col] =
                        __builtin_bit_cast(unsigned short, __float2bfloat16(o));
                else
                    C[(size_t)row*128 + col] = o;
                if (STATS) { s += o; q += o*o; }
            }
        }
        lsum[c] = s; lsq[c] = q;
    }
    if (STATS) {
        #pragma unroll
        for (int c = 0; c < 8; ++c) {
            lsum[c] += __shfl_xor(lsum[c], 16, 64);
            lsum[c] += __shfl_xor(lsum[c], 32, 64);
            lsq[c]  += __shfl_xor(lsq[c], 16, 64);
            lsq[c]  += __shfl_xor(lsq[c], 32, 64);
        }
        __syncthreads();   // sc/sh in sred no longer needed; safe to overwrite
        if ((l >> 4) == 0) {
            #pragma unroll
            for (int c = 0; c < 8; ++c) {
                int col = (c << 4) + l;
                sred[0][w][col] = lsum[c];
                sred[1][w][col] = lsq[c];
            }
        }
        __syncthreads();
        if (tid < 128) {
            float s = sred[0][0][tid] + sred[0][1][tid] + sred[0][2][tid] + sred[0][3][tid];
            float q = sred[1][0][tid] + sred[1][1][tid] + sred[1][2][tid] + sred[1][3][tid];
            atomicAdd(&stats[tid], s);
            atomicAdd(&stats[128 + tid], q);
        }
    }
}

// -------- decoder BN stats (bf16 ya/yb): yb row in regs, gather ya only -----
__global__ __launch_bounds__(256) void csr_stats(const unsigned short* __restrict__ ya,
                                                 const unsigned short* __restrict__ yb,
                                                 const int* __restrict__ rowoff,
                                                 const int* __restrict__ perm,
                                                 const float* __restrict__ lperm,
                                                 const float* __restrict__ wl,
                                                 const float* __restrict__ b1,
                                                 float* __restrict__ stats, int N, int nspan) {
    int w = blockIdx.x * 4 + (threadIdx.x >> 6);
    int lane = threadIdx.x & 63;
    const unsigned int* ya2 = (const unsigned int*)ya;   // 2 bf16 per uint
    const unsigned int* yb2 = (const unsigned int*)yb;
    float2 wl2 = ((const float2*)wl)[lane];
    float2 b12 = ((const float2*)b1)[lane];
    float2 s = make_float2(0.f, 0.f), q = make_float2(0.f, 0.f);
    int i0 = w * nspan;
    int i1 = i0 + nspan; if (i1 > N) i1 = N;
    for (int i = i0; i < i1; ++i) {
        unsigned int ub = yb2[(size_t)i*64 + lane];
        float ybx = bflo(ub), yby = bfhi(ub);
        int b = rowoff[i], t = rowoff[i+1];
        for (int j = b; j < t; ++j) {
            int p = perm[j];
            float lv = lperm[j];
            unsigned int ua = ya2[(size_t)p*64 + lane];
            float zx = bflo(ua) + ybx + fmaf(lv, wl2.x, b12.x);
            float zy = bfhi(ua) + yby + fmaf(lv, wl2.y, b12.y);
            s.x += zx; s.y += zy;
            q.x += zx*zx; q.y += zy*zy;
        }
    }
    __shared__ float red[1024];
    int wv = threadIdx.x >> 6;
    red[wv*128 + lane*2]       = s.x;
    red[wv*128 + lane*2 + 1]   = s.y;
    red[512 + wv*128 + lane*2]     = q.x;
    red[512 + wv*128 + lane*2 + 1] = q.y;
    __syncthreads();
    if (threadIdx.x < 128) {
        int c = threadIdx.x;
        float ss = red[c] + red[128+c] + red[256+c] + red[384+c];
        float qq = red[512+c] + red[640+c] + red[768+c] + red[896+c];
        atomicAdd(&stats[c], ss);
        atomicAdd(&stats[128+c], qq);
    }
}

// -------- fused decoder (CSR slot order), bf16 ya/yb, bf16 MFMA GEMM --------
__global__ __launch_bounds__(256) void decoder_fused(const unsigned short* __restrict__ ya,
                                                     const unsigned short* __restrict__ yb,
                                                     const float* __restrict__ lperm,
                                                     const int* __restrict__ perm,
                                                     const int* __restrict__ dperm,
                                                     const int* __restrict__ eperm,
                                                     const float* __restrict__ wl,
                                                     const float* __restrict__ b1,
                                                     const float* __restrict__ st6,
                                                     const float* __restrict__ dg,
                                                     const float* __restrict__ dbe,
                                                     float invE,
                                                     const unsigned short* __restrict__ w2t,
                                                     const float* __restrict__ b2,
                                                     const float* __restrict__ w3,
                                                     const float* __restrict__ b3p,
                                                     float* __restrict__ out, int E) {
    __shared__ int4 sAB[2048];           // 32KB
    char* sA = (char*)sAB;
    char* sB = (char*)sAB + 16384;
    const int tid = threadIdx.x;
    const int tile0 = blockIdx.x * 64;

    {
        const int4* src = (const int4*)w2t;
        #pragma unroll
        for (int ii = 0; ii < 4; ++ii) {
            int s = tid + 256*ii;
            int col = s >> 4, k16 = s & 15;
            int byte = ((col << 8) + (k16 << 4)) ^ ((col & 7) << 4);
            *(int4*)(sB + byte) = src[s];
        }
    }
    {
        const int c4 = tid & 31;
        const int rb = tid >> 5;
        float4 wv = ((const float4*)wl)[c4];
        float4 bb = ((const float4*)b1)[c4];
        float4 s4, t4;
        {
            int cb = c4 * 4;
            #pragma unroll
            for (int j = 0; j < 4; ++j) {
                float m = st6[cb+j] * invE;
                float v = fmaxf(st6[128+cb+j] * invE - m*m, 0.f);
                float a = dg[cb+j] * rsqrtf(v + 1e-5f);
                ((float*)&s4)[j] = a;
                ((float*)&t4)[j] = dbe[cb+j] - m*a;
            }
        }
        const uint2* ya2 = (const uint2*)ya;
        const uint2* yb2 = (const uint2*)yb;
        #pragma unroll
        for (int i = 0; i < 8; ++i) {
            int r = rb + 8*i;
            int row = tile0 + r;
            float4 v = make_float4(0.f, 0.f, 0.f, 0.f);
            if (row < E) {
                int s0 = perm[row], d0 = dperm[row];
                float lv = lperm[row];
                uint2 ua = ya2[(size_t)s0*32 + c4];
                uint2 ubv = yb2[(size_t)d0*32 + c4];
                float vax = bflo(ua.x), vay = bfhi(ua.x), vaz = bflo(ua.y), vaw = bfhi(ua.y);
                float vbx = bflo(ubv.x), vby = bfhi(ubv.x), vbz = bflo(ubv.y), vbw = bfhi(ubv.y);
                v.x = fmaxf(fmaf(vax + vbx + fmaf(lv, wv.x, bb.x), s4.x, t4.x), 0.f);
                v.y = fmaxf(fmaf(vay + vby + fmaf(lv, wv.y, bb.y), s4.y, t4.y), 0.f);
                v.z = fmaxf(fmaf(vaz + vbz + fmaf(lv, wv.z, bb.z), s4.z, t4.z), 0.f);
                v.w = fmaxf(fmaf(vaw + vbw + fmaf(lv, wv.w, bb.w), s4.w, t4.w), 0.f);
            }
            uint2 pk;
            pk.x = pack_bf16(v.x, v.y);
            pk.y = pack_bf16(v.z, v.w);
            int byte = ((r << 8) + (c4 << 3)) ^ ((r & 7) << 4);
            *(uint2*)(sA + byte) = pk;
        }
    }
    __syncthreads();

    const int l = tid & 63;
    const int w = tid >> 6;
    const int arow = (w << 4) + (l & 15);
    const int kbase = (l >> 4) << 3;
    f32x4 accv[4];
    #pragma unroll
    for (int c = 0; c < 4; ++c) accv[c] = (f32x4){0.f, 0.f, 0.f, 0.f};

    #pragma unroll
    for (int t = 0; t < 4; ++t) {
        int k0 = t*32 + kbase;
        int abyte = ((arow << 8) + (k0 << 1)) ^ ((arow & 7) << 4);
        bf16x8 af = __builtin_bit_cast(bf16x8, *(const int4*)(sA + abyte));
        #pragma unroll
        for (int c = 0; c < 4; ++c) {
            int bcol = (c << 4) + (l & 15);
            int bbyte = ((bcol << 8) + (k0 << 1)) ^ ((bcol & 7) << 4);
            bf16x8 bf = __builtin_bit_cast(bf16x8, *(const int4*)(sB + bbyte));
            accv[c] = __builtin_amdgcn_mfma_f32_16x16x32_bf16(af, bf, accv[c], 0, 0, 0);
        }
    }

    float p0 = 0.f, p1 = 0.f, p2 = 0.f, p3 = 0.f;
    #pragma unroll
    for (int c = 0; c < 4; ++c) {
        int col = (c << 4) + (l & 15);
        float b2c = b2[col], w3c = w3[col];
        f32x4 a = accv[c];
        p0 = fmaf(fmaxf(a[0] + b2c, 0.f), w3c, p0);
        p1 = fmaf(fmaxf(a[1] + b2c, 0.f), w3c, p1);
        p2 = fmaf(fmaxf(a[2] + b2c, 0.f), w3c, p2);
        p3 = fmaf(fmaxf(a[3] + b2c, 0.f), w3c, p3);
    }
    #pragma unroll
    for (int m = 1; m < 16; m <<= 1) {
        p0 += __shfl_xor(p0, m, 64);
        p1 += __shfl_xor(p1, m, 64);
        p2 += __shfl_xor(p2, m, 64);
        p3 += __shfl_xor(p3, m, 64);
    }
    if ((l & 15) == 0) {
        float b3v = b3p[0];
        int rbase = tile0 + (w << 4) + ((l >> 4) << 2);
        float pj[4] = {p0, p1, p2, p3};
        #pragma unroll
        for (int j = 0; j < 4; ++j) {
            int row = rbase + j;
            if (row < E) out[eperm[row]] = 1.f / (1.f + expf(-(pj[j] + b3v)));
        }
    }
}

// ---------------------------------------------------------------------------

extern "C" void kernel_launch(void* const* d_in, const int* in_sizes, int n_in,
                              void* d_out, int out_size, void* d_ws, size_t ws_size,
                              hipStream_t stream) {
    const int N = in_sizes[0] / 3;
    const int E = in_sizes[1] / 2;

    const float* coords = (const float*)d_in[0];
    const int*   ei     = (const int*)d_in[1];
    const int*   esrc = ei;
    const int*   edst = ei + E;
    const float* g0_w1 = (const float*)d_in[2];
    const float* g0_b1 = (const float*)d_in[3];
    const float* g0_g1 = (const float*)d_in[4];
    const float* g0_be1= (const float*)d_in[5];
    const float* g0_w2 = (const float*)d_in[6];
    const float* g0_b2 = (const float*)d_in[7];
    const float* g0_g2 = (const float*)d_in[8];
    const float* g0_be2= (const float*)d_in[9];
    const float* g0_w3 = (const float*)d_in[10];
    const float* g0_b3 = (const float*)d_in[11];
    const float* eps0  = (const float*)d_in[12];
    const float* bn0_g = (const float*)d_in[13];
    const float* bn0_b = (const float*)d_in[14];
    const float* g1_w1 = (const float*)d_in[15];
    const float* g1_b1 = (const float*)d_in[16];
    const float* g1_g1 = (const float*)d_in[17];
    const float* g1_be1= (const float*)d_in[18];
    const float* g1_w2 = (const float*)d_in[19];
    const float* g1_b2 = (const float*)d_in[20];
    const float* g1_g2 = (const float*)d_in[21];
    const float* g1_be2= (const float*)d_in[22];
    const float* g1_w3 = (const float*)d_in[23];
    const float* g1_b3 = (const float*)d_in[24];
    const float* eps1  = (const float*)d_in[25];
    const float* bn1_g = (const float*)d_in[26];
    const float* bn1_b = (const float*)d_in[27];
    const float* d_w1  = (const float*)d_in[28];
    const float* d_b1  = (const float*)d_in[29];
    const float* d_g   = (const float*)d_in[30];
    const float* d_be  = (const float*)d_in[31];
    const float* d_w2  = (const float*)d_in[32];
    const float* d_b2  = (const float*)d_in[33];
    const float* d_w3  = (const float*)d_in[34];
    const float* d_b3  = (const float*)d_in[35];

    float* ws = (float*)d_ws;
    const size_t NF = (size_t)N * 128;
    float* buf0 = ws;
    float* buf1 = ws + NF;
    float* buf2 = ws + 2*NF;
    float* agg0 = ws + 3*NF;                 // N*3
    float* stats= agg0 + (size_t)N*3;        // 7*256
    float* scsh = stats + 7*256;             // 7*256 (unused, kept for layout)
    float* lperm = scsh + 7*256;             // E (slot order)
    int*   cursor = (int*)(lperm + E);       // N
    int*   rowoff = cursor + N;              // N+1
    int*   perm   = rowoff + N + 1;          // E (src per slot)
    int*   dperm  = perm + E;                // E (dst per slot)
    int*   eperm  = dperm + E;               // E (edge id per slot)
    unsigned short* w2t = (unsigned short*)(eperm + E);  // 64*128 bf16
    unsigned short* wT  = w2t + 64*128;                  // 7 * 128*128 bf16
    unsigned short* ya_bf = (unsigned short*)buf1;       // aliases buf1
    unsigned short* yb_bf = (unsigned short*)buf2;       // aliases buf2

    float* out = (float*)d_out;

    const float* wl = d_w1 + 256*128;   // row 256 of d_w1

    #define STATSK(k) (stats + (k)*256)
    #define WT(m) (wT + (m)*16384)

    const int rowTiles = (N + 63) / 64;
    const int edgeTiles = (E + 63) / 64;
    const int eBlocks = (E + 255) / 256;
    const float invN = 1.f / (float)N;
    const float invE = 1.f / (float)E;
    const int nWaves = 2048 * 4;
    const int nspan = (N + nWaves - 1) / nWaves;

    hipMemsetAsync(stats, 0, 7*256 * sizeof(float), stream);
    hipMemsetAsync(cursor, 0, (size_t)N * sizeof(int), stream);

    // CSR build + weight prep
    hist_dst<<<eBlocks, 256, 0, stream>>>(edst, cursor, E);
    scan_deg<<<1, 1024, 0, stream>>>(cursor, rowoff, cursor, N);
    fill_csr<<<eBlocks, 256, 0, stream>>>(esrc, edst, coords, cursor, perm, dperm, eperm, lperm, E);
    prep_w2<<<32, 256, 0, stream>>>(d_w2, w2t);
    prep_wT<<<dim3(64, 7), 256, 0, stream>>>(g0_w2, g0_w3, g1_w1, g1_w2, g1_w3,
                                             d_w1, d_w1 + 128*128, wT);

    // layer 0
    gather_coords<<<(N + 255)/256, 256, 0, stream>>>(coords, rowoff, perm, agg0, N);
    lin0<<<rowTiles, 256, 0, stream>>>(coords, agg0, g0_w1, g0_b1, eps0, buf0, STATSK(0), N);
    gemm_mfma<true,true,false><<<rowTiles, 256, 0, stream>>>(
        buf0, WT(0), g0_b2, STATSK(0), g0_g1, g0_be1, invN, buf1, nullptr, STATSK(1), N);
    gemm_mfma<true,true,false><<<rowTiles, 256, 0, stream>>>(
        buf1, WT(1), g0_b3, STATSK(1), g0_g2, g0_be2, invN, buf2, nullptr, STATSK(2), N);

    // layer 1: h1 = (1+eps1)*bnrelu(t3) + gather(bnrelu(t3))
    gather_combine_bn<<<(N + 3)/4, 256, 0, stream>>>(
        buf2, rowoff, perm, STATSK(2), bn0_g, bn0_b, invN, eps1, buf0, N);
    gemm_mfma<false,true,false><<<rowTiles, 256, 0, stream>>>(
        buf0, WT(2), g1_b1, nullptr, nullptr, nullptr, 0.f, buf1, nullptr, STATSK(3), N);
    gemm_mfma<true,true,false><<<rowTiles, 256, 0, stream>>>(
        buf1, WT(3), g1_b2, STATSK(3), g1_g1, g1_be1, invN, buf2, nullptr, STATSK(4), N);
    gemm_mfma<true,true,false><<<rowTiles, 256, 0, stream>>>(
        buf2, WT(4), g1_b3, STATSK(4), g1_g2, g1_be2, invN, buf0, nullptr, STATSK(5), N);

    // decoder: ya/yb (bf16) from buf0 with BN(5) folded into staging
    gemm_mfma<true,false,true><<<rowTiles, 256, 0, stream>>>(
        buf0, WT(5), nullptr, STATSK(5), bn1_g, bn1_b, invN, nullptr, ya_bf, nullptr, N);
    gemm_mfma<true,false,true><<<rowTiles, 256, 0, stream>>>(
        buf0, WT(6), nullptr, STATSK(5), bn1_g, bn1_b, invN, nullptr, yb_bf, nullptr, N);
    csr_stats<<<2048, 256, 0, stream>>>(ya_bf, yb_bf, rowoff, perm, lperm, wl, d_b1,
                                        STATSK(6), N, nspan);
    decoder_fused<<<edgeTiles, 256, 0, stream>>>(ya_bf, yb_bf, lperm, perm, dperm, eperm,
                                                 wl, d_b1, STATSK(6), d_g, d_be, invE,
                                                 w2t, d_b2, d_w3, d_b3, out, E);
}

// Round 10
// 1500.496 us; speedup vs baseline: 3.1168x; 1.0075x over previous
//
#include <hip/hip_runtime.h>
#include <hip/hip_bf16.h>
#include <math.h>

// ---------------------------------------------------------------------------
// GIN edge-attribute decoder.
// Round 9 -> 10: (1) ALL [N,128] intermediates stored bf16 (t1..t5, h1, x2):
// halves I/O of every node GEMM and of gather_combine_bn's row gathers. BN
// stats still accumulated fp32 pre-rounding; storage rounds (error class
// already validated: absmax pinned 0.0039 through rounds 6-9).
// (2) decoder_fused persistent: W2 LDS tile staged once per block (was once
// per 64-edge tile -> 25k re-stagings), grid-stride over tiles. Round-9 PMC:
// decoder is VALU/staging-bound (FETCH halved, dur flat, VALUBusy 55%).
// Decoder trick: concat(x2[s],x2[d],l)@W1 == ya[s]+yb[d]+l*wl.
// ---------------------------------------------------------------------------

typedef __attribute__((ext_vector_type(8))) __bf16 bf16x8;
typedef __attribute__((ext_vector_type(4))) float f32x4;

__device__ __forceinline__ unsigned int pack_bf16(float a, float b) {
    unsigned short ua = __builtin_bit_cast(unsigned short, __float2bfloat16(a));
    unsigned short ub = __builtin_bit_cast(unsigned short, __float2bfloat16(b));
    return (unsigned int)ua | ((unsigned int)ub << 16);
}
__device__ __forceinline__ float bflo(unsigned int u) {
    return __builtin_bit_cast(float, u << 16);
}
__device__ __forceinline__ float bfhi(unsigned int u) {
    return __builtin_bit_cast(float, u & 0xffff0000u);
}
__device__ __forceinline__ unsigned short bf16r(float a) {
    return __builtin_bit_cast(unsigned short, __float2bfloat16(a));
}

// ---------------- CSR build ----------------

__global__ void hist_dst(const int* __restrict__ edst, int* __restrict__ cursor, int E) {
    int e = blockIdx.x * 256 + threadIdx.x;
    if (e < E) atomicAdd(&cursor[edst[e]], 1);
}

__global__ __launch_bounds__(1024) void scan_deg(const int* deg, int* rowoff, int* cursor, int N) {
    __shared__ int sums[1024];
    const int t = threadIdx.x;
    const int chunk = (N + 1023) >> 10;
    int lo = t * chunk, hi = lo + chunk;
    if (lo > N) lo = N;
    if (hi > N) hi = N;
    int s = 0;
    for (int i = lo; i < hi; ++i) s += deg[i];
    sums[t] = s;
    __syncthreads();
    for (int off = 1; off < 1024; off <<= 1) {
        int add = (t >= off) ? sums[t - off] : 0;
        __syncthreads();
        sums[t] += add;
        __syncthreads();
    }
    int run = sums[t] - s;
    for (int i = lo; i < hi; ++i) {
        int d = deg[i];
        rowoff[i] = run;
        cursor[i] = run;
        run += d;
    }
    if (t == 1023) rowoff[N] = sums[1023];
}

__global__ void fill_csr(const int* __restrict__ esrc, const int* __restrict__ edst,
                         const float* __restrict__ coords,
                         int* cursor, int* __restrict__ perm, int* __restrict__ dperm,
                         int* __restrict__ eperm, float* __restrict__ lperm, int E) {
    int e = blockIdx.x * 256 + threadIdx.x;
    if (e >= E) return;
    int s0 = esrc[e], d0 = edst[e];
    int pos = atomicAdd(&cursor[d0], 1);
    perm[pos] = s0;
    dperm[pos] = d0;
    eperm[pos] = e;
    float dx = coords[d0*3+0] - coords[s0*3+0];
    float dy = coords[d0*3+1] - coords[s0*3+1];
    float dz = coords[d0*3+2] - coords[s0*3+2];
    lperm[pos] = sqrtf(dx*dx + dy*dy + dz*dz);
}

// ---------------- gathers ----------------

__global__ void gather_coords(const float* __restrict__ coords,
                              const int* __restrict__ rowoff, const int* __restrict__ perm,
                              float* __restrict__ agg0, int N) {
    int i = blockIdx.x * 256 + threadIdx.x;
    if (i >= N) return;
    float ax = 0.f, ay = 0.f, az = 0.f;
    int b = rowoff[i], t = rowoff[i+1];
    for (int j = b; j < t; ++j) {
        int p = perm[j];
        ax += coords[p*3+0];
        ay += coords[p*3+1];
        az += coords[p*3+2];
    }
    agg0[i*3+0] = ax; agg0[i*3+1] = ay; agg0[i*3+2] = az;
}

// y[i] = (1+eps)*bnrelu(x[i]) + sum_j bnrelu(x[perm[j]]); x,y bf16; BN from raw stats
__global__ __launch_bounds__(256) void gather_combine_bn(const unsigned short* __restrict__ x,
                                                         const int* __restrict__ rowoff,
                                                         const int* __restrict__ perm,
                                                         const float* __restrict__ st,
                                                         const float* __restrict__ g,
                                                         const float* __restrict__ be,
                                                         float invN,
                                                         const float* __restrict__ eps,
                                                         unsigned short* __restrict__ y, int N) {
    int node = blockIdx.x * 4 + (threadIdx.x >> 6);
    int lane = threadIdx.x & 63;
    if (node >= N) return;
    float ep = 1.f + *eps;
    int c0 = lane*2, c1 = c0 + 1;
    float m0 = st[c0]*invN, m1 = st[c1]*invN;
    float v0 = fmaxf(st[128+c0]*invN - m0*m0, 0.f);
    float v1 = fmaxf(st[128+c1]*invN - m1*m1, 0.f);
    float a0 = g[c0]*rsqrtf(v0 + 1e-5f), a1 = g[c1]*rsqrtf(v1 + 1e-5f);
    float sx = a0, sy = a1;
    float hx = be[c0] - m0*a0, hy = be[c1] - m1*a1;
    const unsigned int* x2 = (const unsigned int*)x;
    int b = rowoff[node], t = rowoff[node+1];
    float accx = 0.f, accy = 0.f;
    int j = b;
    for (; j + 2 <= t; j += 2) {
        unsigned int u0 = x2[(size_t)perm[j]*64 + lane];
        unsigned int u1 = x2[(size_t)perm[j+1]*64 + lane];
        accx += fmaxf(fmaf(bflo(u0), sx, hx), 0.f) + fmaxf(fmaf(bflo(u1), sx, hx), 0.f);
        accy += fmaxf(fmaf(bfhi(u0), sy, hy), 0.f) + fmaxf(fmaf(bfhi(u1), sy, hy), 0.f);
    }
    if (j < t) {
        unsigned int u = x2[(size_t)perm[j]*64 + lane];
        accx += fmaxf(fmaf(bflo(u), sx, hx), 0.f);
        accy += fmaxf(fmaf(bfhi(u), sy, hy), 0.f);
    }
    unsigned int uo = x2[(size_t)node*64 + lane];
    accx = fmaf(ep, fmaxf(fmaf(bflo(uo), sx, hx), 0.f), accx);
    accy = fmaf(ep, fmaxf(fmaf(bfhi(uo), sy, hy), 0.f), accy);
    ((unsigned int*)y)[(size_t)node*64 + lane] = pack_bf16(accx, accy);
}

// ---------------- small kernels ----------------

// t1 = ((1+eps)*coords + agg0) @ W1 + b1  (K=3), bf16 out, fp32 stats
__global__ __launch_bounds__(256) void lin0(const float* __restrict__ coords,
                                            const float* __restrict__ agg0,
                                            const float* __restrict__ W1,
                                            const float* __restrict__ b1,
                                            const float* __restrict__ eps0,
                                            unsigned short* __restrict__ t1,
                                            float* __restrict__ stats, int nrows) {
    int col = threadIdx.x & 127, half = threadIdx.x >> 7;
    float w0 = W1[col], w1 = W1[128+col], w2 = W1[256+col], bb = b1[col];
    float ep = 1.f + *eps0;
    float s = 0.f, q = 0.f;
    int r0 = blockIdx.x * 64;
    for (int i = 0; i < 32; ++i) {
        int row = r0 + half + 2*i;
        if (row < nrows) {
            float h0 = fmaf(ep, coords[row*3+0], agg0[row*3+0]);
            float h1 = fmaf(ep, coords[row*3+1], agg0[row*3+1]);
            float h2 = fmaf(ep, coords[row*3+2], agg0[row*3+2]);
            float v = fmaf(h0, w0, fmaf(h1, w1, fmaf(h2, w2, bb)));
            t1[row*128+col] = bf16r(v);
            s += v; q += v*v;
        }
    }
    __shared__ float red[512];
    red[half*128+col] = s;
    red[256 + half*128+col] = q;
    __syncthreads();
    if (threadIdx.x < 128) {
        atomicAdd(&stats[col],       red[col] + red[128+col]);
        atomicAdd(&stats[128+col],   red[256+col] + red[384+col]);
    }
}

// W2 [128][64] f32 -> w2t [64 cols][128 k] bf16 (decoder)
__global__ void prep_w2(const float* __restrict__ W2, unsigned short* __restrict__ w2t) {
    int i = blockIdx.x * 256 + threadIdx.x;
    if (i >= 128*64) return;
    int k = i >> 6, c = i & 63;
    w2t[c*128 + k] = bf16r(W2[i]);
}

// 7 node-GEMM weights [128][128] f32 -> [col][k] bf16
__global__ void prep_wT(const float* __restrict__ w0, const float* __restrict__ w1,
                        const float* __restrict__ w2, const float* __restrict__ w3,
                        const float* __restrict__ w4, const float* __restrict__ w5,
                        const float* __restrict__ w6, unsigned short* __restrict__ dst) {
    int m = blockIdx.y;
    const float* src = (m==0)?w0:(m==1)?w1:(m==2)?w2:(m==3)?w3:(m==4)?w4:(m==5)?w5:w6;
    int i = blockIdx.x * 256 + threadIdx.x;
    int k = i >> 7, c = i & 127;
    dst[m*16384 + c*128 + k] = bf16r(src[i]);
}

// ---------------- bf16 MFMA node GEMM: bf16 [N,128] @ [128,128] -> bf16 -----
template<bool IN_BN, bool STATS>
__global__ __launch_bounds__(256) void gemm_mfma(const unsigned short* __restrict__ A,
                                                 const unsigned short* __restrict__ wT,
                                                 const float* __restrict__ bias,
                                                 const float* __restrict__ inst,
                                                 const float* __restrict__ bng,
                                                 const float* __restrict__ bnb,
                                                 float invCnt,
                                                 unsigned short* __restrict__ Cb,
                                                 float* __restrict__ stats, int nrows) {
    __shared__ int4 sAi[1024];           // 16KB
    __shared__ int4 sBi[2048];           // 32KB
    __shared__ float sred[2][4][128];    // 4KB (sc/sh during staging)
    char* sA = (char*)sAi;
    char* sB = (char*)sBi;
    float* sSC = &sred[0][0][0];
    float* sSH = &sred[0][1][0];
    const int tid = threadIdx.x;
    const int tile0 = blockIdx.x * 64;

    if (IN_BN) {
        if (tid < 128) {
            float m = inst[tid] * invCnt;
            float v = fmaxf(inst[128+tid] * invCnt - m*m, 0.f);
            float a = bng[tid] * rsqrtf(v + 1e-5f);
            sSC[tid] = a;
            sSH[tid] = bnb[tid] - m*a;
        }
        __syncthreads();
    }

    // stage sB: wT [128 col][128 k] bf16 -> swizzled
    {
        const int4* src = (const int4*)wT;
        #pragma unroll
        for (int ii = 0; ii < 8; ++ii) {
            int s = tid + 256*ii;
            int col = s >> 4, k16 = s & 15;
            int byte = ((col << 8) + (k16 << 4)) ^ ((col & 7) << 4);
            *(int4*)(sB + byte) = src[s];
        }
    }
    // stage sA: bf16 rows (+optional BN/ReLU) -> swizzled. 1024 slots of 8 bf16.
    {
        const int4* A4 = (const int4*)A;   // 16 slots per row
        #pragma unroll
        for (int ii = 0; ii < 4; ++ii) {
            int s = tid + 256*ii;
            int r = s >> 4, k16 = s & 15;
            int row = tile0 + r;
            int4 raw = make_int4(0,0,0,0);
            if (row < nrows) raw = A4[(size_t)row*16 + k16];
            if (IN_BN) {
                float4 sa = ((const float4*)sSC)[k16*2];
                float4 sb = ((const float4*)sSC)[k16*2+1];
                float4 ha = ((const float4*)sSH)[k16*2];
                float4 hb = ((const float4*)sSH)[k16*2+1];
                unsigned int ux = raw.x, uy = raw.y, uz = raw.z, uw = raw.w;
                float e0 = fmaxf(fmaf(bflo(ux), sa.x, ha.x), 0.f);
                float e1 = fmaxf(fmaf(bfhi(ux), sa.y, ha.y), 0.f);
                float e2 = fmaxf(fmaf(bflo(uy), sa.z, ha.z), 0.f);
                float e3 = fmaxf(fmaf(bfhi(uy), sa.w, ha.w), 0.f);
                float e4 = fmaxf(fmaf(bflo(uz), sb.x, hb.x), 0.f);
                float e5 = fmaxf(fmaf(bfhi(uz), sb.y, hb.y), 0.f);
                float e6 = fmaxf(fmaf(bflo(uw), sb.z, hb.z), 0.f);
                float e7 = fmaxf(fmaf(bfhi(uw), sb.w, hb.w), 0.f);
                raw.x = (int)pack_bf16(e0, e1);
                raw.y = (int)pack_bf16(e2, e3);
                raw.z = (int)pack_bf16(e4, e5);
                raw.w = (int)pack_bf16(e6, e7);
            }
            int byte = ((r << 8) + (k16 << 4)) ^ ((r & 7) << 4);
            *(int4*)(sA + byte) = raw;
        }
    }
    __syncthreads();

    const int l = tid & 63;
    const int w = tid >> 6;
    const int arow = (w << 4) + (l & 15);
    const int kbase = (l >> 4) << 3;
    f32x4 accv[8];
    #pragma unroll
    for (int c = 0; c < 8; ++c) accv[c] = (f32x4){0.f, 0.f, 0.f, 0.f};

    #pragma unroll
    for (int t = 0; t < 4; ++t) {
        int k0 = t*32 + kbase;
        int abyte = ((arow << 8) + (k0 << 1)) ^ ((arow & 7) << 4);
        bf16x8 af = __builtin_bit_cast(bf16x8, *(const int4*)(sA + abyte));
        #pragma unroll
        for (int c = 0; c < 8; ++c) {
            int bcol = (c << 4) + (l & 15);
            int bbyte = ((bcol << 8) + (k0 << 1)) ^ ((bcol & 7) << 4);
            bf16x8 bf = __builtin_bit_cast(bf16x8, *(const int4*)(sB + bbyte));
            accv[c] = __builtin_amdgcn_mfma_f32_16x16x32_bf16(af, bf, accv[c], 0, 0, 0);
        }
    }

    const int rj = (l >> 4) << 2;
    float lsum[8], lsq[8];
    #pragma unroll
    for (int c = 0; c < 8; ++c) {
        int col = (c << 4) + (l & 15);
        float bv = bias ? bias[col] : 0.f;
        f32x4 a = accv[c];
        float s = 0.f, q = 0.f;
        #pragma unroll
        for (int j = 0; j < 4; ++j) {
            int row = tile0 + (w << 4) + rj + j;
            float o = a[j] + bv;
            if (row < nrows) {
                Cb[(size_t)row*128 + col] = bf16r(o);
                if (STATS) { s += o; q += o*o; }
            }
        }
        lsum[c] = s; lsq[c] = q;
    }
    if (STATS) {
        #pragma unroll
        for (int c = 0; c < 8; ++c) {
            lsum[c] += __shfl_xor(lsum[c], 16, 64);
            lsum[c] += __shfl_xor(lsum[c], 32, 64);
            lsq[c]  += __shfl_xor(lsq[c], 16, 64);
            lsq[c]  += __shfl_xor(lsq[c], 32, 64);
        }
        __syncthreads();
        if ((l >> 4) == 0) {
            #pragma unroll
            for (int c = 0; c < 8; ++c) {
                int col = (c << 4) + l;
                sred[0][w][col] = lsum[c];
                sred[1][w][col] = lsq[c];
            }
        }
        __syncthreads();
        if (tid < 128) {
            float s = sred[0][0][tid] + sred[0][1][tid] + sred[0][2][tid] + sred[0][3][tid];
            float q = sred[1][0][tid] + sred[1][1][tid] + sred[1][2][tid] + sred[1][3][tid];
            atomicAdd(&stats[tid], s);
            atomicAdd(&stats[128 + tid], q);
        }
    }
}

// -------- decoder BN stats (bf16 ya/yb): yb row in regs, gather ya only -----
__global__ __launch_bounds__(256) void csr_stats(const unsigned short* __restrict__ ya,
                                                 const unsigned short* __restrict__ yb,
                                                 const int* __restrict__ rowoff,
                                                 const int* __restrict__ perm,
                                                 const float* __restrict__ lperm,
                                                 const float* __restrict__ wl,
                                                 const float* __restrict__ b1,
                                                 float* __restrict__ stats, int N, int nspan) {
    int w = blockIdx.x * 4 + (threadIdx.x >> 6);
    int lane = threadIdx.x & 63;
    const unsigned int* ya2 = (const unsigned int*)ya;
    const unsigned int* yb2 = (const unsigned int*)yb;
    float2 wl2 = ((const float2*)wl)[lane];
    float2 b12 = ((const float2*)b1)[lane];
    float2 s = make_float2(0.f, 0.f), q = make_float2(0.f, 0.f);
    int i0 = w * nspan;
    int i1 = i0 + nspan; if (i1 > N) i1 = N;
    for (int i = i0; i < i1; ++i) {
        unsigned int ub = yb2[(size_t)i*64 + lane];
        float ybx = bflo(ub), yby = bfhi(ub);
        int b = rowoff[i], t = rowoff[i+1];
        for (int j = b; j < t; ++j) {
            int p = perm[j];
            float lv = lperm[j];
            unsigned int ua = ya2[(size_t)p*64 + lane];
            float zx = bflo(ua) + ybx + fmaf(lv, wl2.x, b12.x);
            float zy = bfhi(ua) + yby + fmaf(lv, wl2.y, b12.y);
            s.x += zx; s.y += zy;
            q.x += zx*zx; q.y += zy*zy;
        }
    }
    __shared__ float red[1024];
    int wv = threadIdx.x >> 6;
    red[wv*128 + lane*2]       = s.x;
    red[wv*128 + lane*2 + 1]   = s.y;
    red[512 + wv*128 + lane*2]     = q.x;
    red[512 + wv*128 + lane*2 + 1] = q.y;
    __syncthreads();
    if (threadIdx.x < 128) {
        int c = threadIdx.x;
        float ss = red[c] + red[128+c] + red[256+c] + red[384+c];
        float qq = red[512+c] + red[640+c] + red[768+c] + red[896+c];
        atomicAdd(&stats[c], ss);
        atomicAdd(&stats[128+c], qq);
    }
}

// -------- fused decoder, persistent blocks: sB staged ONCE per block --------
__global__ __launch_bounds__(256) void decoder_fused(const unsigned short* __restrict__ ya,
                                                     const unsigned short* __restrict__ yb,
                                                     const float* __restrict__ lperm,
                                                     const int* __restrict__ perm,
                                                     const int* __restrict__ dperm,
                                                     const int* __restrict__ eperm,
                                                     const float* __restrict__ wl,
                                                     const float* __restrict__ b1,
                                                     const float* __restrict__ st6,
                                                     const float* __restrict__ dg,
                                                     const float* __restrict__ dbe,
                                                     float invE,
                                                     const unsigned short* __restrict__ w2t,
                                                     const float* __restrict__ b2,
                                                     const float* __restrict__ w3,
                                                     const float* __restrict__ b3p,
                                                     float* __restrict__ out, int E, int ntiles) {
    __shared__ int4 sAB[2048];           // 32KB
    char* sA = (char*)sAB;
    char* sB = (char*)sAB + 16384;
    const int tid = threadIdx.x;

    // stage sB once
    {
        const int4* src = (const int4*)w2t;
        #pragma unroll
        for (int ii = 0; ii < 4; ++ii) {
            int s = tid + 256*ii;
            int col = s >> 4, k16 = s & 15;
            int byte = ((col << 8) + (k16 << 4)) ^ ((col & 7) << 4);
            *(int4*)(sB + byte) = src[s];
        }
    }

    // per-thread staging constants
    const int c4 = tid & 31;
    const int rb = tid >> 5;
    float4 wv = ((const float4*)wl)[c4];
    float4 bb = ((const float4*)b1)[c4];
    float4 s4, t4;
    {
        int cb = c4 * 4;
        #pragma unroll
        for (int j = 0; j < 4; ++j) {
            float m = st6[cb+j] * invE;
            float v = fmaxf(st6[128+cb+j] * invE - m*m, 0.f);
            float a = dg[cb+j] * rsqrtf(v + 1e-5f);
            ((float*)&s4)[j] = a;
            ((float*)&t4)[j] = dbe[cb+j] - m*a;
        }
    }
    const uint2* ya2 = (const uint2*)ya;
    const uint2* yb2 = (const uint2*)yb;

    const int l = tid & 63;
    const int w = tid >> 6;
    const int arow = (w << 4) + (l & 15);
    const int kbase = (l >> 4) << 3;
    const float b3v = b3p[0];

    for (int tile = blockIdx.x; tile < ntiles; tile += gridDim.x) {
        const int tile0 = tile * 64;
        __syncthreads();   // prior iteration's MFMA reads of sA done
        // stage sA: z = bnrelu(ya[s]+yb[d]+l*wl+b1) -> bf16, swizzled
        #pragma unroll
        for (int i = 0; i < 8; ++i) {
            int r = rb + 8*i;
            int row = tile0 + r;
            float4 v = make_float4(0.f, 0.f, 0.f, 0.f);
            if (row < E) {
                int s0 = perm[row], d0 = dperm[row];
                float lv = lperm[row];
                uint2 ua = ya2[(size_t)s0*32 + c4];
                uint2 ubv = yb2[(size_t)d0*32 + c4];
                float vax = bflo(ua.x), vay = bfhi(ua.x), vaz = bflo(ua.y), vaw = bfhi(ua.y);
                float vbx = bflo(ubv.x), vby = bfhi(ubv.x), vbz = bflo(ubv.y), vbw = bfhi(ubv.y);
                v.x = fmaxf(fmaf(vax + vbx + fmaf(lv, wv.x, bb.x), s4.x, t4.x), 0.f);
                v.y = fmaxf(fmaf(vay + vby + fmaf(lv, wv.y, bb.y), s4.y, t4.y), 0.f);
                v.z = fmaxf(fmaf(vaz + vbz + fmaf(lv, wv.z, bb.z), s4.z, t4.z), 0.f);
                v.w = fmaxf(fmaf(vaw + vbw + fmaf(lv, wv.w, bb.w), s4.w, t4.w), 0.f);
            }
            uint2 pk;
            pk.x = pack_bf16(v.x, v.y);
            pk.y = pack_bf16(v.z, v.w);
            int byte = ((r << 8) + (c4 << 3)) ^ ((r & 7) << 4);
            *(uint2*)(sA + byte) = pk;
        }
        __syncthreads();

        f32x4 accv[4];
        #pragma unroll
        for (int c = 0; c < 4; ++c) accv[c] = (f32x4){0.f, 0.f, 0.f, 0.f};
        #pragma unroll
        for (int t = 0; t < 4; ++t) {
            int k0 = t*32 + kbase;
            int abyte = ((arow << 8) + (k0 << 1)) ^ ((arow & 7) << 4);
            bf16x8 af = __builtin_bit_cast(bf16x8, *(const int4*)(sA + abyte));
            #pragma unroll
            for (int c = 0; c < 4; ++c) {
                int bcol = (c << 4) + (l & 15);
                int bbyte = ((bcol << 8) + (k0 << 1)) ^ ((bcol & 7) << 4);
                bf16x8 bf = __builtin_bit_cast(bf16x8, *(const int4*)(sB + bbyte));
                accv[c] = __builtin_amdgcn_mfma_f32_16x16x32_bf16(af, bf, accv[c], 0, 0, 0);
            }
        }

        float p0 = 0.f, p1 = 0.f, p2 = 0.f, p3 = 0.f;
        #pragma unroll
        for (int c = 0; c < 4; ++c) {
            int col = (c << 4) + (l & 15);
            float b2c = b2[col], w3c = w3[col];
            f32x4 a = accv[c];
            p0 = fmaf(fmaxf(a[0] + b2c, 0.f), w3c, p0);
            p1 = fmaf(fmaxf(a[1] + b2c, 0.f), w3c, p1);
            p2 = fmaf(fmaxf(a[2] + b2c, 0.f), w3c, p2);
            p3 = fmaf(fmaxf(a[3] + b2c, 0.f), w3c, p3);
        }
        #pragma unroll
        for (int m = 1; m < 16; m <<= 1) {
            p0 += __shfl_xor(p0, m, 64);
            p1 += __shfl_xor(p1, m, 64);
            p2 += __shfl_xor(p2, m, 64);
            p3 += __shfl_xor(p3, m, 64);
        }
        if ((l & 15) == 0) {
            int rbase = tile0 + (w << 4) + ((l >> 4) << 2);
            float pj[4] = {p0, p1, p2, p3};
            #pragma unroll
            for (int j = 0; j < 4; ++j) {
                int row = rbase + j;
                if (row < E) out[eperm[row]] = 1.f / (1.f + expf(-(pj[j] + b3v)));
            }
        }
    }
}

// ---------------------------------------------------------------------------

extern "C" void kernel_launch(void* const* d_in, const int* in_sizes, int n_in,
                              void* d_out, int out_size, void* d_ws, size_t ws_size,
                              hipStream_t stream) {
    const int N = in_sizes[0] / 3;
    const int E = in_sizes[1] / 2;

    const float* coords = (const float*)d_in[0];
    const int*   ei     = (const int*)d_in[1];
    const int*   esrc = ei;
    const int*   edst = ei + E;
    const float* g0_w1 = (const float*)d_in[2];
    const float* g0_b1 = (const float*)d_in[3];
    const float* g0_g1 = (const float*)d_in[4];
    const float* g0_be1= (const float*)d_in[5];
    const float* g0_w2 = (const float*)d_in[6];
    const float* g0_b2 = (const float*)d_in[7];
    const float* g0_g2 = (const float*)d_in[8];
    const float* g0_be2= (const float*)d_in[9];
    const float* g0_w3 = (const float*)d_in[10];
    const float* g0_b3 = (const float*)d_in[11];
    const float* eps0  = (const float*)d_in[12];
    const float* bn0_g = (const float*)d_in[13];
    const float* bn0_b = (const float*)d_in[14];
    const float* g1_w1 = (const float*)d_in[15];
    const float* g1_b1 = (const float*)d_in[16];
    const float* g1_g1 = (const float*)d_in[17];
    const float* g1_be1= (const float*)d_in[18];
    const float* g1_w2 = (const float*)d_in[19];
    const float* g1_b2 = (const float*)d_in[20];
    const float* g1_g2 = (const float*)d_in[21];
    const float* g1_be2= (const float*)d_in[22];
    const float* g1_w3 = (const float*)d_in[23];
    const float* g1_b3 = (const float*)d_in[24];
    const float* eps1  = (const float*)d_in[25];
    const float* bn1_g = (const float*)d_in[26];
    const float* bn1_b = (const float*)d_in[27];
    const float* d_w1  = (const float*)d_in[28];
    const float* d_b1  = (const float*)d_in[29];
    const float* d_g   = (const float*)d_in[30];
    const float* d_be  = (const float*)d_in[31];
    const float* d_w2  = (const float*)d_in[32];
    const float* d_b2  = (const float*)d_in[33];
    const float* d_w3  = (const float*)d_in[34];
    const float* d_b3  = (const float*)d_in[35];

    float* ws = (float*)d_ws;
    const size_t NF = (size_t)N * 128;
    float* buf0 = ws;                        // bf16 [N,128] (half-used fp32 slot)
    float* buf1 = ws + NF;
    float* buf2 = ws + 2*NF;
    float* agg0 = ws + 3*NF;                 // N*3
    float* stats= agg0 + (size_t)N*3;        // 7*256
    float* scsh = stats + 7*256;             // 7*256 (layout keep)
    float* lperm = scsh + 7*256;             // E
    int*   cursor = (int*)(lperm + E);       // N
    int*   rowoff = cursor + N;              // N+1
    int*   perm   = rowoff + N + 1;          // E
    int*   dperm  = perm + E;                // E
    int*   eperm  = dperm + E;               // E
    unsigned short* w2t = (unsigned short*)(eperm + E);  // 64*128 bf16
    unsigned short* wT  = w2t + 64*128;                  // 7 * 128*128 bf16

    unsigned short* b0 = (unsigned short*)buf0;
    unsigned short* b1b = (unsigned short*)buf1;
    unsigned short* b2b = (unsigned short*)buf2;

    float* out = (float*)d_out;

    const float* wl = d_w1 + 256*128;   // row 256 of d_w1

    #define STATSK(k) (stats + (k)*256)
    #define WT(m) (wT + (m)*16384)

    const int rowTiles = (N + 63) / 64;
    const int edgeTiles = (E + 63) / 64;
    const int eBlocks = (E + 255) / 256;
    const float invN = 1.f / (float)N;
    const float invE = 1.f / (float)E;
    const int nWaves = 2048 * 4;
    const int nspan = (N + nWaves - 1) / nWaves;
    const int decBlocks = 1280;              // 5 blocks/CU (32KB LDS), persistent

    hipMemsetAsync(stats, 0, 7*256 * sizeof(float), stream);
    hipMemsetAsync(cursor, 0, (size_t)N * sizeof(int), stream);

    // CSR build + weight prep
    hist_dst<<<eBlocks, 256, 0, stream>>>(edst, cursor, E);
    scan_deg<<<1, 1024, 0, stream>>>(cursor, rowoff, cursor, N);
    fill_csr<<<eBlocks, 256, 0, stream>>>(esrc, edst, coords, cursor, perm, dperm, eperm, lperm, E);
    prep_w2<<<32, 256, 0, stream>>>(d_w2, w2t);
    prep_wT<<<dim3(64, 7), 256, 0, stream>>>(g0_w2, g0_w3, g1_w1, g1_w2, g1_w3,
                                             d_w1, d_w1 + 128*128, wT);

    // layer 0
    gather_coords<<<(N + 255)/256, 256, 0, stream>>>(coords, rowoff, perm, agg0, N);
    lin0<<<rowTiles, 256, 0, stream>>>(coords, agg0, g0_w1, g0_b1, eps0, b0, STATSK(0), N);
    gemm_mfma<true,true><<<rowTiles, 256, 0, stream>>>(
        b0, WT(0), g0_b2, STATSK(0), g0_g1, g0_be1, invN, b1b, STATSK(1), N);
    gemm_mfma<true,true><<<rowTiles, 256, 0, stream>>>(
        b1b, WT(1), g0_b3, STATSK(1), g0_g2, g0_be2, invN, b2b, STATSK(2), N);

    // layer 1: h1 = (1+eps1)*bnrelu(t3) + gather(bnrelu(t3))
    gather_combine_bn<<<(N + 3)/4, 256, 0, stream>>>(
        b2b, rowoff, perm, STATSK(2), bn0_g, bn0_b, invN, eps1, b0, N);
    gemm_mfma<false,true><<<rowTiles, 256, 0, stream>>>(
        b0, WT(2), g1_b1, nullptr, nullptr, nullptr, 0.f, b1b, STATSK(3), N);
    gemm_mfma<true,true><<<rowTiles, 256, 0, stream>>>(
        b1b, WT(3), g1_b2, STATSK(3), g1_g1, g1_be1, invN, b2b, STATSK(4), N);
    gemm_mfma<true,true><<<rowTiles, 256, 0, stream>>>(
        b2b, WT(4), g1_b3, STATSK(4), g1_g2, g1_be2, invN, b0, STATSK(5), N);

    // decoder: ya/yb (bf16) from b0 with BN(5) folded into staging
    gemm_mfma<true,false><<<rowTiles, 256, 0, stream>>>(
        b0, WT(5), nullptr, STATSK(5), bn1_g, bn1_b, invN, b1b, nullptr, N);
    gemm_mfma<true,false><<<rowTiles, 256, 0, stream>>>(
        b0, WT(6), nullptr, STATSK(5), bn1_g, bn1_b, invN, b2b, nullptr, N);
    csr_stats<<<2048, 256, 0, stream>>>(b1b, b2b, rowoff, perm, lperm, wl, d_b1,
                                        STATSK(6), N, nspan);
    decoder_fused<<<decBlocks, 256, 0, stream>>>(b1b, b2b, lperm, perm, dperm, eperm,
                                                 wl, d_b1, STATSK(6), d_g, d_be, invE,
                                                 w2t, d_b2, d_w3, d_b3, out, E, edgeTiles);
}